// Round 5
// baseline (538.177 us; speedup 1.0000x reference)
//
#include <hip/hip_runtime.h>
#include <cmath>

// ---------------------------------------------------------------------------
// MLLA block, B=8 L=2048 C=512 H=8 HD=64 MLP_H=2048, fp32 I/O, bf16 MFMA GEMMs
// R12: (a) gemm8 epilogue reverted to direct scalar stores (A/B: 56.5 vs 58.0
//      with LDS-transpose epi at 1 block/CU; conflicts 262K -> 0).
//      (b) gemm_bt keeps wide-store epi (A/B win at 5 blocks/CU) + bf16
//      scratch de-conflicted via +16-col per-quad-pair rotation (4-way -> 2-way).
//      (c) dwc_silu vectorized x8 (bf16x8 + edge scalars).
//      (d) x_q f32->bf16 folded into the transpose launch (concurrent, not
//      serial); xqb relocated to the dead-until-attn OFF_XAMUL region.
// ---------------------------------------------------------------------------

typedef __bf16 bf16;
typedef __bf16 bf16x8 __attribute__((ext_vector_type(8)));
typedef __bf16 bf16x4 __attribute__((ext_vector_type(4)));
typedef float  f32x4  __attribute__((ext_vector_type(4)));

#define B_  8
#define L_  2048
#define C_  512
#define M_  (B_ * L_)          // 16384 tokens

__device__ __forceinline__ float fastrcp(float x) { return __builtin_amdgcn_rcpf(x); }

__device__ __forceinline__ float siluf(float x)
{
    return x * fastrcp(1.f + __expf(-x));
}
__device__ __forceinline__ float elu1f(float x) { return x > 0.f ? x + 1.f : __expf(x); }

// exact-GELU via Abramowitz-Stegun 7.1.25 erf (3-term, |eps| <= 2.5e-5)
__device__ __forceinline__ float geluf(float x)
{
    const float z = fabsf(x) * 0.70710678118654752f;
    const float t = fastrcp(__builtin_fmaf(z, 0.47047f, 1.f));
    const float poly = t * (0.3480242f + t * (-0.0958798f + t * 0.7478556f));
    const float erfz = __builtin_fmaf(-poly, __expf(-z * z), 1.f);
    const float hx = 0.5f * x;
    return __builtin_fmaf(hx, __builtin_copysignf(erfz, x), hx);
}

// global -> LDS direct DMA, 16B per lane. lds dest must be wave-uniform base;
// HW deposits lane i at base + i*16B.
__device__ __forceinline__ void load_lds16(const bf16* g, bf16* l)
{
    __builtin_amdgcn_global_load_lds(
        (const __attribute__((address_space(1))) void*)g,
        (__attribute__((address_space(3))) void*)l, 16, 0, 0);
}

// ---------------------------------------------------------------------------
__global__ __launch_bounds__(256) void zero_k(float* __restrict__ p, int n)
{
    int i = blockIdx.x * 256 + threadIdx.x;
    if (i < n) p[i] = 0.f;
}

__global__ __launch_bounds__(64) void ws_diag_k(float* __restrict__ out, float v)
{
    if (threadIdx.x == 0 && blockIdx.x == 0) out[0] = v;
}

// ---------------------------------------------------------------------------
// ALL weight transposes + x_q f32->bf16 conversion in ONE launch.
// Blocks [0, 3584): transpose jobs. Blocks [3584, 11776): x_q conversion.
// ---------------------------------------------------------------------------
struct TJob  { const float* W; bf16* Wt; int K; int N; int blk0; };
struct TJobs { TJob j[7]; };

__global__ __launch_bounds__(256) void transpose_all_k(
    TJobs jobs, const float* __restrict__ xq, bf16* __restrict__ xqb)
{
    const int bid = blockIdx.x;
    if (bid >= 3584) {
        const int i = (bid - 3584) * 256 + threadIdx.x;   // exactly M_*C_/4
        float4 v = ((const float4*)xq)[i];
        bf16x4 o = { (bf16)v.x, (bf16)v.y, (bf16)v.z, (bf16)v.w };
        ((bf16x4*)xqb)[i] = o;
        return;
    }
    __shared__ float tile[32][33];
    int ji = 0;
#pragma unroll
    for (int i = 1; i < 7; ++i) if (bid >= jobs.j[i].blk0) ji = i;
    const float* W  = jobs.j[ji].W;
    bf16*        Wt = jobs.j[ji].Wt;
    const int K = jobs.j[ji].K, N = jobs.j[ji].N;
    const int rel = bid - jobs.j[ji].blk0;
    const int nb = N >> 5;
    const int n0 = (rel % nb) * 32, k0 = (rel / nb) * 32;
    const int tx = threadIdx.x & 31, ty = threadIdx.x >> 5;   // 32 x 8
#pragma unroll
    for (int i = 0; i < 32; i += 8)
        tile[ty + i][tx] = W[(size_t)(k0 + ty + i) * N + n0 + tx];
    __syncthreads();
#pragma unroll
    for (int i = 0; i < 32; i += 8)
        Wt[(size_t)(n0 + ty + i) * K + k0 + tx] = (bf16)tile[tx][ty + i];
}

// ---------------------------------------------------------------------------
// depthwise conv (k=3, zero pad) along L + residual + LayerNorm.
// ---------------------------------------------------------------------------
__global__ __launch_bounds__(256) void cpe_ln_k(
    const float* __restrict__ xin, const float* __restrict__ cw,
    const float* __restrict__ cb, const float* __restrict__ g,
    const float* __restrict__ bb, float* __restrict__ xres,
    bf16* __restrict__ xln)
{
    const int token = blockIdx.x;
    const int l = token & (L_ - 1);
    const int tid = threadIdx.x;
    const float* row = xin + (size_t)token * C_;
    float v[2]; float s = 0.f, s2 = 0.f;
#pragma unroll
    for (int i = 0; i < 2; ++i) {
        const int c = tid + i * 256;
        float x0 = row[c];
        float xm = (l > 0)      ? row[c - C_] : 0.f;
        float xp = (l < L_ - 1) ? row[c + C_] : 0.f;
        float t = x0 + xm * cw[3*c] + x0 * cw[3*c+1] + xp * cw[3*c+2] + cb[c];
        v[i] = t; s += t; s2 += t * t;
    }
#pragma unroll
    for (int off = 32; off; off >>= 1) { s += __shfl_down(s, off); s2 += __shfl_down(s2, off); }
    __shared__ float rs[4], rs2[4];
    if ((tid & 63) == 0) { rs[tid >> 6] = s; rs2[tid >> 6] = s2; }
    __syncthreads();
    s  = rs[0] + rs[1] + rs[2] + rs[3];
    s2 = rs2[0] + rs2[1] + rs2[2] + rs2[3];
    const float mu = s * (1.f / C_);
    const float rstd = rsqrtf(s2 * (1.f / C_) - mu * mu + 1e-5f);
    float* orow = xres + (size_t)token * C_;
    bf16*  lrow = xln  + (size_t)token * C_;
#pragma unroll
    for (int i = 0; i < 2; ++i) {
        const int c = tid + i * 256;
        orow[c] = v[i];
        lrow[c] = (bf16)((v[i] - mu) * rstd * g[c] + bb[c]);
    }
}

// ---------------------------------------------------------------------------
// dwc conv over the (b,c,l)-reinterpreted flat buffer + SiLU. x8 vectorized:
// 8-aligned runs never cross a 2048-length channel run, so one bf16x8 center
// load + 2 scalar edge loads cover the 3-tap window.
// ---------------------------------------------------------------------------
__global__ __launch_bounds__(256) void dwc_silu_k(
    const bf16* __restrict__ Y, const float* __restrict__ w,
    const float* __restrict__ b, bf16* __restrict__ xp)
{
    const size_t idx = ((size_t)blockIdx.x * 256 + threadIdx.x) * 8;
    const int m = (int)(idx & (size_t)(L_ * C_ - 1));
    const int ch = m >> 11;          // m / 2048
    const int pos = m & (L_ - 1);    // multiple of 8
    const bf16x8 c = *(const bf16x8*)(Y + idx);
    const float left  = (pos > 0)      ? (float)Y[idx - 1] : 0.f;
    const float right = (pos + 8 < L_) ? (float)Y[idx + 8] : 0.f;
    const float w0 = w[3*ch], w1 = w[3*ch+1], w2 = w[3*ch+2], bc = b[ch];
    bf16x8 o;
#pragma unroll
    for (int j = 0; j < 8; ++j) {
        const float x0 = (float)c[j];
        const float xm = j ? (float)c[j-1] : left;
        const float xq = (j < 7) ? (float)c[j+1] : right;
        o[j] = (bf16)siluf(xm * w0 + x0 * w1 + xq * w2 + bc);
    }
    *(bf16x8*)(xp + idx) = o;
}

// ---------------------------------------------------------------------------
// ksum[b, c] = sum_n k[b,n,c] from kvbT rows (c-major): contiguous reduction.
// ---------------------------------------------------------------------------
__global__ __launch_bounds__(256) void ksum_k(
    const bf16* __restrict__ kvbT, float* __restrict__ ksum)
{
    const int c = blockIdx.x;
    const int wave = threadIdx.x >> 6, lane = threadIdx.x & 63;
#pragma unroll
    for (int i = 0; i < 2; ++i) {
        const int b = wave + i * 4;
        const bf16* src = kvbT + (size_t)c * M_ + b * L_ + lane * 32;
        float s = 0.f;
#pragma unroll
        for (int u = 0; u < 4; ++u) {
            bf16x8 v = *(const bf16x8*)(src + u * 8);
#pragma unroll
            for (int j = 0; j < 8; ++j) s += (float)v[j];
        }
#pragma unroll
        for (int o = 32; o; o >>= 1) s += __shfl_down(s, o);
        if (lane == 0) ksum[b * C_ + c] = s;
    }
}

// ---------------------------------------------------------------------------
// kvpart[split][b,h,e,d] = sum_{n in split} v[b,n,h,e] * k[b,n,h,d]
// via MFMA (transposed layout [e][d]); plain stores, no atomics.
// ---------------------------------------------------------------------------
__global__ __launch_bounds__(256) void kvmat_mfma_k(
    const bf16* __restrict__ kvbT, float* __restrict__ kvpart)
{
    const int bh = blockIdx.x, b = bh >> 3, h = bh & 7;
    const int tid = threadIdx.x;
    const int wave = tid >> 6, lane = tid & 63;
    const int l16 = lane & 15, quad = lane >> 4;
    __shared__ bf16 As[64 * 72];   // vT chunk: [e][n]
    __shared__ bf16 Bs[64 * 72];   // kT chunk: [d][n]
    const int r = tid >> 2;              // 0..63: LDS row
    const int cseg = (tid & 3) * 16;     // 16 bf16 per thread
    const size_t kRow = (size_t)(h * 64 + r) * M_;
    const size_t vRow = (size_t)(512 + h * 64 + r) * M_;

    f32x4 acc[4];
    const f32x4 z4 = { 0.f, 0.f, 0.f, 0.f };
#pragma unroll
    for (int ni = 0; ni < 4; ++ni) acc[ni] = z4;

    for (int it = 0; it < 8; ++it) {
        const size_t colBase = (size_t)b * L_ + blockIdx.y * 512 + it * 64;
        {
            const bf16* ga = kvbT + vRow + colBase + cseg;   // A = v
            const bf16* gb = kvbT + kRow + colBase + cseg;   // B = k
            *(uint4*)&As[r * 72 + cseg]     = *(const uint4*)ga;
            *(uint4*)&As[r * 72 + cseg + 8] = *(const uint4*)(ga + 8);
            *(uint4*)&Bs[r * 72 + cseg]     = *(const uint4*)gb;
            *(uint4*)&Bs[r * 72 + cseg + 8] = *(const uint4*)(gb + 8);
        }
        __syncthreads();
#pragma unroll
        for (int kk = 0; kk < 64; kk += 32) {
            bf16x8 af = *(const bf16x8*)(&As[(wave * 16 + l16) * 72 + kk + quad * 8]);
#pragma unroll
            for (int ni = 0; ni < 4; ++ni) {
                bf16x8 bfr = *(const bf16x8*)(&Bs[(ni * 16 + l16) * 72 + kk + quad * 8]);
                acc[ni] = __builtin_amdgcn_mfma_f32_16x16x32_bf16(af, bfr, acc[ni], 0, 0, 0);
            }
        }
        __syncthreads();
    }
    float* dst = kvpart + (size_t)blockIdx.y * 262144 + (size_t)bh * 4096;  // [e][d]
#pragma unroll
    for (int ni = 0; ni < 4; ++ni)
#pragma unroll
        for (int rr = 0; rr < 4; ++rr)
            dst[(wave * 16 + quad * 4 + rr) * 64 + ni * 16 + l16] = acc[ni][rr];
}

// sum 4 partials, scale by 1/L, convert to bf16 (262144 elems)
__global__ __launch_bounds__(256) void kvconv_k(
    const float* __restrict__ p, bf16* __restrict__ out)
{
    int i = blockIdx.x * 256 + threadIdx.x;
    float s = p[i] + p[i + 262144] + p[i + 2 * 262144] + p[i + 3 * 262144];
    out[i] = (bf16)(s * (1.f / (float)L_));
}

// ---------------------------------------------------------------------------
// MFMA attention: per block (bh, 64-token tile); per wave 16 tokens.
// ---------------------------------------------------------------------------
__global__ __launch_bounds__(256) void attn_mfma_k(
    const bf16* __restrict__ q, const bf16* __restrict__ kvbT,
    const bf16* __restrict__ kvmatT, const float* __restrict__ ksum,
    const float* __restrict__ lw, const float* __restrict__ lb,
    const bf16* __restrict__ act_res, bf16* __restrict__ xa_mul)
{
    const int bh = blockIdx.x, b = bh >> 3, h = bh & 7;
    const int n0 = blockIdx.y * 64;
    const int tid = threadIdx.x;
    const int wave = tid >> 6, lane = tid & 63;
    const int l16 = lane & 15, quad = lane >> 4;

    __shared__ bf16 kvT[64 * 72];   // [e][d], stride 72 -> 2-way only
    __shared__ bf16 kmS[64];

#pragma unroll
    for (int i = 0; i < 2; ++i) {
        const int idx = i * 256 + tid;               // 512 chunks of 8
        const int row = idx >> 3, col = (idx & 7) * 8;
        *(bf16x8*)&kvT[row * 72 + col] =
            *(const bf16x8*)&kvmatT[(size_t)bh * 4096 + idx * 8];
    }
    if (tid < 64) kmS[tid] = (bf16)(ksum[b * C_ + h * 64 + tid] * (1.f / (float)L_));
    __syncthreads();

    // A-frags: 16 q-rows direct from global.
    const int tok = n0 + wave * 16;
    const bf16* qbase = q + ((size_t)b * L_ + tok) * C_ + h * 64;
    const bf16x8 af0 = *(const bf16x8*)(qbase + (size_t)l16 * C_ + quad * 8);
    const bf16x8 af1 = *(const bf16x8*)(qbase + (size_t)l16 * C_ + 32 + quad * 8);

    // z-dot: B-tile col0 = k_mean
    const bf16x8 z8 = { bf16(0.f), bf16(0.f), bf16(0.f), bf16(0.f),
                        bf16(0.f), bf16(0.f), bf16(0.f), bf16(0.f) };
    const bf16x8 km0 = *(const bf16x8*)&kmS[quad * 8];
    const bf16x8 km1 = *(const bf16x8*)&kmS[32 + quad * 8];
    const bf16x8 b20 = (l16 == 0) ? km0 : z8;
    const bf16x8 b21 = (l16 == 0) ? km1 : z8;
    f32x4 zd = { 0.f, 0.f, 0.f, 0.f };
    zd = __builtin_amdgcn_mfma_f32_16x16x32_bf16(af0, b20, zd, 0, 0, 0);
    zd = __builtin_amdgcn_mfma_f32_16x16x32_bf16(af1, b21, zd, 0, 0, 0);
    float zr[4];
#pragma unroll
    for (int r = 0; r < 4; ++r)
        zr[r] = fastrcp(__shfl(zd[r], (lane & 48)) + 1e-6f);

    // q @ kvmatT^T
    f32x4 acc[4];
    const f32x4 zf4 = { 0.f, 0.f, 0.f, 0.f };
#pragma unroll
    for (int ni = 0; ni < 4; ++ni) acc[ni] = zf4;
#pragma unroll
    for (int ni = 0; ni < 4; ++ni) {
        const bf16x8 b0 = *(const bf16x8*)&kvT[(ni * 16 + l16) * 72 + quad * 8];
        const bf16x8 b1 = *(const bf16x8*)&kvT[(ni * 16 + l16) * 72 + 32 + quad * 8];
        acc[ni] = __builtin_amdgcn_mfma_f32_16x16x32_bf16(af0, b0, acc[ni], 0, 0, 0);
        acc[ni] = __builtin_amdgcn_mfma_f32_16x16x32_bf16(af1, b1, acc[ni], 0, 0, 0);
    }

    // epilogue: lane holds (token = tok+quad*4+r, e = ni*16+l16)
#pragma unroll
    for (int ni = 0; ni < 4; ++ni) {
        const int e = ni * 16 + l16;
        const int c = h * 64 + e;
        const float w0 = lw[3*c], w1 = lw[3*c+1], w2 = lw[3*c+2], lbc = lb[c];
        const bf16* vrow = kvbT + (size_t)(512 + c) * M_ + b * L_;
#pragma unroll
        for (int r = 0; r < 4; ++r) {
            const int n = tok + quad * 4 + r;
            const float v0 = (float)vrow[n];
            const float vm = (n > 0)      ? (float)vrow[n - 1] : 0.f;
            const float vp = (n < L_ - 1) ? (float)vrow[n + 1] : 0.f;
            const float lepe = vm * w0 + v0 * w1 + vp * w2 + lbc;
            const float xa = acc[ni][r] * zr[r] + lepe;
            const size_t off = ((size_t)b * L_ + n) * C_ + c;
            xa_mul[off] = (bf16)(xa * (float)act_res[off]);
        }
    }
}

// ---------------------------------------------------------------------------
// bf16 MFMA GEMM, m97 structure + XOR-swizzled LDS tiles (128x128, 4 waves).
// Kept for N=512 shapes (q, out-proj, fc2).
// Wide-store epilogue via wave-local LDS transpose; bf16 scratch uses a
// per-quad-pair +16-col rotation so write banks per quad are {0,16,8,24}+4r
// (disjoint -> 2-way only).
// EPI: 2 elu+1->bf16, 4 gelu->bf16, 5 +res->f32, 7 kvT (row<512 elu)->bf16,
//      8 fused act/in: col<512 silu->outp, else plain->outp2
// ---------------------------------------------------------------------------
template <int EPI>
__global__ __launch_bounds__(256) void gemm_bt(
    const bf16* __restrict__ A, const bf16* __restrict__ Bt,
    const float* __restrict__ bias, const float* __restrict__ res,
    void* __restrict__ outp, void* __restrict__ outp2, int K, int N)
{
    __shared__ bf16 smem[2 * 128 * 64];   // As | Bs (8192 each)
    bf16* As = smem;
    bf16* Bs = smem + 8192;
    const int tid = threadIdx.x;
    const int wave = tid >> 6, lane = tid & 63;
    const int wm = (wave & 1) * 64, wn = (wave >> 1) * 64;
    const int l16 = lane & 15, quad = lane >> 4;
    const size_t tileM = (size_t)blockIdx.x * 128;
    const size_t tileN = (size_t)blockIdx.y * 128;

    const int lrow = lane >> 3;
    const int lcol = (((lane & 7) ^ (lrow & 7))) * 8;   // swizzled source col
    const int swz  = l16 & 7;                           // read-side XOR

    const f32x4 z4 = { 0.f, 0.f, 0.f, 0.f };
    f32x4 acc[4][4];
#pragma unroll
    for (int mi = 0; mi < 4; ++mi)
#pragma unroll
        for (int ni = 0; ni < 4; ++ni) acc[mi][ni] = z4;

    for (int k0 = 0; k0 < K; k0 += 64) {
#pragma unroll
        for (int it = 0; it < 4; ++it) {
            const int rg = it * 32 + wave * 8;           // wave-uniform (mult of 8)
            load_lds16(A  + (tileM + rg + lrow) * (size_t)K + k0 + lcol, As + rg * 64);
            load_lds16(Bt + (tileN + rg + lrow) * (size_t)K + k0 + lcol, Bs + rg * 64);
        }
        __syncthreads();
#pragma unroll
        for (int kk = 0; kk < 64; kk += 32) {
            bf16x8 af[4], bfr[4];
#pragma unroll
            for (int mi = 0; mi < 4; ++mi)
                af[mi] = *(const bf16x8*)(&As[(wm + mi * 16 + l16) * 64
                                              + ((((kk >> 3) + quad) ^ swz) * 8)]);
#pragma unroll
            for (int ni = 0; ni < 4; ++ni)
                bfr[ni] = *(const bf16x8*)(&Bs[(wn + ni * 16 + l16) * 64
                                               + ((((kk >> 3) + quad) ^ swz) * 8)]);
#pragma unroll
            for (int mi = 0; mi < 4; ++mi)
#pragma unroll
                for (int ni = 0; ni < 4; ++ni)
                    acc[mi][ni] = __builtin_amdgcn_mfma_f32_16x16x32_bf16(
                        af[mi], bfr[ni], acc[mi][ni], 0, 0, 0);
        }
        __syncthreads();
    }

    // ---- epilogue: wave-local LDS transpose -> coalesced wide stores.
    const int rrow = lane >> 2;           // 0..15
    const int rseg = (lane & 3) * 16;     // 0/16/32/48

    if (EPI == 5 || EPI == 7) {
        float* sc = (float*)smem + wave * 1088;     // 16 rows x 68 f32 (2-way, free)
#pragma unroll
        for (int mi = 0; mi < 4; ++mi) {
#pragma unroll
            for (int ni = 0; ni < 4; ++ni)
#pragma unroll
                for (int r = 0; r < 4; ++r)
                    sc[(quad * 4 + r) * 68 + ni * 16 + l16] = acc[mi][ni][r];
            __builtin_amdgcn_sched_barrier(0);
            const size_t rowg = tileM + wm + mi * 16 + rrow;
            const int    colg = (int)tileN + wn + rseg;
            if (EPI == 5) {
                const float* rp = res + rowg * (size_t)N + colg;
                float*       op = (float*)outp + rowg * (size_t)N + colg;
#pragma unroll
                for (int u = 0; u < 4; ++u) {
                    f32x4 v = *(f32x4*)&sc[rrow * 68 + rseg + u * 4];
                    f32x4 rv = *(const f32x4*)(rp + u * 4);
                    f32x4 bv = *(const f32x4*)(bias + colg + u * 4);
                    f32x4 o;
#pragma unroll
                    for (int j = 0; j < 4; ++j) o[j] = v[j] + bv[j] + rv[j];
                    *(f32x4*)(op + u * 4) = o;
                }
            } else {  // EPI 7
                const float bv = bias[(int)rowg];
                const bool k_side = (rowg < 512);
                bf16* op = (bf16*)outp + rowg * (size_t)N + colg;
#pragma unroll
                for (int hh = 0; hh < 2; ++hh) {
                    bf16x8 o8;
#pragma unroll
                    for (int j = 0; j < 8; ++j) {
                        float x = sc[rrow * 68 + rseg + hh * 8 + j] + bv;
                        o8[j] = (bf16)(k_side ? elu1f(x) : x);
                    }
                    *(bf16x8*)(op + hh * 8) = o8;
                }
            }
            __builtin_amdgcn_sched_barrier(0);
        }
    } else {  // EPI 2, 4, 8: bf16 scratch with +16-col rotation de-conflict
        bf16* sc = (bf16*)smem + wave * 1152;       // 16 rows x 72 bf16
        const int wrot = (quad >> 1) * 16;          // write-side rotation
        const int rrot = ((rrow >> 3) & 1) * 16;    // writer-of-this-row's rot
        const int cbase = (rseg + rrot) & 63;
        float addc[4];
        bool  act_on[4];
#pragma unroll
        for (int ni = 0; ni < 4; ++ni) {
            const int cw = (int)tileN + wn + ni * 16 + l16;
            if (EPI == 8) {
                act_on[ni] = (cw < 512);
                addc[ni] = act_on[ni] ? bias[cw] : res[cw - 512];
            } else { addc[ni] = bias[cw]; act_on[ni] = true; }
        }
#pragma unroll
        for (int mi = 0; mi < 4; ++mi) {
#pragma unroll
            for (int ni = 0; ni < 4; ++ni)
#pragma unroll
                for (int r = 0; r < 4; ++r) {
                    float x = acc[mi][ni][r] + addc[ni];
                    float y;
                    if (EPI == 2)      y = elu1f(x);
                    else if (EPI == 4) y = geluf(x);
                    else               y = act_on[ni] ? siluf(x) : x;
                    sc[(quad * 4 + r) * 72 + ((ni * 16 + l16 + wrot) & 63)] = (bf16)y;
                }
            __builtin_amdgcn_sched_barrier(0);
            const size_t rowg = tileM + wm + mi * 16 + rrow;
            const int    colg = (int)tileN + wn + rseg;
            bf16x8 o0 = *(bf16x8*)&sc[rrow * 72 + cbase];
            bf16x8 o1 = *(bf16x8*)&sc[rrow * 72 + cbase + 8];
            if (EPI == 8) {
                const size_t orow = rowg * (size_t)512;
                bf16* dst = (colg < 512) ? ((bf16*)outp  + orow + colg)
                                         : ((bf16*)outp2 + orow + colg - 512);
                *(bf16x8*)dst = o0; *(bf16x8*)(dst + 8) = o1;
            } else {
                bf16* dst = (bf16*)outp + rowg * (size_t)N + colg;
                *(bf16x8*)dst = o0; *(bf16x8*)(dst + 8) = o1;
            }
            __builtin_amdgcn_sched_barrier(0);
        }
    }
}

// ---------------------------------------------------------------------------
// 256x256 8-wave (2M x 4N) deep-pipelined bf16 GEMM (R9 4-phase core). BK=64,
// double-buffered 128KB LDS, 4 phases per K-tile:
//   ph0: read A-half0(8) + B n0-1(4); stage next-tile loads 0-3;  MFMA m0-3 x n0-1
//   ph1: read B n2-3(4);              stage next-tile loads 4-7;  MFMA m0-3 x n2-3
//   ph2: read A-half1(8);                                         MFMA m4-7 x n0-1
//   ph3: vmcnt(0);                                                MFMA m4-7 x n2-3
// Each phase: raw s_barrier / lgkmcnt(0) / sched_barrier(0) / setprio(1) MFMA.
// R12: epilogue = direct scalar stores (A/B-proven vs LDS-transpose at 1
// block/CU: 56.5 vs 58.0 us on fc1).
// Requires: M % 256 == 0, N % 256 == 0, K % 64 == 0.
// ---------------------------------------------------------------------------
template <int EPI>
__global__ __launch_bounds__(512, 2) void gemm8(
    const bf16* __restrict__ A, const bf16* __restrict__ Bt,
    const float* __restrict__ bias, const float* __restrict__ res,
    void* __restrict__ outp, void* __restrict__ outp2, int K, int N)
{
    __shared__ bf16 smem[4 * 256 * 64];   // As[2] (32768) | Bs[2] (32768)
    bf16* const AsBase = smem;
    bf16* const BsBase = smem + 32768;
    const int tid  = threadIdx.x;
    const int wave = tid >> 6, lane = tid & 63;
    const int wrow = wave >> 2, wcol = wave & 3;       // 2 x 4 wave grid
    const int l16 = lane & 15, quad = lane >> 4;
    const int lrow = lane >> 3;                        // 0..7
    const int lcol = ((lane & 7) ^ lrow) * 8;          // swizzled source chunk
    const int swz  = l16 & 7;                          // read-side XOR
    const size_t tileM = (size_t)blockIdx.x * 256;
    const size_t tileN = (size_t)blockIdx.y * 256;

    // staging bases: wave w, load j covers rows j*64 + w*8 .. +7
    const bf16* aBase = A  + (tileM + wave * 8 + lrow) * (size_t)K + lcol;
    const bf16* bBase = Bt + (tileN + wave * 8 + lrow) * (size_t)K + lcol;
    const int ldsRow0 = wave * 8;

    f32x4 acc[8][4];
    const f32x4 z4 = { 0.f, 0.f, 0.f, 0.f };
#pragma unroll
    for (int mi = 0; mi < 8; ++mi)
#pragma unroll
        for (int ni = 0; ni < 4; ++ni) acc[mi][ni] = z4;

    // prologue: stage K-tile 0 into buf 0 (8 loads/thread), drain, barrier
#pragma unroll
    for (int j = 0; j < 4; ++j) {
        load_lds16(aBase + (size_t)(j * 64) * K, AsBase + (j * 64 + ldsRow0) * 64);
        load_lds16(bBase + (size_t)(j * 64) * K, BsBase + (j * 64 + ldsRow0) * 64);
    }
    asm volatile("s_waitcnt vmcnt(0)" ::: "memory");
    __builtin_amdgcn_s_barrier();

    const int T = K >> 6;
    int cur = 0;
    for (int t = 0; t < T; ++t) {
        const int nxt = cur ^ 1;
        const bool pf = (t + 1 < T);
        const int kc = (t + 1) << 6;                   // next tile's K offset
        const bf16* as = AsBase + cur * 16384;
        const bf16* bs = BsBase + cur * 16384;
        bf16* asn = AsBase + nxt * 16384;
        bf16* bsn = BsBase + nxt * 16384;
        bf16x8 af[4][2], bfr[4][2];

        // ---------------- phase 0: A-half0 + B(n0,n1); stage loads 0-3 ----
#pragma unroll
        for (int j = 0; j < 4; ++j)
#pragma unroll
            for (int kh = 0; kh < 2; ++kh)
                af[j][kh] = *(const bf16x8*)&as[(wrow * 128 + j * 16 + l16) * 64
                                               + (((kh * 4 + quad) ^ swz) * 8)];
#pragma unroll
        for (int ni = 0; ni < 2; ++ni)
#pragma unroll
            for (int kh = 0; kh < 2; ++kh)
                bfr[ni][kh] = *(const bf16x8*)&bs[(wcol * 64 + ni * 16 + l16) * 64
                                                  + (((kh * 4 + quad) ^ swz) * 8)];
        if (pf) {
#pragma unroll
            for (int j = 0; j < 2; ++j) {
                load_lds16(aBase + (size_t)(j * 64) * K + kc, asn + (j * 64 + ldsRow0) * 64);
                load_lds16(bBase + (size_t)(j * 64) * K + kc, bsn + (j * 64 + ldsRow0) * 64);
            }
        }
        __builtin_amdgcn_s_barrier();
        asm volatile("s_waitcnt lgkmcnt(0)" ::: "memory");
        __builtin_amdgcn_sched_barrier(0);
        __builtin_amdgcn_s_setprio(1);
#pragma unroll
        for (int j = 0; j < 4; ++j)
#pragma unroll
            for (int ni = 0; ni < 2; ++ni)
#pragma unroll
                for (int kh = 0; kh < 2; ++kh)
                    acc[j][ni] = __builtin_amdgcn_mfma_f32_16x16x32_bf16(
                        af[j][kh], bfr[ni][kh], acc[j][ni], 0, 0, 0);
        __builtin_amdgcn_s_setprio(0);
        __builtin_amdgcn_s_barrier();

        // ---------------- phase 1: B(n2,n3); stage loads 4-7 --------------
#pragma unroll
        for (int ni = 2; ni < 4; ++ni)
#pragma unroll
            for (int kh = 0; kh < 2; ++kh)
                bfr[ni][kh] = *(const bf16x8*)&bs[(wcol * 64 + ni * 16 + l16) * 64
                                                  + (((kh * 4 + quad) ^ swz) * 8)];
        if (pf) {
#pragma unroll
            for (int j = 2; j < 4; ++j) {
                load_lds16(aBase + (size_t)(j * 64) * K + kc, asn + (j * 64 + ldsRow0) * 64);
                load_lds16(bBase + (size_t)(j * 64) * K + kc, bsn + (j * 64 + ldsRow0) * 64);
            }
        }
        __builtin_amdgcn_s_barrier();
        asm volatile("s_waitcnt lgkmcnt(0)" ::: "memory");
        __builtin_amdgcn_sched_barrier(0);
        __builtin_amdgcn_s_setprio(1);
#pragma unroll
        for (int j = 0; j < 4; ++j)
#pragma unroll
            for (int ni = 2; ni < 4; ++ni)
#pragma unroll
                for (int kh = 0; kh < 2; ++kh)
                    acc[j][ni] = __builtin_amdgcn_mfma_f32_16x16x32_bf16(
                        af[j][kh], bfr[ni][kh], acc[j][ni], 0, 0, 0);
        __builtin_amdgcn_s_setprio(0);
        __builtin_amdgcn_s_barrier();

        // ---------------- phase 2: A-half1 --------------------------------
#pragma unroll
        for (int j = 0; j < 4; ++j)
#pragma unroll
            for (int kh = 0; kh < 2; ++kh)
                af[j][kh] = *(const bf16x8*)&as[(wrow * 128 + 64 + j * 16 + l16) * 64
                                               + (((kh * 4 + quad) ^ swz) * 8)];
        __builtin_amdgcn_s_barrier();
        asm volatile("s_waitcnt lgkmcnt(0)" ::: "memory");
        __builtin_amdgcn_sched_barrier(0);
        __builtin_amdgcn_s_setprio(1);
#pragma unroll
        for (int j = 0; j < 4; ++j)
#pragma unroll
            for (int ni = 0; ni < 2; ++ni)
#pragma unroll
                for (int kh = 0; kh < 2; ++kh)
                    acc[4 + j][ni] = __builtin_amdgcn_mfma_f32_16x16x32_bf16(
                        af[j][kh], bfr[ni][kh], acc[4 + j][ni], 0, 0, 0);
        __builtin_amdgcn_s_setprio(0);
        __builtin_amdgcn_s_barrier();

        // ---------------- phase 3: wait next tile; last quadrant ----------
        if (pf) asm volatile("s_waitcnt vmcnt(0)" ::: "memory");
        __builtin_amdgcn_s_barrier();
        __builtin_amdgcn_sched_barrier(0);
        __builtin_amdgcn_s_setprio(1);
#pragma unroll
        for (int j = 0; j < 4; ++j)
#pragma unroll
            for (int ni = 2; ni < 4; ++ni)
#pragma unroll
                for (int kh = 0; kh < 2; ++kh)
                    acc[4 + j][ni] = __builtin_amdgcn_mfma_f32_16x16x32_bf16(
                        af[j][kh], bfr[ni][kh], acc[4 + j][ni], 0, 0, 0);
        __builtin_amdgcn_s_setprio(0);
        __builtin_amdgcn_s_barrier();

        cur = nxt;
    }

    // epilogue (R12: direct scalar stores): lane holds
    // (row = tileM + wrow*128 + mi*16 + quad*4 + r, col = tileN + wcol*64 + ni*16 + l16)
#pragma unroll
    for (int mi = 0; mi < 8; ++mi) {
#pragma unroll
        for (int ni = 0; ni < 4; ++ni) {
#pragma unroll
            for (int r = 0; r < 4; ++r) {
                const size_t row = tileM + wrow * 128 + mi * 16 + quad * 4 + r;
                const int   col = (int)tileN + wcol * 64 + ni * 16 + l16;
                float v = acc[mi][ni][r];
                const size_t oidx = row * (size_t)N + col;
                if (EPI == 2)      ((bf16*)outp)[oidx] = (bf16)elu1f(v + bias[col]);
                else if (EPI == 4) ((bf16*)outp)[oidx] = (bf16)geluf(v + bias[col]);
                else if (EPI == 5) ((float*)outp)[oidx] = v + bias[col] + res[oidx];
                else if (EPI == 7) {
                    v += bias[(int)row];
                    ((bf16*)outp)[oidx] = (bf16)((row < 512) ? elu1f(v) : v);
                } else if (EPI == 8) {
                    const size_t orow = row * (size_t)512;
                    if (col < 512) ((bf16*)outp )[orow + col]       = (bf16)siluf(v + bias[col]);
                    else           ((bf16*)outp2)[orow + col - 512] = (bf16)(v + res[col - 512]);
                }
            }
        }
    }
}

// ---------------------------------------------------------------------------
// workspace layout (bytes) — total 125,845,504 (~120 MiB)
// ---------------------------------------------------------------------------
#define OFF_WT_ACTIN ((size_t)0)         // bf16 [1024][512] 1MB
#define OFF_WT_Q    ((size_t)1048576)
#define OFF_WT_KV   ((size_t)1572864)
#define OFF_WT_OUT  ((size_t)2621440)
#define OFF_WT_FC1  ((size_t)3145728)
#define OFF_WT_FC2  ((size_t)5242880)
#define OFF_XLN     ((size_t)7340032)    // bf16 16MB (kvbf, hln alias)
#define OFF_ACTRES  ((size_t)24117248)   // bf16 16MB (x3 aliases from here)
#define OFF_Y       ((size_t)40894464)   // bf16 16MB (qb aliases)
#define OFF_XP      ((size_t)57671680)   // bf16 16MB (kvpart, h1 alias from here)
#define OFF_KV      ((size_t)74448896)   // bf16 32MB  kvbT [1024][16384]
#define OFF_KSUM    ((size_t)108003328)  // f32 16KB
#define OFF_XAMUL   ((size_t)109068288)  // bf16 16MB  (xqb early, xamul late)
#define OFF_X3      ((size_t)24117248)   // f32 32MB over actres+Y (dead)
#define OFF_H1      ((size_t)57671680)   // bf16 64MB over xp+kv+xamul (dead)
#define WS_REQUIRED ((size_t)125845504)

extern "C" void kernel_launch(void* const* d_in, const int* in_sizes, int n_in,
                              void* d_out, int out_size, void* d_ws, size_t ws_size,
                              hipStream_t stream)
{
    const float* x_q    = (const float*)d_in[0];
    const float* x_kv   = (const float*)d_in[1];
    const float* cpe1_w = (const float*)d_in[2];
    const float* cpe1_b = (const float*)d_in[3];
    const float* n1_g   = (const float*)d_in[4];
    const float* n1_b   = (const float*)d_in[5];
    const float* in_w   = (const float*)d_in[6];
    const float* in_b   = (const float*)d_in[7];
    const float* act_w  = (const float*)d_in[8];
    const float* act_b  = (const float*)d_in[9];
    const float* dwc_w  = (const float*)d_in[10];
    const float* dwc_b  = (const float*)d_in[11];
    const float* q_w    = (const float*)d_in[12];
    const float* q_b    = (const float*)d_in[13];
    const float* kv_w   = (const float*)d_in[14];
    const float* kv_b   = (const float*)d_in[15];
    const float* lepe_w = (const float*)d_in[16];
    const float* lepe_b = (const float*)d_in[17];
    const float* out_w  = (const float*)d_in[18];
    const float* out_b  = (const float*)d_in[19];
    const float* cpe2_w = (const float*)d_in[20];
    const float* cpe2_b = (const float*)d_in[21];
    const float* n2_g   = (const float*)d_in[22];
    const float* n2_b   = (const float*)d_in[23];
    const float* fc1_w  = (const float*)d_in[24];
    const float* fc1_b  = (const float*)d_in[25];
    const float* fc2_w  = (const float*)d_in[26];
    const float* fc2_b  = (const float*)d_in[27];

    float* outf = (float*)d_out;

    if (ws_size < WS_REQUIRED) {
        zero_k<<<(out_size + 255) / 256, 256, 0, stream>>>(outf, out_size);
        ws_diag_k<<<1, 64, 0, stream>>>(outf, (float)ws_size);
        return;
    }

    char* ws = (char*)d_ws;
    bf16*  wt_actin = (bf16*)(ws + OFF_WT_ACTIN);
    bf16*  wt_q   = (bf16*)(ws + OFF_WT_Q);
    bf16*  wt_kv  = (bf16*)(ws + OFF_WT_KV);
    bf16*  wt_out = (bf16*)(ws + OFF_WT_OUT);
    bf16*  wt_fc1 = (bf16*)(ws + OFF_WT_FC1);
    bf16*  wt_fc2 = (bf16*)(ws + OFF_WT_FC2);
    bf16*  xln    = (bf16*)(ws + OFF_XLN);
    bf16*  kvbf   = (bf16*)(ws + OFF_XLN);      // alias: xln dead after act/in
    bf16*  hln    = (bf16*)(ws + OFF_XLN);      // alias: kvbf dead after attn
    bf16*  actres = (bf16*)(ws + OFF_ACTRES);
    bf16*  Y      = (bf16*)(ws + OFF_Y);
    bf16*  qb     = (bf16*)(ws + OFF_Y);        // alias: Y dead after dwc
    bf16*  xp     = (bf16*)(ws + OFF_XP);
    float* kvpart = (float*)(ws + OFF_XP);      // alias: xp dead after kv-gemm (4MB)
    bf16*  kvbT   = (bf16*)(ws + OFF_KV);       // [1024][16384]
    float* ksum   = (float*)(ws + OFF_KSUM);
    bf16*  xqb    = (bf16*)(ws + OFF_XAMUL);    // early use; dead before attn
    bf16*  xamul  = (bf16*)(ws + OFF_XAMUL);    // written by attn (after q-gemm)
    float* x3     = (float*)(ws + OFF_X3);      // alias
    bf16*  h1     = (bf16*)(ws + OFF_H1);       // alias

    // all weight transposes + x_q -> bf16 conversion, one launch
    TJobs jobs;
    jobs.j[0] = { act_w, wt_actin,             512,  512,    0 };
    jobs.j[1] = { in_w,  wt_actin + 512 * 512, 512,  512,  256 };
    jobs.j[2] = { q_w,   wt_q,                 512,  512,  512 };
    jobs.j[3] = { kv_w,  wt_kv,                512, 1024,  768 };
    jobs.j[4] = { out_w, wt_out,               512,  512, 1280 };
    jobs.j[5] = { fc1_w, wt_fc1,               512, 2048, 1536 };
    jobs.j[6] = { fc2_w, wt_fc2,              2048,  512, 2560 };
    transpose_all_k<<<11776, 256, 0, stream>>>(jobs, x_q, xqb);

    // cpe1 + LN1: shortcut (fp32) lives in d_out
    cpe_ln_k<<<M_, 256, 0, stream>>>(x_kv, cpe1_w, cpe1_b, n1_g, n1_b, outf, xln);

    // fused act gate + in-proj (one pass over xln), N=1024  [256x256 pipelined]
    gemm8<8><<<dim3(64, 4), 512, 0, stream>>>(xln, wt_actin, act_b, in_b, actres, Y, 512, 1024);

    // flat-reshape dwconv + silu -> xp (frees Y)
    dwc_silu_k<<<4096, 256, 0, stream>>>(Y, dwc_w, dwc_b, xp);

    // q = elu+1(xqb @ q_w) -> qb (@Y)
    gemm_bt<2><<<dim3(128, 4), 256, 0, stream>>>(xqb, wt_q, q_b, nullptr, qb, nullptr, 512, 512);

    // kvbT[c][token] = (xp @ kv_w)^T : roles swapped (A=wt_kv, Bt=xp)  [256x256]
    gemm8<7><<<dim3(4, 64), 512, 0, stream>>>(wt_kv, xp, kv_b, nullptr, kvbT, nullptr, 512, M_);

    // k_mean, kvmatT partials (MFMA, no atomics), reduce+bf16 convert
    ksum_k<<<C_, 256, 0, stream>>>(kvbT, ksum);
    kvmat_mfma_k<<<dim3(64, 4), 256, 0, stream>>>(kvbT, kvpart);
    kvconv_k<<<1024, 256, 0, stream>>>(kvpart, kvbf);

    // MFMA attention + lepe + gate multiply (xqb dead from here; xamul written)
    attn_mfma_k<<<dim3(64, 32), 256, 0, stream>>>(qb, kvbT, kvbf, ksum,
                                                  lepe_w, lepe_b, actres, xamul);

    // out-proj + shortcut residual, in-place on d_out
    gemm_bt<5><<<dim3(128, 4), 256, 0, stream>>>(xamul, wt_out, out_b, outf, outf, nullptr, 512, 512);

    // cpe2 + LN2: x2 (=d_out) -> x3 (fp32 ws) + hln (bf16)
    cpe_ln_k<<<M_, 256, 0, stream>>>(outf, cpe2_w, cpe2_b, n2_g, n2_b, x3, hln);

    // MLP: fc1 (gelu) [256x256 pipelined] -> fc2 (+x3) -> d_out
    gemm8<4><<<dim3(64, 8), 512, 0, stream>>>(hln, wt_fc1, fc1_b, nullptr, h1, nullptr, 512, 2048);
    gemm_bt<5><<<dim3(128, 4),  256, 0, stream>>>(h1,  wt_fc2, fc2_b, x3, outf, nullptr, 2048, 512);

    (void)in_sizes; (void)n_in; (void)out_size; (void)ws_size;
}

// Round 6
// 454.558 us; speedup vs baseline: 1.1840x; 1.1840x over previous
//
#include <hip/hip_runtime.h>
#include <cmath>

// ---------------------------------------------------------------------------
// MLLA block, B=8 L=2048 C=512 H=8 HD=64 MLP_H=2048, fp32 I/O, bf16 MFMA GEMMs
// R13: recovery round. Exact R11 GEMM kernels (best measured total: 469us;
//      gemm8-fc1 58.0us). Only two low-risk deltas vs R11, both in separate
//      small kernels: (1) dwc_silu vectorized x8; (2) x_q f32->bf16 merged
//      into the transpose launch (xqb -> OFF_XAMUL region, dead until attn).
//      R12's gemm8 scalar-epilogue revert (83.7us, -44%) is NOT carried:
//      identical code measured 56.5 in R9 -> codegen/env fluke, not signal.
// ---------------------------------------------------------------------------

typedef __bf16 bf16;
typedef __bf16 bf16x8 __attribute__((ext_vector_type(8)));
typedef __bf16 bf16x4 __attribute__((ext_vector_type(4)));
typedef float  f32x4  __attribute__((ext_vector_type(4)));

#define B_  8
#define L_  2048
#define C_  512
#define M_  (B_ * L_)          // 16384 tokens

__device__ __forceinline__ float fastrcp(float x) { return __builtin_amdgcn_rcpf(x); }

__device__ __forceinline__ float siluf(float x)
{
    return x * fastrcp(1.f + __expf(-x));
}
__device__ __forceinline__ float elu1f(float x) { return x > 0.f ? x + 1.f : __expf(x); }

// exact-GELU via Abramowitz-Stegun 7.1.25 erf (3-term, |eps| <= 2.5e-5)
__device__ __forceinline__ float geluf(float x)
{
    const float z = fabsf(x) * 0.70710678118654752f;
    const float t = fastrcp(__builtin_fmaf(z, 0.47047f, 1.f));
    const float poly = t * (0.3480242f + t * (-0.0958798f + t * 0.7478556f));
    const float erfz = __builtin_fmaf(-poly, __expf(-z * z), 1.f);
    const float hx = 0.5f * x;
    return __builtin_fmaf(hx, __builtin_copysignf(erfz, x), hx);
}

// global -> LDS direct DMA, 16B per lane. lds dest must be wave-uniform base;
// HW deposits lane i at base + i*16B.
__device__ __forceinline__ void load_lds16(const bf16* g, bf16* l)
{
    __builtin_amdgcn_global_load_lds(
        (const __attribute__((address_space(1))) void*)g,
        (__attribute__((address_space(3))) void*)l, 16, 0, 0);
}

// ---------------------------------------------------------------------------
__global__ __launch_bounds__(256) void zero_k(float* __restrict__ p, int n)
{
    int i = blockIdx.x * 256 + threadIdx.x;
    if (i < n) p[i] = 0.f;
}

__global__ __launch_bounds__(64) void ws_diag_k(float* __restrict__ out, float v)
{
    if (threadIdx.x == 0 && blockIdx.x == 0) out[0] = v;
}

// ---------------------------------------------------------------------------
// ALL weight transposes + x_q f32->bf16 conversion in ONE launch.
// Blocks [0, 3584): transpose jobs. Blocks [3584, 11776): x_q conversion.
// ---------------------------------------------------------------------------
struct TJob  { const float* W; bf16* Wt; int K; int N; int blk0; };
struct TJobs { TJob j[7]; };

__global__ __launch_bounds__(256) void transpose_all_k(
    TJobs jobs, const float* __restrict__ xq, bf16* __restrict__ xqb)
{
    const int bid = blockIdx.x;
    if (bid >= 3584) {
        const int i = (bid - 3584) * 256 + threadIdx.x;   // exactly M_*C_/4
        float4 v = ((const float4*)xq)[i];
        bf16x4 o = { (bf16)v.x, (bf16)v.y, (bf16)v.z, (bf16)v.w };
        ((bf16x4*)xqb)[i] = o;
        return;
    }
    __shared__ float tile[32][33];
    int ji = 0;
#pragma unroll
    for (int i = 1; i < 7; ++i) if (bid >= jobs.j[i].blk0) ji = i;
    const float* W  = jobs.j[ji].W;
    bf16*        Wt = jobs.j[ji].Wt;
    const int K = jobs.j[ji].K, N = jobs.j[ji].N;
    const int rel = bid - jobs.j[ji].blk0;
    const int nb = N >> 5;
    const int n0 = (rel % nb) * 32, k0 = (rel / nb) * 32;
    const int tx = threadIdx.x & 31, ty = threadIdx.x >> 5;   // 32 x 8
#pragma unroll
    for (int i = 0; i < 32; i += 8)
        tile[ty + i][tx] = W[(size_t)(k0 + ty + i) * N + n0 + tx];
    __syncthreads();
#pragma unroll
    for (int i = 0; i < 32; i += 8)
        Wt[(size_t)(n0 + ty + i) * K + k0 + tx] = (bf16)tile[tx][ty + i];
}

// ---------------------------------------------------------------------------
// depthwise conv (k=3, zero pad) along L + residual + LayerNorm.
// ---------------------------------------------------------------------------
__global__ __launch_bounds__(256) void cpe_ln_k(
    const float* __restrict__ xin, const float* __restrict__ cw,
    const float* __restrict__ cb, const float* __restrict__ g,
    const float* __restrict__ bb, float* __restrict__ xres,
    bf16* __restrict__ xln)
{
    const int token = blockIdx.x;
    const int l = token & (L_ - 1);
    const int tid = threadIdx.x;
    const float* row = xin + (size_t)token * C_;
    float v[2]; float s = 0.f, s2 = 0.f;
#pragma unroll
    for (int i = 0; i < 2; ++i) {
        const int c = tid + i * 256;
        float x0 = row[c];
        float xm = (l > 0)      ? row[c - C_] : 0.f;
        float xp = (l < L_ - 1) ? row[c + C_] : 0.f;
        float t = x0 + xm * cw[3*c] + x0 * cw[3*c+1] + xp * cw[3*c+2] + cb[c];
        v[i] = t; s += t; s2 += t * t;
    }
#pragma unroll
    for (int off = 32; off; off >>= 1) { s += __shfl_down(s, off); s2 += __shfl_down(s2, off); }
    __shared__ float rs[4], rs2[4];
    if ((tid & 63) == 0) { rs[tid >> 6] = s; rs2[tid >> 6] = s2; }
    __syncthreads();
    s  = rs[0] + rs[1] + rs[2] + rs[3];
    s2 = rs2[0] + rs2[1] + rs2[2] + rs2[3];
    const float mu = s * (1.f / C_);
    const float rstd = rsqrtf(s2 * (1.f / C_) - mu * mu + 1e-5f);
    float* orow = xres + (size_t)token * C_;
    bf16*  lrow = xln  + (size_t)token * C_;
#pragma unroll
    for (int i = 0; i < 2; ++i) {
        const int c = tid + i * 256;
        orow[c] = v[i];
        lrow[c] = (bf16)((v[i] - mu) * rstd * g[c] + bb[c]);
    }
}

// ---------------------------------------------------------------------------
// dwc conv over the (b,c,l)-reinterpreted flat buffer + SiLU. x8 vectorized:
// 8-aligned runs never cross a 2048-length channel run, so one bf16x8 center
// load + 2 scalar edge loads cover the 3-tap window.
// ---------------------------------------------------------------------------
__global__ __launch_bounds__(256) void dwc_silu_k(
    const bf16* __restrict__ Y, const float* __restrict__ w,
    const float* __restrict__ b, bf16* __restrict__ xp)
{
    const size_t idx = ((size_t)blockIdx.x * 256 + threadIdx.x) * 8;
    const int m = (int)(idx & (size_t)(L_ * C_ - 1));
    const int ch = m >> 11;          // m / 2048
    const int pos = m & (L_ - 1);    // multiple of 8
    const bf16x8 c = *(const bf16x8*)(Y + idx);
    const float left  = (pos > 0)      ? (float)Y[idx - 1] : 0.f;
    const float right = (pos + 8 < L_) ? (float)Y[idx + 8] : 0.f;
    const float w0 = w[3*ch], w1 = w[3*ch+1], w2 = w[3*ch+2], bc = b[ch];
    bf16x8 o;
#pragma unroll
    for (int j = 0; j < 8; ++j) {
        const float x0 = (float)c[j];
        const float xm = j ? (float)c[j-1] : left;
        const float xq = (j < 7) ? (float)c[j+1] : right;
        o[j] = (bf16)siluf(xm * w0 + x0 * w1 + xq * w2 + bc);
    }
    *(bf16x8*)(xp + idx) = o;
}

// ---------------------------------------------------------------------------
// ksum[b, c] = sum_n k[b,n,c] from kvbT rows (c-major): contiguous reduction.
// ---------------------------------------------------------------------------
__global__ __launch_bounds__(256) void ksum_k(
    const bf16* __restrict__ kvbT, float* __restrict__ ksum)
{
    const int c = blockIdx.x;
    const int wave = threadIdx.x >> 6, lane = threadIdx.x & 63;
#pragma unroll
    for (int i = 0; i < 2; ++i) {
        const int b = wave + i * 4;
        const bf16* src = kvbT + (size_t)c * M_ + b * L_ + lane * 32;
        float s = 0.f;
#pragma unroll
        for (int u = 0; u < 4; ++u) {
            bf16x8 v = *(const bf16x8*)(src + u * 8);
#pragma unroll
            for (int j = 0; j < 8; ++j) s += (float)v[j];
        }
#pragma unroll
        for (int o = 32; o; o >>= 1) s += __shfl_down(s, o);
        if (lane == 0) ksum[b * C_ + c] = s;
    }
}

// ---------------------------------------------------------------------------
// kvpart[split][b,h,e,d] = sum_{n in split} v[b,n,h,e] * k[b,n,h,d]
// via MFMA (transposed layout [e][d]); plain stores, no atomics.
// ---------------------------------------------------------------------------
__global__ __launch_bounds__(256) void kvmat_mfma_k(
    const bf16* __restrict__ kvbT, float* __restrict__ kvpart)
{
    const int bh = blockIdx.x, b = bh >> 3, h = bh & 7;
    const int tid = threadIdx.x;
    const int wave = tid >> 6, lane = tid & 63;
    const int l16 = lane & 15, quad = lane >> 4;
    __shared__ bf16 As[64 * 72];   // vT chunk: [e][n]
    __shared__ bf16 Bs[64 * 72];   // kT chunk: [d][n]
    const int r = tid >> 2;              // 0..63: LDS row
    const int cseg = (tid & 3) * 16;     // 16 bf16 per thread
    const size_t kRow = (size_t)(h * 64 + r) * M_;
    const size_t vRow = (size_t)(512 + h * 64 + r) * M_;

    f32x4 acc[4];
    const f32x4 z4 = { 0.f, 0.f, 0.f, 0.f };
#pragma unroll
    for (int ni = 0; ni < 4; ++ni) acc[ni] = z4;

    for (int it = 0; it < 8; ++it) {
        const size_t colBase = (size_t)b * L_ + blockIdx.y * 512 + it * 64;
        {
            const bf16* ga = kvbT + vRow + colBase + cseg;   // A = v
            const bf16* gb = kvbT + kRow + colBase + cseg;   // B = k
            *(uint4*)&As[r * 72 + cseg]     = *(const uint4*)ga;
            *(uint4*)&As[r * 72 + cseg + 8] = *(const uint4*)(ga + 8);
            *(uint4*)&Bs[r * 72 + cseg]     = *(const uint4*)gb;
            *(uint4*)&Bs[r * 72 + cseg + 8] = *(const uint4*)(gb + 8);
        }
        __syncthreads();
#pragma unroll
        for (int kk = 0; kk < 64; kk += 32) {
            bf16x8 af = *(const bf16x8*)(&As[(wave * 16 + l16) * 72 + kk + quad * 8]);
#pragma unroll
            for (int ni = 0; ni < 4; ++ni) {
                bf16x8 bfr = *(const bf16x8*)(&Bs[(ni * 16 + l16) * 72 + kk + quad * 8]);
                acc[ni] = __builtin_amdgcn_mfma_f32_16x16x32_bf16(af, bfr, acc[ni], 0, 0, 0);
            }
        }
        __syncthreads();
    }
    float* dst = kvpart + (size_t)blockIdx.y * 262144 + (size_t)bh * 4096;  // [e][d]
#pragma unroll
    for (int ni = 0; ni < 4; ++ni)
#pragma unroll
        for (int rr = 0; rr < 4; ++rr)
            dst[(wave * 16 + quad * 4 + rr) * 64 + ni * 16 + l16] = acc[ni][rr];
}

// sum 4 partials, scale by 1/L, convert to bf16 (262144 elems)
__global__ __launch_bounds__(256) void kvconv_k(
    const float* __restrict__ p, bf16* __restrict__ out)
{
    int i = blockIdx.x * 256 + threadIdx.x;
    float s = p[i] + p[i + 262144] + p[i + 2 * 262144] + p[i + 3 * 262144];
    out[i] = (bf16)(s * (1.f / (float)L_));
}

// ---------------------------------------------------------------------------
// MFMA attention: per block (bh, 64-token tile); per wave 16 tokens.
// ---------------------------------------------------------------------------
__global__ __launch_bounds__(256) void attn_mfma_k(
    const bf16* __restrict__ q, const bf16* __restrict__ kvbT,
    const bf16* __restrict__ kvmatT, const float* __restrict__ ksum,
    const float* __restrict__ lw, const float* __restrict__ lb,
    const bf16* __restrict__ act_res, bf16* __restrict__ xa_mul)
{
    const int bh = blockIdx.x, b = bh >> 3, h = bh & 7;
    const int n0 = blockIdx.y * 64;
    const int tid = threadIdx.x;
    const int wave = tid >> 6, lane = tid & 63;
    const int l16 = lane & 15, quad = lane >> 4;

    __shared__ bf16 kvT[64 * 72];   // [e][d], stride 72 -> 2-way only
    __shared__ bf16 kmS[64];

#pragma unroll
    for (int i = 0; i < 2; ++i) {
        const int idx = i * 256 + tid;               // 512 chunks of 8
        const int row = idx >> 3, col = (idx & 7) * 8;
        *(bf16x8*)&kvT[row * 72 + col] =
            *(const bf16x8*)&kvmatT[(size_t)bh * 4096 + idx * 8];
    }
    if (tid < 64) kmS[tid] = (bf16)(ksum[b * C_ + h * 64 + tid] * (1.f / (float)L_));
    __syncthreads();

    // A-frags: 16 q-rows direct from global.
    const int tok = n0 + wave * 16;
    const bf16* qbase = q + ((size_t)b * L_ + tok) * C_ + h * 64;
    const bf16x8 af0 = *(const bf16x8*)(qbase + (size_t)l16 * C_ + quad * 8);
    const bf16x8 af1 = *(const bf16x8*)(qbase + (size_t)l16 * C_ + 32 + quad * 8);

    // z-dot: B-tile col0 = k_mean
    const bf16x8 z8 = { bf16(0.f), bf16(0.f), bf16(0.f), bf16(0.f),
                        bf16(0.f), bf16(0.f), bf16(0.f), bf16(0.f) };
    const bf16x8 km0 = *(const bf16x8*)&kmS[quad * 8];
    const bf16x8 km1 = *(const bf16x8*)&kmS[32 + quad * 8];
    const bf16x8 b20 = (l16 == 0) ? km0 : z8;
    const bf16x8 b21 = (l16 == 0) ? km1 : z8;
    f32x4 zd = { 0.f, 0.f, 0.f, 0.f };
    zd = __builtin_amdgcn_mfma_f32_16x16x32_bf16(af0, b20, zd, 0, 0, 0);
    zd = __builtin_amdgcn_mfma_f32_16x16x32_bf16(af1, b21, zd, 0, 0, 0);
    float zr[4];
#pragma unroll
    for (int r = 0; r < 4; ++r)
        zr[r] = fastrcp(__shfl(zd[r], (lane & 48)) + 1e-6f);

    // q @ kvmatT^T
    f32x4 acc[4];
    const f32x4 zf4 = { 0.f, 0.f, 0.f, 0.f };
#pragma unroll
    for (int ni = 0; ni < 4; ++ni) acc[ni] = zf4;
#pragma unroll
    for (int ni = 0; ni < 4; ++ni) {
        const bf16x8 b0 = *(const bf16x8*)&kvT[(ni * 16 + l16) * 72 + quad * 8];
        const bf16x8 b1 = *(const bf16x8*)&kvT[(ni * 16 + l16) * 72 + 32 + quad * 8];
        acc[ni] = __builtin_amdgcn_mfma_f32_16x16x32_bf16(af0, b0, acc[ni], 0, 0, 0);
        acc[ni] = __builtin_amdgcn_mfma_f32_16x16x32_bf16(af1, b1, acc[ni], 0, 0, 0);
    }

    // epilogue: lane holds (token = tok+quad*4+r, e = ni*16+l16)
#pragma unroll
    for (int ni = 0; ni < 4; ++ni) {
        const int e = ni * 16 + l16;
        const int c = h * 64 + e;
        const float w0 = lw[3*c], w1 = lw[3*c+1], w2 = lw[3*c+2], lbc = lb[c];
        const bf16* vrow = kvbT + (size_t)(512 + c) * M_ + b * L_;
#pragma unroll
        for (int r = 0; r < 4; ++r) {
            const int n = tok + quad * 4 + r;
            const float v0 = (float)vrow[n];
            const float vm = (n > 0)      ? (float)vrow[n - 1] : 0.f;
            const float vp = (n < L_ - 1) ? (float)vrow[n + 1] : 0.f;
            const float lepe = vm * w0 + v0 * w1 + vp * w2 + lbc;
            const float xa = acc[ni][r] * zr[r] + lepe;
            const size_t off = ((size_t)b * L_ + n) * C_ + c;
            xa_mul[off] = (bf16)(xa * (float)act_res[off]);
        }
    }
}

// ---------------------------------------------------------------------------
// bf16 MFMA GEMM, m97 structure + XOR-swizzled LDS tiles (128x128, 4 waves).
// Kept for N=512 shapes (q, out-proj, fc2).
// R11 epilogue: wide-store via wave-local LDS transpose (reuses As/Bs LDS
// after the final __syncthreads; per-wave disjoint scratch; no extra sync).
// EPI: 2 elu+1->bf16, 4 gelu->bf16, 5 +res->f32, 7 kvT (row<512 elu)->bf16,
//      8 fused act/in: col<512 silu->outp, else plain->outp2
// ---------------------------------------------------------------------------
template <int EPI>
__global__ __launch_bounds__(256) void gemm_bt(
    const bf16* __restrict__ A, const bf16* __restrict__ Bt,
    const float* __restrict__ bias, const float* __restrict__ res,
    void* __restrict__ outp, void* __restrict__ outp2, int K, int N)
{
    __shared__ bf16 smem[2 * 128 * 64];   // As | Bs (8192 each)
    bf16* As = smem;
    bf16* Bs = smem + 8192;
    const int tid = threadIdx.x;
    const int wave = tid >> 6, lane = tid & 63;
    const int wm = (wave & 1) * 64, wn = (wave >> 1) * 64;
    const int l16 = lane & 15, quad = lane >> 4;
    const size_t tileM = (size_t)blockIdx.x * 128;
    const size_t tileN = (size_t)blockIdx.y * 128;

    const int lrow = lane >> 3;
    const int lcol = (((lane & 7) ^ (lrow & 7))) * 8;   // swizzled source col
    const int swz  = l16 & 7;                           // read-side XOR

    const f32x4 z4 = { 0.f, 0.f, 0.f, 0.f };
    f32x4 acc[4][4];
#pragma unroll
    for (int mi = 0; mi < 4; ++mi)
#pragma unroll
        for (int ni = 0; ni < 4; ++ni) acc[mi][ni] = z4;

    for (int k0 = 0; k0 < K; k0 += 64) {
#pragma unroll
        for (int it = 0; it < 4; ++it) {
            const int rg = it * 32 + wave * 8;           // wave-uniform (mult of 8)
            load_lds16(A  + (tileM + rg + lrow) * (size_t)K + k0 + lcol, As + rg * 64);
            load_lds16(Bt + (tileN + rg + lrow) * (size_t)K + k0 + lcol, Bs + rg * 64);
        }
        __syncthreads();
#pragma unroll
        for (int kk = 0; kk < 64; kk += 32) {
            bf16x8 af[4], bfr[4];
#pragma unroll
            for (int mi = 0; mi < 4; ++mi)
                af[mi] = *(const bf16x8*)(&As[(wm + mi * 16 + l16) * 64
                                              + ((((kk >> 3) + quad) ^ swz) * 8)]);
#pragma unroll
            for (int ni = 0; ni < 4; ++ni)
                bfr[ni] = *(const bf16x8*)(&Bs[(wn + ni * 16 + l16) * 64
                                               + ((((kk >> 3) + quad) ^ swz) * 8)]);
#pragma unroll
            for (int mi = 0; mi < 4; ++mi)
#pragma unroll
                for (int ni = 0; ni < 4; ++ni)
                    acc[mi][ni] = __builtin_amdgcn_mfma_f32_16x16x32_bf16(
                        af[mi], bfr[ni], acc[mi][ni], 0, 0, 0);
        }
        __syncthreads();
    }

    // ---- epilogue: wave-local LDS transpose -> coalesced wide stores.
    const int rrow = lane >> 2;           // 0..15
    const int rseg = (lane & 3) * 16;     // 0/16/32/48

    if (EPI == 5 || EPI == 7) {
        float* sc = (float*)smem + wave * 1088;     // 16 rows x 68 f32
#pragma unroll
        for (int mi = 0; mi < 4; ++mi) {
#pragma unroll
            for (int ni = 0; ni < 4; ++ni)
#pragma unroll
                for (int r = 0; r < 4; ++r)
                    sc[(quad * 4 + r) * 68 + ni * 16 + l16] = acc[mi][ni][r];
            __builtin_amdgcn_sched_barrier(0);
            const size_t rowg = tileM + wm + mi * 16 + rrow;
            const int    colg = (int)tileN + wn + rseg;
            if (EPI == 5) {
                const float* rp = res + rowg * (size_t)N + colg;
                float*       op = (float*)outp + rowg * (size_t)N + colg;
#pragma unroll
                for (int u = 0; u < 4; ++u) {
                    f32x4 v = *(f32x4*)&sc[rrow * 68 + rseg + u * 4];
                    f32x4 rv = *(const f32x4*)(rp + u * 4);
                    f32x4 bv = *(const f32x4*)(bias + colg + u * 4);
                    f32x4 o;
#pragma unroll
                    for (int j = 0; j < 4; ++j) o[j] = v[j] + bv[j] + rv[j];
                    *(f32x4*)(op + u * 4) = o;
                }
            } else {  // EPI 7
                const float bv = bias[(int)rowg];
                const bool k_side = (rowg < 512);
                bf16* op = (bf16*)outp + rowg * (size_t)N + colg;
#pragma unroll
                for (int hh = 0; hh < 2; ++hh) {
                    bf16x8 o8;
#pragma unroll
                    for (int j = 0; j < 8; ++j) {
                        float x = sc[rrow * 68 + rseg + hh * 8 + j] + bv;
                        o8[j] = (bf16)(k_side ? elu1f(x) : x);
                    }
                    *(bf16x8*)(op + hh * 8) = o8;
                }
            }
            __builtin_amdgcn_sched_barrier(0);
        }
    } else {  // EPI 2, 4, 8: bf16 scratch, write-side bias+activation
        bf16* sc = (bf16*)smem + wave * 1152;       // 16 rows x 72 bf16
        float addc[4];
        bool  act_on[4];
#pragma unroll
        for (int ni = 0; ni < 4; ++ni) {
            const int cw = (int)tileN + wn + ni * 16 + l16;
            if (EPI == 8) {
                act_on[ni] = (cw < 512);
                addc[ni] = act_on[ni] ? bias[cw] : res[cw - 512];
            } else { addc[ni] = bias[cw]; act_on[ni] = true; }
        }
#pragma unroll
        for (int mi = 0; mi < 4; ++mi) {
#pragma unroll
            for (int ni = 0; ni < 4; ++ni)
#pragma unroll
                for (int r = 0; r < 4; ++r) {
                    float x = acc[mi][ni][r] + addc[ni];
                    float y;
                    if (EPI == 2)      y = elu1f(x);
                    else if (EPI == 4) y = geluf(x);
                    else               y = act_on[ni] ? siluf(x) : x;
                    sc[(quad * 4 + r) * 72 + ni * 16 + l16] = (bf16)y;
                }
            __builtin_amdgcn_sched_barrier(0);
            const size_t rowg = tileM + wm + mi * 16 + rrow;
            const int    colg = (int)tileN + wn + rseg;
            bf16x8 o0 = *(bf16x8*)&sc[rrow * 72 + rseg];
            bf16x8 o1 = *(bf16x8*)&sc[rrow * 72 + rseg + 8];
            if (EPI == 8) {
                const size_t orow = rowg * (size_t)512;
                bf16* dst = (colg < 512) ? ((bf16*)outp  + orow + colg)
                                         : ((bf16*)outp2 + orow + colg - 512);
                *(bf16x8*)dst = o0; *(bf16x8*)(dst + 8) = o1;
            } else {
                bf16* dst = (bf16*)outp + rowg * (size_t)N + colg;
                *(bf16x8*)dst = o0; *(bf16x8*)(dst + 8) = o1;
            }
            __builtin_amdgcn_sched_barrier(0);
        }
    }
}

// ---------------------------------------------------------------------------
// 256x256 8-wave (2M x 4N) deep-pipelined bf16 GEMM (R9 4-phase core). BK=64,
// double-buffered 128KB LDS, 4 phases per K-tile:
//   ph0: read A-half0(8) + B n0-1(4); stage next-tile loads 0-3;  MFMA m0-3 x n0-1
//   ph1: read B n2-3(4);              stage next-tile loads 4-7;  MFMA m0-3 x n2-3
//   ph2: read A-half1(8);                                         MFMA m4-7 x n0-1
//   ph3: vmcnt(0);                                                MFMA m4-7 x n2-3
// Each phase: raw s_barrier / lgkmcnt(0) / sched_barrier(0) / setprio(1) MFMA.
// R11 epilogue: wide-store via wave-local LDS transpose.
// Requires: M % 256 == 0, N % 256 == 0, K % 64 == 0.
// ---------------------------------------------------------------------------
template <int EPI>
__global__ __launch_bounds__(512, 2) void gemm8(
    const bf16* __restrict__ A, const bf16* __restrict__ Bt,
    const float* __restrict__ bias, const float* __restrict__ res,
    void* __restrict__ outp, void* __restrict__ outp2, int K, int N)
{
    __shared__ bf16 smem[4 * 256 * 64];   // As[2] (32768) | Bs[2] (32768)
    bf16* const AsBase = smem;
    bf16* const BsBase = smem + 32768;
    const int tid  = threadIdx.x;
    const int wave = tid >> 6, lane = tid & 63;
    const int wrow = wave >> 2, wcol = wave & 3;       // 2 x 4 wave grid
    const int l16 = lane & 15, quad = lane >> 4;
    const int lrow = lane >> 3;                        // 0..7
    const int lcol = ((lane & 7) ^ lrow) * 8;          // swizzled source chunk
    const int swz  = l16 & 7;                          // read-side XOR
    const size_t tileM = (size_t)blockIdx.x * 256;
    const size_t tileN = (size_t)blockIdx.y * 256;

    // staging bases: wave w, load j covers rows j*64 + w*8 .. +7
    const bf16* aBase = A  + (tileM + wave * 8 + lrow) * (size_t)K + lcol;
    const bf16* bBase = Bt + (tileN + wave * 8 + lrow) * (size_t)K + lcol;
    const int ldsRow0 = wave * 8;

    f32x4 acc[8][4];
    const f32x4 z4 = { 0.f, 0.f, 0.f, 0.f };
#pragma unroll
    for (int mi = 0; mi < 8; ++mi)
#pragma unroll
        for (int ni = 0; ni < 4; ++ni) acc[mi][ni] = z4;

    // prologue: stage K-tile 0 into buf 0 (8 loads/thread), drain, barrier
#pragma unroll
    for (int j = 0; j < 4; ++j) {
        load_lds16(aBase + (size_t)(j * 64) * K, AsBase + (j * 64 + ldsRow0) * 64);
        load_lds16(bBase + (size_t)(j * 64) * K, BsBase + (j * 64 + ldsRow0) * 64);
    }
    asm volatile("s_waitcnt vmcnt(0)" ::: "memory");
    __builtin_amdgcn_s_barrier();

    const int T = K >> 6;
    int cur = 0;
    for (int t = 0; t < T; ++t) {
        const int nxt = cur ^ 1;
        const bool pf = (t + 1 < T);
        const int kc = (t + 1) << 6;                   // next tile's K offset
        const bf16* as = AsBase + cur * 16384;
        const bf16* bs = BsBase + cur * 16384;
        bf16* asn = AsBase + nxt * 16384;
        bf16* bsn = BsBase + nxt * 16384;
        bf16x8 af[4][2], bfr[4][2];

        // ---------------- phase 0: A-half0 + B(n0,n1); stage loads 0-3 ----
#pragma unroll
        for (int j = 0; j < 4; ++j)
#pragma unroll
            for (int kh = 0; kh < 2; ++kh)
                af[j][kh] = *(const bf16x8*)&as[(wrow * 128 + j * 16 + l16) * 64
                                               + (((kh * 4 + quad) ^ swz) * 8)];
#pragma unroll
        for (int ni = 0; ni < 2; ++ni)
#pragma unroll
            for (int kh = 0; kh < 2; ++kh)
                bfr[ni][kh] = *(const bf16x8*)&bs[(wcol * 64 + ni * 16 + l16) * 64
                                                  + (((kh * 4 + quad) ^ swz) * 8)];
        if (pf) {
#pragma unroll
            for (int j = 0; j < 2; ++j) {
                load_lds16(aBase + (size_t)(j * 64) * K + kc, asn + (j * 64 + ldsRow0) * 64);
                load_lds16(bBase + (size_t)(j * 64) * K + kc, bsn + (j * 64 + ldsRow0) * 64);
            }
        }
        __builtin_amdgcn_s_barrier();
        asm volatile("s_waitcnt lgkmcnt(0)" ::: "memory");
        __builtin_amdgcn_sched_barrier(0);
        __builtin_amdgcn_s_setprio(1);
#pragma unroll
        for (int j = 0; j < 4; ++j)
#pragma unroll
            for (int ni = 0; ni < 2; ++ni)
#pragma unroll
                for (int kh = 0; kh < 2; ++kh)
                    acc[j][ni] = __builtin_amdgcn_mfma_f32_16x16x32_bf16(
                        af[j][kh], bfr[ni][kh], acc[j][ni], 0, 0, 0);
        __builtin_amdgcn_s_setprio(0);
        __builtin_amdgcn_s_barrier();

        // ---------------- phase 1: B(n2,n3); stage loads 4-7 --------------
#pragma unroll
        for (int ni = 2; ni < 4; ++ni)
#pragma unroll
            for (int kh = 0; kh < 2; ++kh)
                bfr[ni][kh] = *(const bf16x8*)&bs[(wcol * 64 + ni * 16 + l16) * 64
                                                  + (((kh * 4 + quad) ^ swz) * 8)];
        if (pf) {
#pragma unroll
            for (int j = 2; j < 4; ++j) {
                load_lds16(aBase + (size_t)(j * 64) * K + kc, asn + (j * 64 + ldsRow0) * 64);
                load_lds16(bBase + (size_t)(j * 64) * K + kc, bsn + (j * 64 + ldsRow0) * 64);
            }
        }
        __builtin_amdgcn_s_barrier();
        asm volatile("s_waitcnt lgkmcnt(0)" ::: "memory");
        __builtin_amdgcn_sched_barrier(0);
        __builtin_amdgcn_s_setprio(1);
#pragma unroll
        for (int j = 0; j < 4; ++j)
#pragma unroll
            for (int ni = 2; ni < 4; ++ni)
#pragma unroll
                for (int kh = 0; kh < 2; ++kh)
                    acc[j][ni] = __builtin_amdgcn_mfma_f32_16x16x32_bf16(
                        af[j][kh], bfr[ni][kh], acc[j][ni], 0, 0, 0);
        __builtin_amdgcn_s_setprio(0);
        __builtin_amdgcn_s_barrier();

        // ---------------- phase 2: A-half1 --------------------------------
#pragma unroll
        for (int j = 0; j < 4; ++j)
#pragma unroll
            for (int kh = 0; kh < 2; ++kh)
                af[j][kh] = *(const bf16x8*)&as[(wrow * 128 + 64 + j * 16 + l16) * 64
                                               + (((kh * 4 + quad) ^ swz) * 8)];
        __builtin_amdgcn_s_barrier();
        asm volatile("s_waitcnt lgkmcnt(0)" ::: "memory");
        __builtin_amdgcn_sched_barrier(0);
        __builtin_amdgcn_s_setprio(1);
#pragma unroll
        for (int j = 0; j < 4; ++j)
#pragma unroll
            for (int ni = 0; ni < 2; ++ni)
#pragma unroll
                for (int kh = 0; kh < 2; ++kh)
                    acc[4 + j][ni] = __builtin_amdgcn_mfma_f32_16x16x32_bf16(
                        af[j][kh], bfr[ni][kh], acc[4 + j][ni], 0, 0, 0);
        __builtin_amdgcn_s_setprio(0);
        __builtin_amdgcn_s_barrier();

        // ---------------- phase 3: wait next tile; last quadrant ----------
        if (pf) asm volatile("s_waitcnt vmcnt(0)" ::: "memory");
        __builtin_amdgcn_s_barrier();
        __builtin_amdgcn_sched_barrier(0);
        __builtin_amdgcn_s_setprio(1);
#pragma unroll
        for (int j = 0; j < 4; ++j)
#pragma unroll
            for (int ni = 2; ni < 4; ++ni)
#pragma unroll
                for (int kh = 0; kh < 2; ++kh)
                    acc[4 + j][ni] = __builtin_amdgcn_mfma_f32_16x16x32_bf16(
                        af[j][kh], bfr[ni][kh], acc[4 + j][ni], 0, 0, 0);
        __builtin_amdgcn_s_setprio(0);
        __builtin_amdgcn_s_barrier();

        cur = nxt;
    }

    // ---- epilogue: wave-local LDS transpose -> coalesced wide stores.
    // Loop ended with s_barrier: all waves done reading As/Bs; vmcnt drained.
    const int rrow = lane >> 2;           // 0..15
    const int rseg = (lane & 3) * 16;     // 0/16/32/48

    if (EPI == 5 || EPI == 7) {
        float* sc = (float*)smem + wave * 1088;     // 16 rows x 68 f32
#pragma unroll
        for (int mi = 0; mi < 8; ++mi) {
#pragma unroll
            for (int ni = 0; ni < 4; ++ni)
#pragma unroll
                for (int r = 0; r < 4; ++r)
                    sc[(quad * 4 + r) * 68 + ni * 16 + l16] = acc[mi][ni][r];
            __builtin_amdgcn_sched_barrier(0);
            const size_t rowg = tileM + wrow * 128 + mi * 16 + rrow;
            const int    colg = (int)tileN + wcol * 64 + rseg;
            if (EPI == 5) {
                const float* rp = res + rowg * (size_t)N + colg;
                float*       op = (float*)outp + rowg * (size_t)N + colg;
#pragma unroll
                for (int u = 0; u < 4; ++u) {
                    f32x4 v = *(f32x4*)&sc[rrow * 68 + rseg + u * 4];
                    f32x4 rv = *(const f32x4*)(rp + u * 4);
                    f32x4 bv = *(const f32x4*)(bias + colg + u * 4);
                    f32x4 o;
#pragma unroll
                    for (int j = 0; j < 4; ++j) o[j] = v[j] + bv[j] + rv[j];
                    *(f32x4*)(op + u * 4) = o;
                }
            } else {  // EPI 7
                const float bv = bias[(int)rowg];
                const bool k_side = (rowg < 512);
                bf16* op = (bf16*)outp + rowg * (size_t)N + colg;
#pragma unroll
                for (int hh = 0; hh < 2; ++hh) {
                    bf16x8 o8;
#pragma unroll
                    for (int j = 0; j < 8; ++j) {
                        float x = sc[rrow * 68 + rseg + hh * 8 + j] + bv;
                        o8[j] = (bf16)(k_side ? elu1f(x) : x);
                    }
                    *(bf16x8*)(op + hh * 8) = o8;
                }
            }
            __builtin_amdgcn_sched_barrier(0);
        }
    } else {  // EPI 2, 4, 8: bf16 scratch, write-side bias+activation
        bf16* sc = (bf16*)smem + wave * 1152;       // 16 rows x 72 bf16
        float addc[4];
        bool  act_on[4];
#pragma unroll
        for (int ni = 0; ni < 4; ++ni) {
            const int cw = (int)tileN + wcol * 64 + ni * 16 + l16;
            if (EPI == 8) {
                act_on[ni] = (cw < 512);
                addc[ni] = act_on[ni] ? bias[cw] : res[cw - 512];
            } else { addc[ni] = bias[cw]; act_on[ni] = true; }
        }
#pragma unroll
        for (int mi = 0; mi < 8; ++mi) {
#pragma unroll
            for (int ni = 0; ni < 4; ++ni)
#pragma unroll
                for (int r = 0; r < 4; ++r) {
                    float x = acc[mi][ni][r] + addc[ni];
                    float y;
                    if (EPI == 2)      y = elu1f(x);
                    else if (EPI == 4) y = geluf(x);
                    else               y = act_on[ni] ? siluf(x) : x;
                    sc[(quad * 4 + r) * 72 + ni * 16 + l16] = (bf16)y;
                }
            __builtin_amdgcn_sched_barrier(0);
            const size_t rowg = tileM + wrow * 128 + mi * 16 + rrow;
            const int    colg = (int)tileN + wcol * 64 + rseg;
            bf16x8 o0 = *(bf16x8*)&sc[rrow * 72 + rseg];
            bf16x8 o1 = *(bf16x8*)&sc[rrow * 72 + rseg + 8];
            if (EPI == 8) {
                const size_t orow = rowg * (size_t)512;
                bf16* dst = (colg < 512) ? ((bf16*)outp  + orow + colg)
                                         : ((bf16*)outp2 + orow + colg - 512);
                *(bf16x8*)dst = o0; *(bf16x8*)(dst + 8) = o1;
            } else {
                bf16* dst = (bf16*)outp + rowg * (size_t)N + colg;
                *(bf16x8*)dst = o0; *(bf16x8*)(dst + 8) = o1;
            }
            __builtin_amdgcn_sched_barrier(0);
        }
    }
}

// ---------------------------------------------------------------------------
// workspace layout (bytes) — total 125,845,504 (~120 MiB)
// ---------------------------------------------------------------------------
#define OFF_WT_ACTIN ((size_t)0)         // bf16 [1024][512] 1MB
#define OFF_WT_Q    ((size_t)1048576)
#define OFF_WT_KV   ((size_t)1572864)
#define OFF_WT_OUT  ((size_t)2621440)
#define OFF_WT_FC1  ((size_t)3145728)
#define OFF_WT_FC2  ((size_t)5242880)
#define OFF_XLN     ((size_t)7340032)    // bf16 16MB (kvbf, hln alias)
#define OFF_ACTRES  ((size_t)24117248)   // bf16 16MB (x3 aliases from here)
#define OFF_Y       ((size_t)40894464)   // bf16 16MB (qb aliases)
#define OFF_XP      ((size_t)57671680)   // bf16 16MB (kvpart, h1 alias from here)
#define OFF_KV      ((size_t)74448896)   // bf16 32MB  kvbT [1024][16384]
#define OFF_KSUM    ((size_t)108003328)  // f32 16KB
#define OFF_XAMUL   ((size_t)109068288)  // bf16 16MB  (xqb early, xamul late)
#define OFF_X3      ((size_t)24117248)   // f32 32MB over actres+Y (dead)
#define OFF_H1      ((size_t)57671680)   // bf16 64MB over xp+kv+xamul (dead)
#define WS_REQUIRED ((size_t)125845504)

extern "C" void kernel_launch(void* const* d_in, const int* in_sizes, int n_in,
                              void* d_out, int out_size, void* d_ws, size_t ws_size,
                              hipStream_t stream)
{
    const float* x_q    = (const float*)d_in[0];
    const float* x_kv   = (const float*)d_in[1];
    const float* cpe1_w = (const float*)d_in[2];
    const float* cpe1_b = (const float*)d_in[3];
    const float* n1_g   = (const float*)d_in[4];
    const float* n1_b   = (const float*)d_in[5];
    const float* in_w   = (const float*)d_in[6];
    const float* in_b   = (const float*)d_in[7];
    const float* act_w  = (const float*)d_in[8];
    const float* act_b  = (const float*)d_in[9];
    const float* dwc_w  = (const float*)d_in[10];
    const float* dwc_b  = (const float*)d_in[11];
    const float* q_w    = (const float*)d_in[12];
    const float* q_b    = (const float*)d_in[13];
    const float* kv_w   = (const float*)d_in[14];
    const float* kv_b   = (const float*)d_in[15];
    const float* lepe_w = (const float*)d_in[16];
    const float* lepe_b = (const float*)d_in[17];
    const float* out_w  = (const float*)d_in[18];
    const float* out_b  = (const float*)d_in[19];
    const float* cpe2_w = (const float*)d_in[20];
    const float* cpe2_b = (const float*)d_in[21];
    const float* n2_g   = (const float*)d_in[22];
    const float* n2_b   = (const float*)d_in[23];
    const float* fc1_w  = (const float*)d_in[24];
    const float* fc1_b  = (const float*)d_in[25];
    const float* fc2_w  = (const float*)d_in[26];
    const float* fc2_b  = (const float*)d_in[27];

    float* outf = (float*)d_out;

    if (ws_size < WS_REQUIRED) {
        zero_k<<<(out_size + 255) / 256, 256, 0, stream>>>(outf, out_size);
        ws_diag_k<<<1, 64, 0, stream>>>(outf, (float)ws_size);
        return;
    }

    char* ws = (char*)d_ws;
    bf16*  wt_actin = (bf16*)(ws + OFF_WT_ACTIN);
    bf16*  wt_q   = (bf16*)(ws + OFF_WT_Q);
    bf16*  wt_kv  = (bf16*)(ws + OFF_WT_KV);
    bf16*  wt_out = (bf16*)(ws + OFF_WT_OUT);
    bf16*  wt_fc1 = (bf16*)(ws + OFF_WT_FC1);
    bf16*  wt_fc2 = (bf16*)(ws + OFF_WT_FC2);
    bf16*  xln    = (bf16*)(ws + OFF_XLN);
    bf16*  kvbf   = (bf16*)(ws + OFF_XLN);      // alias: xln dead after act/in
    bf16*  hln    = (bf16*)(ws + OFF_XLN);      // alias: kvbf dead after attn
    bf16*  actres = (bf16*)(ws + OFF_ACTRES);
    bf16*  Y      = (bf16*)(ws + OFF_Y);
    bf16*  qb     = (bf16*)(ws + OFF_Y);        // alias: Y dead after dwc
    bf16*  xp     = (bf16*)(ws + OFF_XP);
    float* kvpart = (float*)(ws + OFF_XP);      // alias: xp dead after kv-gemm (4MB)
    bf16*  kvbT   = (bf16*)(ws + OFF_KV);       // [1024][16384]
    float* ksum   = (float*)(ws + OFF_KSUM);
    bf16*  xqb    = (bf16*)(ws + OFF_XAMUL);    // early use; dead before attn
    bf16*  xamul  = (bf16*)(ws + OFF_XAMUL);    // written by attn (after q-gemm)
    float* x3     = (float*)(ws + OFF_X3);      // alias
    bf16*  h1     = (bf16*)(ws + OFF_H1);       // alias

    // all weight transposes + x_q -> bf16 conversion, one launch
    TJobs jobs;
    jobs.j[0] = { act_w, wt_actin,             512,  512,    0 };
    jobs.j[1] = { in_w,  wt_actin + 512 * 512, 512,  512,  256 };
    jobs.j[2] = { q_w,   wt_q,                 512,  512,  512 };
    jobs.j[3] = { kv_w,  wt_kv,                512, 1024,  768 };
    jobs.j[4] = { out_w, wt_out,               512,  512, 1280 };
    jobs.j[5] = { fc1_w, wt_fc1,               512, 2048, 1536 };
    jobs.j[6] = { fc2_w, wt_fc2,              2048,  512, 2560 };
    transpose_all_k<<<11776, 256, 0, stream>>>(jobs, x_q, xqb);

    // cpe1 + LN1: shortcut (fp32) lives in d_out
    cpe_ln_k<<<M_, 256, 0, stream>>>(x_kv, cpe1_w, cpe1_b, n1_g, n1_b, outf, xln);

    // fused act gate + in-proj (one pass over xln), N=1024  [256x256 pipelined]
    gemm8<8><<<dim3(64, 4), 512, 0, stream>>>(xln, wt_actin, act_b, in_b, actres, Y, 512, 1024);

    // flat-reshape dwconv + silu -> xp (frees Y)
    dwc_silu_k<<<4096, 256, 0, stream>>>(Y, dwc_w, dwc_b, xp);

    // q = elu+1(xqb @ q_w) -> qb (@Y)
    gemm_bt<2><<<dim3(128, 4), 256, 0, stream>>>(xqb, wt_q, q_b, nullptr, qb, nullptr, 512, 512);

    // kvbT[c][token] = (xp @ kv_w)^T : roles swapped (A=wt_kv, Bt=xp)  [256x256]
    gemm8<7><<<dim3(4, 64), 512, 0, stream>>>(wt_kv, xp, kv_b, nullptr, kvbT, nullptr, 512, M_);

    // k_mean, kvmatT partials (MFMA, no atomics), reduce+bf16 convert
    ksum_k<<<C_, 256, 0, stream>>>(kvbT, ksum);
    kvmat_mfma_k<<<dim3(64, 4), 256, 0, stream>>>(kvbT, kvpart);
    kvconv_k<<<1024, 256, 0, stream>>>(kvpart, kvbf);

    // MFMA attention + lepe + gate multiply (xqb dead from here; xamul written)
    attn_mfma_k<<<dim3(64, 32), 256, 0, stream>>>(qb, kvbT, kvbf, ksum,
                                                  lepe_w, lepe_b, actres, xamul);

    // out-proj + shortcut residual, in-place on d_out
    gemm_bt<5><<<dim3(128, 4), 256, 0, stream>>>(xamul, wt_out, out_b, outf, outf, nullptr, 512, 512);

    // cpe2 + LN2: x2 (=d_out) -> x3 (fp32 ws) + hln (bf16)
    cpe_ln_k<<<M_, 256, 0, stream>>>(outf, cpe2_w, cpe2_b, n2_g, n2_b, x3, hln);

    // MLP: fc1 (gelu) [256x256 pipelined] -> fc2 (+x3) -> d_out
    gemm8<4><<<dim3(64, 8), 512, 0, stream>>>(hln, wt_fc1, fc1_b, nullptr, h1, nullptr, 512, 2048);
    gemm_bt<5><<<dim3(128, 4),  256, 0, stream>>>(h1,  wt_fc2, fc2_b, x3, outf, nullptr, 2048, 512);

    (void)in_sizes; (void)n_in; (void)out_size; (void)ws_size;
}

// Round 7
// 442.151 us; speedup vs baseline: 1.2172x; 1.0281x over previous
//
#include <hip/hip_runtime.h>
#include <cmath>

// ---------------------------------------------------------------------------
// MLLA block, B=8 L=2048 C=512 H=8 HD=64 MLP_H=2048, fp32 I/O, bf16 MFMA GEMMs
// R14: attn_mfma_k lepe epilogue de-scattered — V-halo tile (64x66) staged
//      coalesced into LDS (Vs[64][72], halo cols at 64/65). Previously each
//      lane issued ~22 scalar bf16 loads across V-rows 32KB apart (16 cache
//      lines per wave-group for 32B useful). Values and FLOP order identical
//      -> bit-identical output. GEMMs byte-identical to R13 (fc1 56.0us,
//      total 454.6us; R12's 83.7 confirmed as codegen/env fluke).
// ---------------------------------------------------------------------------

typedef __bf16 bf16;
typedef __bf16 bf16x8 __attribute__((ext_vector_type(8)));
typedef __bf16 bf16x4 __attribute__((ext_vector_type(4)));
typedef float  f32x4  __attribute__((ext_vector_type(4)));

#define B_  8
#define L_  2048
#define C_  512
#define M_  (B_ * L_)          // 16384 tokens

__device__ __forceinline__ float fastrcp(float x) { return __builtin_amdgcn_rcpf(x); }

__device__ __forceinline__ float siluf(float x)
{
    return x * fastrcp(1.f + __expf(-x));
}
__device__ __forceinline__ float elu1f(float x) { return x > 0.f ? x + 1.f : __expf(x); }

// exact-GELU via Abramowitz-Stegun 7.1.25 erf (3-term, |eps| <= 2.5e-5)
__device__ __forceinline__ float geluf(float x)
{
    const float z = fabsf(x) * 0.70710678118654752f;
    const float t = fastrcp(__builtin_fmaf(z, 0.47047f, 1.f));
    const float poly = t * (0.3480242f + t * (-0.0958798f + t * 0.7478556f));
    const float erfz = __builtin_fmaf(-poly, __expf(-z * z), 1.f);
    const float hx = 0.5f * x;
    return __builtin_fmaf(hx, __builtin_copysignf(erfz, x), hx);
}

// global -> LDS direct DMA, 16B per lane. lds dest must be wave-uniform base;
// HW deposits lane i at base + i*16B.
__device__ __forceinline__ void load_lds16(const bf16* g, bf16* l)
{
    __builtin_amdgcn_global_load_lds(
        (const __attribute__((address_space(1))) void*)g,
        (__attribute__((address_space(3))) void*)l, 16, 0, 0);
}

// ---------------------------------------------------------------------------
__global__ __launch_bounds__(256) void zero_k(float* __restrict__ p, int n)
{
    int i = blockIdx.x * 256 + threadIdx.x;
    if (i < n) p[i] = 0.f;
}

__global__ __launch_bounds__(64) void ws_diag_k(float* __restrict__ out, float v)
{
    if (threadIdx.x == 0 && blockIdx.x == 0) out[0] = v;
}

// ---------------------------------------------------------------------------
// ALL weight transposes + x_q f32->bf16 conversion in ONE launch.
// Blocks [0, 3584): transpose jobs. Blocks [3584, 11776): x_q conversion.
// ---------------------------------------------------------------------------
struct TJob  { const float* W; bf16* Wt; int K; int N; int blk0; };
struct TJobs { TJob j[7]; };

__global__ __launch_bounds__(256) void transpose_all_k(
    TJobs jobs, const float* __restrict__ xq, bf16* __restrict__ xqb)
{
    const int bid = blockIdx.x;
    if (bid >= 3584) {
        const int i = (bid - 3584) * 256 + threadIdx.x;   // exactly M_*C_/4
        float4 v = ((const float4*)xq)[i];
        bf16x4 o = { (bf16)v.x, (bf16)v.y, (bf16)v.z, (bf16)v.w };
        ((bf16x4*)xqb)[i] = o;
        return;
    }
    __shared__ float tile[32][33];
    int ji = 0;
#pragma unroll
    for (int i = 1; i < 7; ++i) if (bid >= jobs.j[i].blk0) ji = i;
    const float* W  = jobs.j[ji].W;
    bf16*        Wt = jobs.j[ji].Wt;
    const int K = jobs.j[ji].K, N = jobs.j[ji].N;
    const int rel = bid - jobs.j[ji].blk0;
    const int nb = N >> 5;
    const int n0 = (rel % nb) * 32, k0 = (rel / nb) * 32;
    const int tx = threadIdx.x & 31, ty = threadIdx.x >> 5;   // 32 x 8
#pragma unroll
    for (int i = 0; i < 32; i += 8)
        tile[ty + i][tx] = W[(size_t)(k0 + ty + i) * N + n0 + tx];
    __syncthreads();
#pragma unroll
    for (int i = 0; i < 32; i += 8)
        Wt[(size_t)(n0 + ty + i) * K + k0 + tx] = (bf16)tile[tx][ty + i];
}

// ---------------------------------------------------------------------------
// depthwise conv (k=3, zero pad) along L + residual + LayerNorm.
// ---------------------------------------------------------------------------
__global__ __launch_bounds__(256) void cpe_ln_k(
    const float* __restrict__ xin, const float* __restrict__ cw,
    const float* __restrict__ cb, const float* __restrict__ g,
    const float* __restrict__ bb, float* __restrict__ xres,
    bf16* __restrict__ xln)
{
    const int token = blockIdx.x;
    const int l = token & (L_ - 1);
    const int tid = threadIdx.x;
    const float* row = xin + (size_t)token * C_;
    float v[2]; float s = 0.f, s2 = 0.f;
#pragma unroll
    for (int i = 0; i < 2; ++i) {
        const int c = tid + i * 256;
        float x0 = row[c];
        float xm = (l > 0)      ? row[c - C_] : 0.f;
        float xp = (l < L_ - 1) ? row[c + C_] : 0.f;
        float t = x0 + xm * cw[3*c] + x0 * cw[3*c+1] + xp * cw[3*c+2] + cb[c];
        v[i] = t; s += t; s2 += t * t;
    }
#pragma unroll
    for (int off = 32; off; off >>= 1) { s += __shfl_down(s, off); s2 += __shfl_down(s2, off); }
    __shared__ float rs[4], rs2[4];
    if ((tid & 63) == 0) { rs[tid >> 6] = s; rs2[tid >> 6] = s2; }
    __syncthreads();
    s  = rs[0] + rs[1] + rs[2] + rs[3];
    s2 = rs2[0] + rs2[1] + rs2[2] + rs2[3];
    const float mu = s * (1.f / C_);
    const float rstd = rsqrtf(s2 * (1.f / C_) - mu * mu + 1e-5f);
    float* orow = xres + (size_t)token * C_;
    bf16*  lrow = xln  + (size_t)token * C_;
#pragma unroll
    for (int i = 0; i < 2; ++i) {
        const int c = tid + i * 256;
        orow[c] = v[i];
        lrow[c] = (bf16)((v[i] - mu) * rstd * g[c] + bb[c]);
    }
}

// ---------------------------------------------------------------------------
// dwc conv over the (b,c,l)-reinterpreted flat buffer + SiLU. x8 vectorized:
// 8-aligned runs never cross a 2048-length channel run, so one bf16x8 center
// load + 2 scalar edge loads cover the 3-tap window.
// ---------------------------------------------------------------------------
__global__ __launch_bounds__(256) void dwc_silu_k(
    const bf16* __restrict__ Y, const float* __restrict__ w,
    const float* __restrict__ b, bf16* __restrict__ xp)
{
    const size_t idx = ((size_t)blockIdx.x * 256 + threadIdx.x) * 8;
    const int m = (int)(idx & (size_t)(L_ * C_ - 1));
    const int ch = m >> 11;          // m / 2048
    const int pos = m & (L_ - 1);    // multiple of 8
    const bf16x8 c = *(const bf16x8*)(Y + idx);
    const float left  = (pos > 0)      ? (float)Y[idx - 1] : 0.f;
    const float right = (pos + 8 < L_) ? (float)Y[idx + 8] : 0.f;
    const float w0 = w[3*ch], w1 = w[3*ch+1], w2 = w[3*ch+2], bc = b[ch];
    bf16x8 o;
#pragma unroll
    for (int j = 0; j < 8; ++j) {
        const float x0 = (float)c[j];
        const float xm = j ? (float)c[j-1] : left;
        const float xq = (j < 7) ? (float)c[j+1] : right;
        o[j] = (bf16)siluf(xm * w0 + x0 * w1 + xq * w2 + bc);
    }
    *(bf16x8*)(xp + idx) = o;
}

// ---------------------------------------------------------------------------
// ksum[b, c] = sum_n k[b,n,c] from kvbT rows (c-major): contiguous reduction.
// ---------------------------------------------------------------------------
__global__ __launch_bounds__(256) void ksum_k(
    const bf16* __restrict__ kvbT, float* __restrict__ ksum)
{
    const int c = blockIdx.x;
    const int wave = threadIdx.x >> 6, lane = threadIdx.x & 63;
#pragma unroll
    for (int i = 0; i < 2; ++i) {
        const int b = wave + i * 4;
        const bf16* src = kvbT + (size_t)c * M_ + b * L_ + lane * 32;
        float s = 0.f;
#pragma unroll
        for (int u = 0; u < 4; ++u) {
            bf16x8 v = *(const bf16x8*)(src + u * 8);
#pragma unroll
            for (int j = 0; j < 8; ++j) s += (float)v[j];
        }
#pragma unroll
        for (int o = 32; o; o >>= 1) s += __shfl_down(s, o);
        if (lane == 0) ksum[b * C_ + c] = s;
    }
}

// ---------------------------------------------------------------------------
// kvpart[split][b,h,e,d] = sum_{n in split} v[b,n,h,e] * k[b,n,h,d]
// via MFMA (transposed layout [e][d]); plain stores, no atomics.
// ---------------------------------------------------------------------------
__global__ __launch_bounds__(256) void kvmat_mfma_k(
    const bf16* __restrict__ kvbT, float* __restrict__ kvpart)
{
    const int bh = blockIdx.x, b = bh >> 3, h = bh & 7;
    const int tid = threadIdx.x;
    const int wave = tid >> 6, lane = tid & 63;
    const int l16 = lane & 15, quad = lane >> 4;
    __shared__ bf16 As[64 * 72];   // vT chunk: [e][n]
    __shared__ bf16 Bs[64 * 72];   // kT chunk: [d][n]
    const int r = tid >> 2;              // 0..63: LDS row
    const int cseg = (tid & 3) * 16;     // 16 bf16 per thread
    const size_t kRow = (size_t)(h * 64 + r) * M_;
    const size_t vRow = (size_t)(512 + h * 64 + r) * M_;

    f32x4 acc[4];
    const f32x4 z4 = { 0.f, 0.f, 0.f, 0.f };
#pragma unroll
    for (int ni = 0; ni < 4; ++ni) acc[ni] = z4;

    for (int it = 0; it < 8; ++it) {
        const size_t colBase = (size_t)b * L_ + blockIdx.y * 512 + it * 64;
        {
            const bf16* ga = kvbT + vRow + colBase + cseg;   // A = v
            const bf16* gb = kvbT + kRow + colBase + cseg;   // B = k
            *(uint4*)&As[r * 72 + cseg]     = *(const uint4*)ga;
            *(uint4*)&As[r * 72 + cseg + 8] = *(const uint4*)(ga + 8);
            *(uint4*)&Bs[r * 72 + cseg]     = *(const uint4*)gb;
            *(uint4*)&Bs[r * 72 + cseg + 8] = *(const uint4*)(gb + 8);
        }
        __syncthreads();
#pragma unroll
        for (int kk = 0; kk < 64; kk += 32) {
            bf16x8 af = *(const bf16x8*)(&As[(wave * 16 + l16) * 72 + kk + quad * 8]);
#pragma unroll
            for (int ni = 0; ni < 4; ++ni) {
                bf16x8 bfr = *(const bf16x8*)(&Bs[(ni * 16 + l16) * 72 + kk + quad * 8]);
                acc[ni] = __builtin_amdgcn_mfma_f32_16x16x32_bf16(af, bfr, acc[ni], 0, 0, 0);
            }
        }
        __syncthreads();
    }
    float* dst = kvpart + (size_t)blockIdx.y * 262144 + (size_t)bh * 4096;  // [e][d]
#pragma unroll
    for (int ni = 0; ni < 4; ++ni)
#pragma unroll
        for (int rr = 0; rr < 4; ++rr)
            dst[(wave * 16 + quad * 4 + rr) * 64 + ni * 16 + l16] = acc[ni][rr];
}

// sum 4 partials, scale by 1/L, convert to bf16 (262144 elems)
__global__ __launch_bounds__(256) void kvconv_k(
    const float* __restrict__ p, bf16* __restrict__ out)
{
    int i = blockIdx.x * 256 + threadIdx.x;
    float s = p[i] + p[i + 262144] + p[i + 2 * 262144] + p[i + 3 * 262144];
    out[i] = (bf16)(s * (1.f / (float)L_));
}

// ---------------------------------------------------------------------------
// MFMA attention: per block (bh, 64-token tile); per wave 16 tokens.
// R14: V-halo tile staged coalesced into LDS (Vs); lepe epilogue reads LDS
// instead of ~22 scattered scalar global loads per lane (V rows 32KB apart).
// Vs cols [0,64) = tokens n0..n0+63; col 64 = n0-1 (or 0); col 65 = n0+64
// (or 0). Stride 72 (144B): 16B-aligned chunks, 4-bank row stride (2-way).
// ---------------------------------------------------------------------------
__global__ __launch_bounds__(256) void attn_mfma_k(
    const bf16* __restrict__ q, const bf16* __restrict__ kvbT,
    const bf16* __restrict__ kvmatT, const float* __restrict__ ksum,
    const float* __restrict__ lw, const float* __restrict__ lb,
    const bf16* __restrict__ act_res, bf16* __restrict__ xa_mul)
{
    const int bh = blockIdx.x, b = bh >> 3, h = bh & 7;
    const int n0 = blockIdx.y * 64;
    const int tid = threadIdx.x;
    const int wave = tid >> 6, lane = tid & 63;
    const int l16 = lane & 15, quad = lane >> 4;

    __shared__ bf16 kvT[64 * 72];   // [e][d], stride 72 -> 2-way only
    __shared__ bf16 Vs[64 * 72];    // [e][token-in-tile] + halo cols 64/65
    __shared__ bf16 kmS[64];

    const bf16* vbase = kvbT + (size_t)(512 + h * 64) * M_ + (size_t)b * L_;

#pragma unroll
    for (int i = 0; i < 2; ++i) {
        const int idx = i * 256 + tid;               // 512 chunks of 8
        const int row = idx >> 3, col = (idx & 7) * 8;
        *(bf16x8*)&kvT[row * 72 + col] =
            *(const bf16x8*)&kvmatT[(size_t)bh * 4096 + idx * 8];
        *(bf16x8*)&Vs[row * 72 + col] =
            *(const bf16x8*)(vbase + (size_t)row * M_ + n0 + col);
    }
    if (tid < 64) {
        Vs[tid * 72 + 64] = (n0 > 0) ? vbase[(size_t)tid * M_ + n0 - 1] : (bf16)0.f;
        kmS[tid] = (bf16)(ksum[b * C_ + h * 64 + tid] * (1.f / (float)L_));
    } else if (tid < 128) {
        const int r2 = tid - 64;
        Vs[r2 * 72 + 65] = (n0 + 64 < L_) ? vbase[(size_t)r2 * M_ + n0 + 64] : (bf16)0.f;
    }
    __syncthreads();

    // A-frags: 16 q-rows direct from global.
    const int tok = n0 + wave * 16;
    const bf16* qbase = q + ((size_t)b * L_ + tok) * C_ + h * 64;
    const bf16x8 af0 = *(const bf16x8*)(qbase + (size_t)l16 * C_ + quad * 8);
    const bf16x8 af1 = *(const bf16x8*)(qbase + (size_t)l16 * C_ + 32 + quad * 8);

    // z-dot: B-tile col0 = k_mean
    const bf16x8 z8 = { bf16(0.f), bf16(0.f), bf16(0.f), bf16(0.f),
                        bf16(0.f), bf16(0.f), bf16(0.f), bf16(0.f) };
    const bf16x8 km0 = *(const bf16x8*)&kmS[quad * 8];
    const bf16x8 km1 = *(const bf16x8*)&kmS[32 + quad * 8];
    const bf16x8 b20 = (l16 == 0) ? km0 : z8;
    const bf16x8 b21 = (l16 == 0) ? km1 : z8;
    f32x4 zd = { 0.f, 0.f, 0.f, 0.f };
    zd = __builtin_amdgcn_mfma_f32_16x16x32_bf16(af0, b20, zd, 0, 0, 0);
    zd = __builtin_amdgcn_mfma_f32_16x16x32_bf16(af1, b21, zd, 0, 0, 0);
    float zr[4];
#pragma unroll
    for (int r = 0; r < 4; ++r)
        zr[r] = fastrcp(__shfl(zd[r], (lane & 48)) + 1e-6f);

    // q @ kvmatT^T
    f32x4 acc[4];
    const f32x4 zf4 = { 0.f, 0.f, 0.f, 0.f };
#pragma unroll
    for (int ni = 0; ni < 4; ++ni) acc[ni] = zf4;
#pragma unroll
    for (int ni = 0; ni < 4; ++ni) {
        const bf16x8 b0 = *(const bf16x8*)&kvT[(ni * 16 + l16) * 72 + quad * 8];
        const bf16x8 b1 = *(const bf16x8*)&kvT[(ni * 16 + l16) * 72 + 32 + quad * 8];
        acc[ni] = __builtin_amdgcn_mfma_f32_16x16x32_bf16(af0, b0, acc[ni], 0, 0, 0);
        acc[ni] = __builtin_amdgcn_mfma_f32_16x16x32_bf16(af1, b1, acc[ni], 0, 0, 0);
    }

    // epilogue: lane holds (token = tok+quad*4+r, e = ni*16+l16).
    // lepe taps from Vs: same values as global reads, identical FLOP order.
#pragma unroll
    for (int ni = 0; ni < 4; ++ni) {
        const int e = ni * 16 + l16;
        const int c = h * 64 + e;
        const float w0 = lw[3*c], w1 = lw[3*c+1], w2 = lw[3*c+2], lbc = lb[c];
        const bf16* vr = &Vs[e * 72];
#pragma unroll
        for (int r = 0; r < 4; ++r) {
            const int n = tok + quad * 4 + r;
            const int cb = wave * 16 + quad * 4 + r;   // n - n0, in [0,64)
            const float v0 = (float)vr[cb];
            const float vm = (float)((cb > 0)  ? vr[cb - 1] : vr[64]);
            const float vp = (float)((cb < 63) ? vr[cb + 1] : vr[65]);
            const float lepe = vm * w0 + v0 * w1 + vp * w2 + lbc;
            const float xa = acc[ni][r] * zr[r] + lepe;
            const size_t off = ((size_t)b * L_ + n) * C_ + c;
            xa_mul[off] = (bf16)(xa * (float)act_res[off]);
        }
    }
}

// ---------------------------------------------------------------------------
// bf16 MFMA GEMM, m97 structure + XOR-swizzled LDS tiles (128x128, 4 waves).
// Kept for N=512 shapes (q, out-proj, fc2).
// R11 epilogue: wide-store via wave-local LDS transpose (reuses As/Bs LDS
// after the final __syncthreads; per-wave disjoint scratch; no extra sync).
// EPI: 2 elu+1->bf16, 4 gelu->bf16, 5 +res->f32, 7 kvT (row<512 elu)->bf16,
//      8 fused act/in: col<512 silu->outp, else plain->outp2
// ---------------------------------------------------------------------------
template <int EPI>
__global__ __launch_bounds__(256) void gemm_bt(
    const bf16* __restrict__ A, const bf16* __restrict__ Bt,
    const float* __restrict__ bias, const float* __restrict__ res,
    void* __restrict__ outp, void* __restrict__ outp2, int K, int N)
{
    __shared__ bf16 smem[2 * 128 * 64];   // As | Bs (8192 each)
    bf16* As = smem;
    bf16* Bs = smem + 8192;
    const int tid = threadIdx.x;
    const int wave = tid >> 6, lane = tid & 63;
    const int wm = (wave & 1) * 64, wn = (wave >> 1) * 64;
    const int l16 = lane & 15, quad = lane >> 4;
    const size_t tileM = (size_t)blockIdx.x * 128;
    const size_t tileN = (size_t)blockIdx.y * 128;

    const int lrow = lane >> 3;
    const int lcol = (((lane & 7) ^ (lrow & 7))) * 8;   // swizzled source col
    const int swz  = l16 & 7;                           // read-side XOR

    const f32x4 z4 = { 0.f, 0.f, 0.f, 0.f };
    f32x4 acc[4][4];
#pragma unroll
    for (int mi = 0; mi < 4; ++mi)
#pragma unroll
        for (int ni = 0; ni < 4; ++ni) acc[mi][ni] = z4;

    for (int k0 = 0; k0 < K; k0 += 64) {
#pragma unroll
        for (int it = 0; it < 4; ++it) {
            const int rg = it * 32 + wave * 8;           // wave-uniform (mult of 8)
            load_lds16(A  + (tileM + rg + lrow) * (size_t)K + k0 + lcol, As + rg * 64);
            load_lds16(Bt + (tileN + rg + lrow) * (size_t)K + k0 + lcol, Bs + rg * 64);
        }
        __syncthreads();
#pragma unroll
        for (int kk = 0; kk < 64; kk += 32) {
            bf16x8 af[4], bfr[4];
#pragma unroll
            for (int mi = 0; mi < 4; ++mi)
                af[mi] = *(const bf16x8*)(&As[(wm + mi * 16 + l16) * 64
                                              + ((((kk >> 3) + quad) ^ swz) * 8)]);
#pragma unroll
            for (int ni = 0; ni < 4; ++ni)
                bfr[ni] = *(const bf16x8*)(&Bs[(wn + ni * 16 + l16) * 64
                                               + ((((kk >> 3) + quad) ^ swz) * 8)]);
#pragma unroll
            for (int mi = 0; mi < 4; ++mi)
#pragma unroll
                for (int ni = 0; ni < 4; ++ni)
                    acc[mi][ni] = __builtin_amdgcn_mfma_f32_16x16x32_bf16(
                        af[mi], bfr[ni], acc[mi][ni], 0, 0, 0);
        }
        __syncthreads();
    }

    // ---- epilogue: wave-local LDS transpose -> coalesced wide stores.
    const int rrow = lane >> 2;           // 0..15
    const int rseg = (lane & 3) * 16;     // 0/16/32/48

    if (EPI == 5 || EPI == 7) {
        float* sc = (float*)smem + wave * 1088;     // 16 rows x 68 f32
#pragma unroll
        for (int mi = 0; mi < 4; ++mi) {
#pragma unroll
            for (int ni = 0; ni < 4; ++ni)
#pragma unroll
                for (int r = 0; r < 4; ++r)
                    sc[(quad * 4 + r) * 68 + ni * 16 + l16] = acc[mi][ni][r];
            __builtin_amdgcn_sched_barrier(0);
            const size_t rowg = tileM + wm + mi * 16 + rrow;
            const int    colg = (int)tileN + wn + rseg;
            if (EPI == 5) {
                const float* rp = res + rowg * (size_t)N + colg;
                float*       op = (float*)outp + rowg * (size_t)N + colg;
#pragma unroll
                for (int u = 0; u < 4; ++u) {
                    f32x4 v = *(f32x4*)&sc[rrow * 68 + rseg + u * 4];
                    f32x4 rv = *(const f32x4*)(rp + u * 4);
                    f32x4 bv = *(const f32x4*)(bias + colg + u * 4);
                    f32x4 o;
#pragma unroll
                    for (int j = 0; j < 4; ++j) o[j] = v[j] + bv[j] + rv[j];
                    *(f32x4*)(op + u * 4) = o;
                }
            } else {  // EPI 7
                const float bv = bias[(int)rowg];
                const bool k_side = (rowg < 512);
                bf16* op = (bf16*)outp + rowg * (size_t)N + colg;
#pragma unroll
                for (int hh = 0; hh < 2; ++hh) {
                    bf16x8 o8;
#pragma unroll
                    for (int j = 0; j < 8; ++j) {
                        float x = sc[rrow * 68 + rseg + hh * 8 + j] + bv;
                        o8[j] = (bf16)(k_side ? elu1f(x) : x);
                    }
                    *(bf16x8*)(op + hh * 8) = o8;
                }
            }
            __builtin_amdgcn_sched_barrier(0);
        }
    } else {  // EPI 2, 4, 8: bf16 scratch, write-side bias+activation
        bf16* sc = (bf16*)smem + wave * 1152;       // 16 rows x 72 bf16
        float addc[4];
        bool  act_on[4];
#pragma unroll
        for (int ni = 0; ni < 4; ++ni) {
            const int cw = (int)tileN + wn + ni * 16 + l16;
            if (EPI == 8) {
                act_on[ni] = (cw < 512);
                addc[ni] = act_on[ni] ? bias[cw] : res[cw - 512];
            } else { addc[ni] = bias[cw]; act_on[ni] = true; }
        }
#pragma unroll
        for (int mi = 0; mi < 4; ++mi) {
#pragma unroll
            for (int ni = 0; ni < 4; ++ni)
#pragma unroll
                for (int r = 0; r < 4; ++r) {
                    float x = acc[mi][ni][r] + addc[ni];
                    float y;
                    if (EPI == 2)      y = elu1f(x);
                    else if (EPI == 4) y = geluf(x);
                    else               y = act_on[ni] ? siluf(x) : x;
                    sc[(quad * 4 + r) * 72 + ni * 16 + l16] = (bf16)y;
                }
            __builtin_amdgcn_sched_barrier(0);
            const size_t rowg = tileM + wm + mi * 16 + rrow;
            const int    colg = (int)tileN + wn + rseg;
            bf16x8 o0 = *(bf16x8*)&sc[rrow * 72 + rseg];
            bf16x8 o1 = *(bf16x8*)&sc[rrow * 72 + rseg + 8];
            if (EPI == 8) {
                const size_t orow = rowg * (size_t)512;
                bf16* dst = (colg < 512) ? ((bf16*)outp  + orow + colg)
                                         : ((bf16*)outp2 + orow + colg - 512);
                *(bf16x8*)dst = o0; *(bf16x8*)(dst + 8) = o1;
            } else {
                bf16* dst = (bf16*)outp + rowg * (size_t)N + colg;
                *(bf16x8*)dst = o0; *(bf16x8*)(dst + 8) = o1;
            }
            __builtin_amdgcn_sched_barrier(0);
        }
    }
}

// ---------------------------------------------------------------------------
// 256x256 8-wave (2M x 4N) deep-pipelined bf16 GEMM (R9 4-phase core). BK=64,
// double-buffered 128KB LDS, 4 phases per K-tile:
//   ph0: read A-half0(8) + B n0-1(4); stage next-tile loads 0-3;  MFMA m0-3 x n0-1
//   ph1: read B n2-3(4);              stage next-tile loads 4-7;  MFMA m0-3 x n2-3
//   ph2: read A-half1(8);                                         MFMA m4-7 x n0-1
//   ph3: vmcnt(0);                                                MFMA m4-7 x n2-3
// Each phase: raw s_barrier / lgkmcnt(0) / sched_barrier(0) / setprio(1) MFMA.
// R11 epilogue: wide-store via wave-local LDS transpose.
// Requires: M % 256 == 0, N % 256 == 0, K % 64 == 0.
// ---------------------------------------------------------------------------
template <int EPI>
__global__ __launch_bounds__(512, 2) void gemm8(
    const bf16* __restrict__ A, const bf16* __restrict__ Bt,
    const float* __restrict__ bias, const float* __restrict__ res,
    void* __restrict__ outp, void* __restrict__ outp2, int K, int N)
{
    __shared__ bf16 smem[4 * 256 * 64];   // As[2] (32768) | Bs[2] (32768)
    bf16* const AsBase = smem;
    bf16* const BsBase = smem + 32768;
    const int tid  = threadIdx.x;
    const int wave = tid >> 6, lane = tid & 63;
    const int wrow = wave >> 2, wcol = wave & 3;       // 2 x 4 wave grid
    const int l16 = lane & 15, quad = lane >> 4;
    const int lrow = lane >> 3;                        // 0..7
    const int lcol = ((lane & 7) ^ lrow) * 8;          // swizzled source chunk
    const int swz  = l16 & 7;                          // read-side XOR
    const size_t tileM = (size_t)blockIdx.x * 256;
    const size_t tileN = (size_t)blockIdx.y * 256;

    // staging bases: wave w, load j covers rows j*64 + w*8 .. +7
    const bf16* aBase = A  + (tileM + wave * 8 + lrow) * (size_t)K + lcol;
    const bf16* bBase = Bt + (tileN + wave * 8 + lrow) * (size_t)K + lcol;
    const int ldsRow0 = wave * 8;

    f32x4 acc[8][4];
    const f32x4 z4 = { 0.f, 0.f, 0.f, 0.f };
#pragma unroll
    for (int mi = 0; mi < 8; ++mi)
#pragma unroll
        for (int ni = 0; ni < 4; ++ni) acc[mi][ni] = z4;

    // prologue: stage K-tile 0 into buf 0 (8 loads/thread), drain, barrier
#pragma unroll
    for (int j = 0; j < 4; ++j) {
        load_lds16(aBase + (size_t)(j * 64) * K, AsBase + (j * 64 + ldsRow0) * 64);
        load_lds16(bBase + (size_t)(j * 64) * K, BsBase + (j * 64 + ldsRow0) * 64);
    }
    asm volatile("s_waitcnt vmcnt(0)" ::: "memory");
    __builtin_amdgcn_s_barrier();

    const int T = K >> 6;
    int cur = 0;
    for (int t = 0; t < T; ++t) {
        const int nxt = cur ^ 1;
        const bool pf = (t + 1 < T);
        const int kc = (t + 1) << 6;                   // next tile's K offset
        const bf16* as = AsBase + cur * 16384;
        const bf16* bs = BsBase + cur * 16384;
        bf16* asn = AsBase + nxt * 16384;
        bf16* bsn = BsBase + nxt * 16384;
        bf16x8 af[4][2], bfr[4][2];

        // ---------------- phase 0: A-half0 + B(n0,n1); stage loads 0-3 ----
#pragma unroll
        for (int j = 0; j < 4; ++j)
#pragma unroll
            for (int kh = 0; kh < 2; ++kh)
                af[j][kh] = *(const bf16x8*)&as[(wrow * 128 + j * 16 + l16) * 64
                                               + (((kh * 4 + quad) ^ swz) * 8)];
#pragma unroll
        for (int ni = 0; ni < 2; ++ni)
#pragma unroll
            for (int kh = 0; kh < 2; ++kh)
                bfr[ni][kh] = *(const bf16x8*)&bs[(wcol * 64 + ni * 16 + l16) * 64
                                                  + (((kh * 4 + quad) ^ swz) * 8)];
        if (pf) {
#pragma unroll
            for (int j = 0; j < 2; ++j) {
                load_lds16(aBase + (size_t)(j * 64) * K + kc, asn + (j * 64 + ldsRow0) * 64);
                load_lds16(bBase + (size_t)(j * 64) * K + kc, bsn + (j * 64 + ldsRow0) * 64);
            }
        }
        __builtin_amdgcn_s_barrier();
        asm volatile("s_waitcnt lgkmcnt(0)" ::: "memory");
        __builtin_amdgcn_sched_barrier(0);
        __builtin_amdgcn_s_setprio(1);
#pragma unroll
        for (int j = 0; j < 4; ++j)
#pragma unroll
            for (int ni = 0; ni < 2; ++ni)
#pragma unroll
                for (int kh = 0; kh < 2; ++kh)
                    acc[j][ni] = __builtin_amdgcn_mfma_f32_16x16x32_bf16(
                        af[j][kh], bfr[ni][kh], acc[j][ni], 0, 0, 0);
        __builtin_amdgcn_s_setprio(0);
        __builtin_amdgcn_s_barrier();

        // ---------------- phase 1: B(n2,n3); stage loads 4-7 --------------
#pragma unroll
        for (int ni = 2; ni < 4; ++ni)
#pragma unroll
            for (int kh = 0; kh < 2; ++kh)
                bfr[ni][kh] = *(const bf16x8*)&bs[(wcol * 64 + ni * 16 + l16) * 64
                                                  + (((kh * 4 + quad) ^ swz) * 8)];
        if (pf) {
#pragma unroll
            for (int j = 2; j < 4; ++j) {
                load_lds16(aBase + (size_t)(j * 64) * K + kc, asn + (j * 64 + ldsRow0) * 64);
                load_lds16(bBase + (size_t)(j * 64) * K + kc, bsn + (j * 64 + ldsRow0) * 64);
            }
        }
        __builtin_amdgcn_s_barrier();
        asm volatile("s_waitcnt lgkmcnt(0)" ::: "memory");
        __builtin_amdgcn_sched_barrier(0);
        __builtin_amdgcn_s_setprio(1);
#pragma unroll
        for (int j = 0; j < 4; ++j)
#pragma unroll
            for (int ni = 2; ni < 4; ++ni)
#pragma unroll
                for (int kh = 0; kh < 2; ++kh)
                    acc[j][ni] = __builtin_amdgcn_mfma_f32_16x16x32_bf16(
                        af[j][kh], bfr[ni][kh], acc[j][ni], 0, 0, 0);
        __builtin_amdgcn_s_setprio(0);
        __builtin_amdgcn_s_barrier();

        // ---------------- phase 2: A-half1 --------------------------------
#pragma unroll
        for (int j = 0; j < 4; ++j)
#pragma unroll
            for (int kh = 0; kh < 2; ++kh)
                af[j][kh] = *(const bf16x8*)&as[(wrow * 128 + 64 + j * 16 + l16) * 64
                                               + (((kh * 4 + quad) ^ swz) * 8)];
        __builtin_amdgcn_s_barrier();
        asm volatile("s_waitcnt lgkmcnt(0)" ::: "memory");
        __builtin_amdgcn_sched_barrier(0);
        __builtin_amdgcn_s_setprio(1);
#pragma unroll
        for (int j = 0; j < 4; ++j)
#pragma unroll
            for (int ni = 0; ni < 2; ++ni)
#pragma unroll
                for (int kh = 0; kh < 2; ++kh)
                    acc[4 + j][ni] = __builtin_amdgcn_mfma_f32_16x16x32_bf16(
                        af[j][kh], bfr[ni][kh], acc[4 + j][ni], 0, 0, 0);
        __builtin_amdgcn_s_setprio(0);
        __builtin_amdgcn_s_barrier();

        // ---------------- phase 3: wait next tile; last quadrant ----------
        if (pf) asm volatile("s_waitcnt vmcnt(0)" ::: "memory");
        __builtin_amdgcn_s_barrier();
        __builtin_amdgcn_sched_barrier(0);
        __builtin_amdgcn_s_setprio(1);
#pragma unroll
        for (int j = 0; j < 4; ++j)
#pragma unroll
            for (int ni = 2; ni < 4; ++ni)
#pragma unroll
                for (int kh = 0; kh < 2; ++kh)
                    acc[4 + j][ni] = __builtin_amdgcn_mfma_f32_16x16x32_bf16(
                        af[j][kh], bfr[ni][kh], acc[4 + j][ni], 0, 0, 0);
        __builtin_amdgcn_s_setprio(0);
        __builtin_amdgcn_s_barrier();

        cur = nxt;
    }

    // ---- epilogue: wave-local LDS transpose -> coalesced wide stores.
    // Loop ended with s_barrier: all waves done reading As/Bs; vmcnt drained.
    const int rrow = lane >> 2;           // 0..15
    const int rseg = (lane & 3) * 16;     // 0/16/32/48

    if (EPI == 5 || EPI == 7) {
        float* sc = (float*)smem + wave * 1088;     // 16 rows x 68 f32
#pragma unroll
        for (int mi = 0; mi < 8; ++mi) {
#pragma unroll
            for (int ni = 0; ni < 4; ++ni)
#pragma unroll
                for (int r = 0; r < 4; ++r)
                    sc[(quad * 4 + r) * 68 + ni * 16 + l16] = acc[mi][ni][r];
            __builtin_amdgcn_sched_barrier(0);
            const size_t rowg = tileM + wrow * 128 + mi * 16 + rrow;
            const int    colg = (int)tileN + wcol * 64 + rseg;
            if (EPI == 5) {
                const float* rp = res + rowg * (size_t)N + colg;
                float*       op = (float*)outp + rowg * (size_t)N + colg;
#pragma unroll
                for (int u = 0; u < 4; ++u) {
                    f32x4 v = *(f32x4*)&sc[rrow * 68 + rseg + u * 4];
                    f32x4 rv = *(const f32x4*)(rp + u * 4);
                    f32x4 bv = *(const f32x4*)(bias + colg + u * 4);
                    f32x4 o;
#pragma unroll
                    for (int j = 0; j < 4; ++j) o[j] = v[j] + bv[j] + rv[j];
                    *(f32x4*)(op + u * 4) = o;
                }
            } else {  // EPI 7
                const float bv = bias[(int)rowg];
                const bool k_side = (rowg < 512);
                bf16* op = (bf16*)outp + rowg * (size_t)N + colg;
#pragma unroll
                for (int hh = 0; hh < 2; ++hh) {
                    bf16x8 o8;
#pragma unroll
                    for (int j = 0; j < 8; ++j) {
                        float x = sc[rrow * 68 + rseg + hh * 8 + j] + bv;
                        o8[j] = (bf16)(k_side ? elu1f(x) : x);
                    }
                    *(bf16x8*)(op + hh * 8) = o8;
                }
            }
            __builtin_amdgcn_sched_barrier(0);
        }
    } else {  // EPI 2, 4, 8: bf16 scratch, write-side bias+activation
        bf16* sc = (bf16*)smem + wave * 1152;       // 16 rows x 72 bf16
        float addc[4];
        bool  act_on[4];
#pragma unroll
        for (int ni = 0; ni < 4; ++ni) {
            const int cw = (int)tileN + wcol * 64 + ni * 16 + l16;
            if (EPI == 8) {
                act_on[ni] = (cw < 512);
                addc[ni] = act_on[ni] ? bias[cw] : res[cw - 512];
            } else { addc[ni] = bias[cw]; act_on[ni] = true; }
        }
#pragma unroll
        for (int mi = 0; mi < 8; ++mi) {
#pragma unroll
            for (int ni = 0; ni < 4; ++ni)
#pragma unroll
                for (int r = 0; r < 4; ++r) {
                    float x = acc[mi][ni][r] + addc[ni];
                    float y;
                    if (EPI == 2)      y = elu1f(x);
                    else if (EPI == 4) y = geluf(x);
                    else               y = act_on[ni] ? siluf(x) : x;
                    sc[(quad * 4 + r) * 72 + ni * 16 + l16] = (bf16)y;
                }
            __builtin_amdgcn_sched_barrier(0);
            const size_t rowg = tileM + wrow * 128 + mi * 16 + rrow;
            const int    colg = (int)tileN + wcol * 64 + rseg;
            bf16x8 o0 = *(bf16x8*)&sc[rrow * 72 + rseg];
            bf16x8 o1 = *(bf16x8*)&sc[rrow * 72 + rseg + 8];
            if (EPI == 8) {
                const size_t orow = rowg * (size_t)512;
                bf16* dst = (colg < 512) ? ((bf16*)outp  + orow + colg)
                                         : ((bf16*)outp2 + orow + colg - 512);
                *(bf16x8*)dst = o0; *(bf16x8*)(dst + 8) = o1;
            } else {
                bf16* dst = (bf16*)outp + rowg * (size_t)N + colg;
                *(bf16x8*)dst = o0; *(bf16x8*)(dst + 8) = o1;
            }
            __builtin_amdgcn_sched_barrier(0);
        }
    }
}

// ---------------------------------------------------------------------------
// workspace layout (bytes) — total 125,845,504 (~120 MiB)
// ---------------------------------------------------------------------------
#define OFF_WT_ACTIN ((size_t)0)         // bf16 [1024][512] 1MB
#define OFF_WT_Q    ((size_t)1048576)
#define OFF_WT_KV   ((size_t)1572864)
#define OFF_WT_OUT  ((size_t)2621440)
#define OFF_WT_FC1  ((size_t)3145728)
#define OFF_WT_FC2  ((size_t)5242880)
#define OFF_XLN     ((size_t)7340032)    // bf16 16MB (kvbf, hln alias)
#define OFF_ACTRES  ((size_t)24117248)   // bf16 16MB (x3 aliases from here)
#define OFF_Y       ((size_t)40894464)   // bf16 16MB (qb aliases)
#define OFF_XP      ((size_t)57671680)   // bf16 16MB (kvpart, h1 alias from here)
#define OFF_KV      ((size_t)74448896)   // bf16 32MB  kvbT [1024][16384]
#define OFF_KSUM    ((size_t)108003328)  // f32 16KB
#define OFF_XAMUL   ((size_t)109068288)  // bf16 16MB  (xqb early, xamul late)
#define OFF_X3      ((size_t)24117248)   // f32 32MB over actres+Y (dead)
#define OFF_H1      ((size_t)57671680)   // bf16 64MB over xp+kv+xamul (dead)
#define WS_REQUIRED ((size_t)125845504)

extern "C" void kernel_launch(void* const* d_in, const int* in_sizes, int n_in,
                              void* d_out, int out_size, void* d_ws, size_t ws_size,
                              hipStream_t stream)
{
    const float* x_q    = (const float*)d_in[0];
    const float* x_kv   = (const float*)d_in[1];
    const float* cpe1_w = (const float*)d_in[2];
    const float* cpe1_b = (const float*)d_in[3];
    const float* n1_g   = (const float*)d_in[4];
    const float* n1_b   = (const float*)d_in[5];
    const float* in_w   = (const float*)d_in[6];
    const float* in_b   = (const float*)d_in[7];
    const float* act_w  = (const float*)d_in[8];
    const float* act_b  = (const float*)d_in[9];
    const float* dwc_w  = (const float*)d_in[10];
    const float* dwc_b  = (const float*)d_in[11];
    const float* q_w    = (const float*)d_in[12];
    const float* q_b    = (const float*)d_in[13];
    const float* kv_w   = (const float*)d_in[14];
    const float* kv_b   = (const float*)d_in[15];
    const float* lepe_w = (const float*)d_in[16];
    const float* lepe_b = (const float*)d_in[17];
    const float* out_w  = (const float*)d_in[18];
    const float* out_b  = (const float*)d_in[19];
    const float* cpe2_w = (const float*)d_in[20];
    const float* cpe2_b = (const float*)d_in[21];
    const float* n2_g   = (const float*)d_in[22];
    const float* n2_b   = (const float*)d_in[23];
    const float* fc1_w  = (const float*)d_in[24];
    const float* fc1_b  = (const float*)d_in[25];
    const float* fc2_w  = (const float*)d_in[26];
    const float* fc2_b  = (const float*)d_in[27];

    float* outf = (float*)d_out;

    if (ws_size < WS_REQUIRED) {
        zero_k<<<(out_size + 255) / 256, 256, 0, stream>>>(outf, out_size);
        ws_diag_k<<<1, 64, 0, stream>>>(outf, (float)ws_size);
        return;
    }

    char* ws = (char*)d_ws;
    bf16*  wt_actin = (bf16*)(ws + OFF_WT_ACTIN);
    bf16*  wt_q   = (bf16*)(ws + OFF_WT_Q);
    bf16*  wt_kv  = (bf16*)(ws + OFF_WT_KV);
    bf16*  wt_out = (bf16*)(ws + OFF_WT_OUT);
    bf16*  wt_fc1 = (bf16*)(ws + OFF_WT_FC1);
    bf16*  wt_fc2 = (bf16*)(ws + OFF_WT_FC2);
    bf16*  xln    = (bf16*)(ws + OFF_XLN);
    bf16*  kvbf   = (bf16*)(ws + OFF_XLN);      // alias: xln dead after act/in
    bf16*  hln    = (bf16*)(ws + OFF_XLN);      // alias: kvbf dead after attn
    bf16*  actres = (bf16*)(ws + OFF_ACTRES);
    bf16*  Y      = (bf16*)(ws + OFF_Y);
    bf16*  qb     = (bf16*)(ws + OFF_Y);        // alias: Y dead after dwc
    bf16*  xp     = (bf16*)(ws + OFF_XP);
    float* kvpart = (float*)(ws + OFF_XP);      // alias: xp dead after kv-gemm (4MB)
    bf16*  kvbT   = (bf16*)(ws + OFF_KV);       // [1024][16384]
    float* ksum   = (float*)(ws + OFF_KSUM);
    bf16*  xqb    = (bf16*)(ws + OFF_XAMUL);    // early use; dead before attn
    bf16*  xamul  = (bf16*)(ws + OFF_XAMUL);    // written by attn (after q-gemm)
    float* x3     = (float*)(ws + OFF_X3);      // alias
    bf16*  h1     = (bf16*)(ws + OFF_H1);       // alias

    // all weight transposes + x_q -> bf16 conversion, one launch
    TJobs jobs;
    jobs.j[0] = { act_w, wt_actin,             512,  512,    0 };
    jobs.j[1] = { in_w,  wt_actin + 512 * 512, 512,  512,  256 };
    jobs.j[2] = { q_w,   wt_q,                 512,  512,  512 };
    jobs.j[3] = { kv_w,  wt_kv,                512, 1024,  768 };
    jobs.j[4] = { out_w, wt_out,               512,  512, 1280 };
    jobs.j[5] = { fc1_w, wt_fc1,               512, 2048, 1536 };
    jobs.j[6] = { fc2_w, wt_fc2,              2048,  512, 2560 };
    transpose_all_k<<<11776, 256, 0, stream>>>(jobs, x_q, xqb);

    // cpe1 + LN1: shortcut (fp32) lives in d_out
    cpe_ln_k<<<M_, 256, 0, stream>>>(x_kv, cpe1_w, cpe1_b, n1_g, n1_b, outf, xln);

    // fused act gate + in-proj (one pass over xln), N=1024  [256x256 pipelined]
    gemm8<8><<<dim3(64, 4), 512, 0, stream>>>(xln, wt_actin, act_b, in_b, actres, Y, 512, 1024);

    // flat-reshape dwconv + silu -> xp (frees Y)
    dwc_silu_k<<<4096, 256, 0, stream>>>(Y, dwc_w, dwc_b, xp);

    // q = elu+1(xqb @ q_w) -> qb (@Y)
    gemm_bt<2><<<dim3(128, 4), 256, 0, stream>>>(xqb, wt_q, q_b, nullptr, qb, nullptr, 512, 512);

    // kvbT[c][token] = (xp @ kv_w)^T : roles swapped (A=wt_kv, Bt=xp)  [256x256]
    gemm8<7><<<dim3(4, 64), 512, 0, stream>>>(wt_kv, xp, kv_b, nullptr, kvbT, nullptr, 512, M_);

    // k_mean, kvmatT partials (MFMA, no atomics), reduce+bf16 convert
    ksum_k<<<C_, 256, 0, stream>>>(kvbT, ksum);
    kvmat_mfma_k<<<dim3(64, 4), 256, 0, stream>>>(kvbT, kvpart);
    kvconv_k<<<1024, 256, 0, stream>>>(kvpart, kvbf);

    // MFMA attention + lepe + gate multiply (xqb dead from here; xamul written)
    attn_mfma_k<<<dim3(64, 32), 256, 0, stream>>>(qb, kvbT, kvbf, ksum,
                                                  lepe_w, lepe_b, actres, xamul);

    // out-proj + shortcut residual, in-place on d_out
    gemm_bt<5><<<dim3(128, 4), 256, 0, stream>>>(xamul, wt_out, out_b, outf, outf, nullptr, 512, 512);

    // cpe2 + LN2: x2 (=d_out) -> x3 (fp32 ws) + hln (bf16)
    cpe_ln_k<<<M_, 256, 0, stream>>>(outf, cpe2_w, cpe2_b, n2_g, n2_b, x3, hln);

    // MLP: fc1 (gelu) [256x256 pipelined] -> fc2 (+x3) -> d_out
    gemm8<4><<<dim3(64, 8), 512, 0, stream>>>(hln, wt_fc1, fc1_b, nullptr, h1, nullptr, 512, 2048);
    gemm_bt<5><<<dim3(128, 4),  256, 0, stream>>>(h1,  wt_fc2, fc2_b, x3, outf, nullptr, 2048, 512);

    (void)in_sizes; (void)n_in; (void)out_size; (void)ws_size;
}

// Round 8
// 427.364 us; speedup vs baseline: 1.2593x; 1.0346x over previous
//
#include <hip/hip_runtime.h>
#include <cmath>

// ---------------------------------------------------------------------------
// MLLA block, B=8 L=2048 C=512 H=8 HD=64 MLP_H=2048, fp32 I/O, bf16 MFMA GEMMs
// R15: non-GEMM tail trim. (1) cpe_ln_k processes 2 tokens/block: halo rows
//      shared, 4 row-reads per block vs 6 (-33% reads); per-token math and
//      reduction order identical -> bit-exact. (2) ksum folded into the
//      kvconv launch (kvfin_k, blockIdx-partitioned) -> one less dispatch.
//      GEMMs + attn byte-identical to R14 (total 442.2us; fc1 56.3us stable).
// ---------------------------------------------------------------------------

typedef __bf16 bf16;
typedef __bf16 bf16x8 __attribute__((ext_vector_type(8)));
typedef __bf16 bf16x4 __attribute__((ext_vector_type(4)));
typedef float  f32x4  __attribute__((ext_vector_type(4)));

#define B_  8
#define L_  2048
#define C_  512
#define M_  (B_ * L_)          // 16384 tokens

__device__ __forceinline__ float fastrcp(float x) { return __builtin_amdgcn_rcpf(x); }

__device__ __forceinline__ float siluf(float x)
{
    return x * fastrcp(1.f + __expf(-x));
}
__device__ __forceinline__ float elu1f(float x) { return x > 0.f ? x + 1.f : __expf(x); }

// exact-GELU via Abramowitz-Stegun 7.1.25 erf (3-term, |eps| <= 2.5e-5)
__device__ __forceinline__ float geluf(float x)
{
    const float z = fabsf(x) * 0.70710678118654752f;
    const float t = fastrcp(__builtin_fmaf(z, 0.47047f, 1.f));
    const float poly = t * (0.3480242f + t * (-0.0958798f + t * 0.7478556f));
    const float erfz = __builtin_fmaf(-poly, __expf(-z * z), 1.f);
    const float hx = 0.5f * x;
    return __builtin_fmaf(hx, __builtin_copysignf(erfz, x), hx);
}

// global -> LDS direct DMA, 16B per lane. lds dest must be wave-uniform base;
// HW deposits lane i at base + i*16B.
__device__ __forceinline__ void load_lds16(const bf16* g, bf16* l)
{
    __builtin_amdgcn_global_load_lds(
        (const __attribute__((address_space(1))) void*)g,
        (__attribute__((address_space(3))) void*)l, 16, 0, 0);
}

// ---------------------------------------------------------------------------
__global__ __launch_bounds__(256) void zero_k(float* __restrict__ p, int n)
{
    int i = blockIdx.x * 256 + threadIdx.x;
    if (i < n) p[i] = 0.f;
}

__global__ __launch_bounds__(64) void ws_diag_k(float* __restrict__ out, float v)
{
    if (threadIdx.x == 0 && blockIdx.x == 0) out[0] = v;
}

// ---------------------------------------------------------------------------
// ALL weight transposes + x_q f32->bf16 conversion in ONE launch.
// Blocks [0, 3584): transpose jobs. Blocks [3584, 11776): x_q conversion.
// ---------------------------------------------------------------------------
struct TJob  { const float* W; bf16* Wt; int K; int N; int blk0; };
struct TJobs { TJob j[7]; };

__global__ __launch_bounds__(256) void transpose_all_k(
    TJobs jobs, const float* __restrict__ xq, bf16* __restrict__ xqb)
{
    const int bid = blockIdx.x;
    if (bid >= 3584) {
        const int i = (bid - 3584) * 256 + threadIdx.x;   // exactly M_*C_/4
        float4 v = ((const float4*)xq)[i];
        bf16x4 o = { (bf16)v.x, (bf16)v.y, (bf16)v.z, (bf16)v.w };
        ((bf16x4*)xqb)[i] = o;
        return;
    }
    __shared__ float tile[32][33];
    int ji = 0;
#pragma unroll
    for (int i = 1; i < 7; ++i) if (bid >= jobs.j[i].blk0) ji = i;
    const float* W  = jobs.j[ji].W;
    bf16*        Wt = jobs.j[ji].Wt;
    const int K = jobs.j[ji].K, N = jobs.j[ji].N;
    const int rel = bid - jobs.j[ji].blk0;
    const int nb = N >> 5;
    const int n0 = (rel % nb) * 32, k0 = (rel / nb) * 32;
    const int tx = threadIdx.x & 31, ty = threadIdx.x >> 5;   // 32 x 8
#pragma unroll
    for (int i = 0; i < 32; i += 8)
        tile[ty + i][tx] = W[(size_t)(k0 + ty + i) * N + n0 + tx];
    __syncthreads();
#pragma unroll
    for (int i = 0; i < 32; i += 8)
        Wt[(size_t)(n0 + ty + i) * K + k0 + tx] = (bf16)tile[tx][ty + i];
}

// ---------------------------------------------------------------------------
// depthwise conv (k=3, zero pad) along L + residual + LayerNorm.
// R15: 2 tokens per block (t0 = 2*blockIdx.x, t0+1). Shared halo rows: block
// reads rows t0-1..t0+2 (4) instead of 6 across two blocks. Per-token conv,
// per-thread partials, shuffle tree, and normalize are identical -> bit-exact.
// t0 is even so l0 = t0 & 2047 is even: row t0+1 always in-batch; token t0's
// xp always valid; token t0+1's xp valid iff l0+2 < L_.
// ---------------------------------------------------------------------------
__global__ __launch_bounds__(256) void cpe_ln_k(
    const float* __restrict__ xin, const float* __restrict__ cw,
    const float* __restrict__ cb, const float* __restrict__ g,
    const float* __restrict__ bb, float* __restrict__ xres,
    bf16* __restrict__ xln)
{
    const int t0 = blockIdx.x * 2;
    const int l0 = t0 & (L_ - 1);
    const int tid = threadIdx.x;
    const float* r0 = xin + (size_t)t0 * C_;
    float v[2][2];
    float s0 = 0.f, s20 = 0.f, s1 = 0.f, s21 = 0.f;
#pragma unroll
    for (int i = 0; i < 2; ++i) {
        const int c = tid + i * 256;
        const float w0 = cw[3*c], w1 = cw[3*c+1], w2 = cw[3*c+2], cbc = cb[c];
        const float xa = (l0 > 0)        ? r0[c - C_]     : 0.f;  // row t0-1
        const float xb = r0[c];                                   // row t0
        const float xc = r0[c + C_];                              // row t0+1
        const float xd = (l0 + 2 < L_)   ? r0[c + 2 * C_] : 0.f;  // row t0+2
        const float ta = xb + xa * w0 + xb * w1 + xc * w2 + cbc;  // token t0
        const float tb = xc + xb * w0 + xc * w1 + xd * w2 + cbc;  // token t0+1
        v[0][i] = ta; v[1][i] = tb;
        s0 += ta; s20 += ta * ta;
        s1 += tb; s21 += tb * tb;
    }
#pragma unroll
    for (int off = 32; off; off >>= 1) {
        s0  += __shfl_down(s0, off);  s20 += __shfl_down(s20, off);
        s1  += __shfl_down(s1, off);  s21 += __shfl_down(s21, off);
    }
    __shared__ float rs[2][4], rs2[2][4];
    if ((tid & 63) == 0) {
        rs[0][tid >> 6] = s0; rs2[0][tid >> 6] = s20;
        rs[1][tid >> 6] = s1; rs2[1][tid >> 6] = s21;
    }
    __syncthreads();
    const float S0  = rs[0][0] + rs[0][1] + rs[0][2] + rs[0][3];
    const float S20 = rs2[0][0] + rs2[0][1] + rs2[0][2] + rs2[0][3];
    const float S1  = rs[1][0] + rs[1][1] + rs[1][2] + rs[1][3];
    const float S21 = rs2[1][0] + rs2[1][1] + rs2[1][2] + rs2[1][3];
    const float mu0 = S0 * (1.f / C_);
    const float rstd0 = rsqrtf(S20 * (1.f / C_) - mu0 * mu0 + 1e-5f);
    const float mu1 = S1 * (1.f / C_);
    const float rstd1 = rsqrtf(S21 * (1.f / C_) - mu1 * mu1 + 1e-5f);
    float* orow0 = xres + (size_t)t0 * C_;
    bf16*  lrow0 = xln  + (size_t)t0 * C_;
#pragma unroll
    for (int i = 0; i < 2; ++i) {
        const int c = tid + i * 256;
        const float gc = g[c], bbc = bb[c];
        orow0[c] = v[0][i];
        lrow0[c] = (bf16)((v[0][i] - mu0) * rstd0 * gc + bbc);
        orow0[C_ + c] = v[1][i];
        lrow0[C_ + c] = (bf16)((v[1][i] - mu1) * rstd1 * gc + bbc);
    }
}

// ---------------------------------------------------------------------------
// dwc conv over the (b,c,l)-reinterpreted flat buffer + SiLU. x8 vectorized:
// 8-aligned runs never cross a 2048-length channel run, so one bf16x8 center
// load + 2 scalar edge loads cover the 3-tap window.
// ---------------------------------------------------------------------------
__global__ __launch_bounds__(256) void dwc_silu_k(
    const bf16* __restrict__ Y, const float* __restrict__ w,
    const float* __restrict__ b, bf16* __restrict__ xp)
{
    const size_t idx = ((size_t)blockIdx.x * 256 + threadIdx.x) * 8;
    const int m = (int)(idx & (size_t)(L_ * C_ - 1));
    const int ch = m >> 11;          // m / 2048
    const int pos = m & (L_ - 1);    // multiple of 8
    const bf16x8 c = *(const bf16x8*)(Y + idx);
    const float left  = (pos > 0)      ? (float)Y[idx - 1] : 0.f;
    const float right = (pos + 8 < L_) ? (float)Y[idx + 8] : 0.f;
    const float w0 = w[3*ch], w1 = w[3*ch+1], w2 = w[3*ch+2], bc = b[ch];
    bf16x8 o;
#pragma unroll
    for (int j = 0; j < 8; ++j) {
        const float x0 = (float)c[j];
        const float xm = j ? (float)c[j-1] : left;
        const float xq = (j < 7) ? (float)c[j+1] : right;
        o[j] = (bf16)siluf(xm * w0 + x0 * w1 + xq * w2 + bc);
    }
    *(bf16x8*)(xp + idx) = o;
}

// ---------------------------------------------------------------------------
// kvpart[split][b,h,e,d] = sum_{n in split} v[b,n,h,e] * k[b,n,h,d]
// via MFMA (transposed layout [e][d]); plain stores, no atomics.
// ---------------------------------------------------------------------------
__global__ __launch_bounds__(256) void kvmat_mfma_k(
    const bf16* __restrict__ kvbT, float* __restrict__ kvpart)
{
    const int bh = blockIdx.x, b = bh >> 3, h = bh & 7;
    const int tid = threadIdx.x;
    const int wave = tid >> 6, lane = tid & 63;
    const int l16 = lane & 15, quad = lane >> 4;
    __shared__ bf16 As[64 * 72];   // vT chunk: [e][n]
    __shared__ bf16 Bs[64 * 72];   // kT chunk: [d][n]
    const int r = tid >> 2;              // 0..63: LDS row
    const int cseg = (tid & 3) * 16;     // 16 bf16 per thread
    const size_t kRow = (size_t)(h * 64 + r) * M_;
    const size_t vRow = (size_t)(512 + h * 64 + r) * M_;

    f32x4 acc[4];
    const f32x4 z4 = { 0.f, 0.f, 0.f, 0.f };
#pragma unroll
    for (int ni = 0; ni < 4; ++ni) acc[ni] = z4;

    for (int it = 0; it < 8; ++it) {
        const size_t colBase = (size_t)b * L_ + blockIdx.y * 512 + it * 64;
        {
            const bf16* ga = kvbT + vRow + colBase + cseg;   // A = v
            const bf16* gb = kvbT + kRow + colBase + cseg;   // B = k
            *(uint4*)&As[r * 72 + cseg]     = *(const uint4*)ga;
            *(uint4*)&As[r * 72 + cseg + 8] = *(const uint4*)(ga + 8);
            *(uint4*)&Bs[r * 72 + cseg]     = *(const uint4*)gb;
            *(uint4*)&Bs[r * 72 + cseg + 8] = *(const uint4*)(gb + 8);
        }
        __syncthreads();
#pragma unroll
        for (int kk = 0; kk < 64; kk += 32) {
            bf16x8 af = *(const bf16x8*)(&As[(wave * 16 + l16) * 72 + kk + quad * 8]);
#pragma unroll
            for (int ni = 0; ni < 4; ++ni) {
                bf16x8 bfr = *(const bf16x8*)(&Bs[(ni * 16 + l16) * 72 + kk + quad * 8]);
                acc[ni] = __builtin_amdgcn_mfma_f32_16x16x32_bf16(af, bfr, acc[ni], 0, 0, 0);
            }
        }
        __syncthreads();
    }
    float* dst = kvpart + (size_t)blockIdx.y * 262144 + (size_t)bh * 4096;  // [e][d]
#pragma unroll
    for (int ni = 0; ni < 4; ++ni)
#pragma unroll
        for (int rr = 0; rr < 4; ++rr)
            dst[(wave * 16 + quad * 4 + rr) * 64 + ni * 16 + l16] = acc[ni][rr];
}

// ---------------------------------------------------------------------------
// kvfin: blocks [0,1024): sum 4 kvpart partials, scale 1/L, -> bf16 kvbf.
//        blocks [1024,1536): ksum[b,c] = sum_n k[b,n,c] (body identical to
//        the former ksum_k). One launch instead of two.
// ---------------------------------------------------------------------------
__global__ __launch_bounds__(256) void kvfin_k(
    const float* __restrict__ p, bf16* __restrict__ out,
    const bf16* __restrict__ kvbT, float* __restrict__ ksum)
{
    if (blockIdx.x < 1024) {
        int i = blockIdx.x * 256 + threadIdx.x;
        float s = p[i] + p[i + 262144] + p[i + 2 * 262144] + p[i + 3 * 262144];
        out[i] = (bf16)(s * (1.f / (float)L_));
        return;
    }
    const int c = blockIdx.x - 1024;
    const int wave = threadIdx.x >> 6, lane = threadIdx.x & 63;
#pragma unroll
    for (int i = 0; i < 2; ++i) {
        const int b = wave + i * 4;
        const bf16* src = kvbT + (size_t)c * M_ + b * L_ + lane * 32;
        float s = 0.f;
#pragma unroll
        for (int u = 0; u < 4; ++u) {
            bf16x8 v = *(const bf16x8*)(src + u * 8);
#pragma unroll
            for (int j = 0; j < 8; ++j) s += (float)v[j];
        }
#pragma unroll
        for (int o = 32; o; o >>= 1) s += __shfl_down(s, o);
        if (lane == 0) ksum[b * C_ + c] = s;
    }
}

// ---------------------------------------------------------------------------
// MFMA attention: per block (bh, 64-token tile); per wave 16 tokens.
// R14: V-halo tile staged coalesced into LDS (Vs); lepe epilogue reads LDS
// instead of ~22 scattered scalar global loads per lane (V rows 32KB apart).
// ---------------------------------------------------------------------------
__global__ __launch_bounds__(256) void attn_mfma_k(
    const bf16* __restrict__ q, const bf16* __restrict__ kvbT,
    const bf16* __restrict__ kvmatT, const float* __restrict__ ksum,
    const float* __restrict__ lw, const float* __restrict__ lb,
    const bf16* __restrict__ act_res, bf16* __restrict__ xa_mul)
{
    const int bh = blockIdx.x, b = bh >> 3, h = bh & 7;
    const int n0 = blockIdx.y * 64;
    const int tid = threadIdx.x;
    const int wave = tid >> 6, lane = tid & 63;
    const int l16 = lane & 15, quad = lane >> 4;

    __shared__ bf16 kvT[64 * 72];   // [e][d], stride 72 -> 2-way only
    __shared__ bf16 Vs[64 * 72];    // [e][token-in-tile] + halo cols 64/65
    __shared__ bf16 kmS[64];

    const bf16* vbase = kvbT + (size_t)(512 + h * 64) * M_ + (size_t)b * L_;

#pragma unroll
    for (int i = 0; i < 2; ++i) {
        const int idx = i * 256 + tid;               // 512 chunks of 8
        const int row = idx >> 3, col = (idx & 7) * 8;
        *(bf16x8*)&kvT[row * 72 + col] =
            *(const bf16x8*)&kvmatT[(size_t)bh * 4096 + idx * 8];
        *(bf16x8*)&Vs[row * 72 + col] =
            *(const bf16x8*)(vbase + (size_t)row * M_ + n0 + col);
    }
    if (tid < 64) {
        Vs[tid * 72 + 64] = (n0 > 0) ? vbase[(size_t)tid * M_ + n0 - 1] : (bf16)0.f;
        kmS[tid] = (bf16)(ksum[b * C_ + h * 64 + tid] * (1.f / (float)L_));
    } else if (tid < 128) {
        const int r2 = tid - 64;
        Vs[r2 * 72 + 65] = (n0 + 64 < L_) ? vbase[(size_t)r2 * M_ + n0 + 64] : (bf16)0.f;
    }
    __syncthreads();

    // A-frags: 16 q-rows direct from global.
    const int tok = n0 + wave * 16;
    const bf16* qbase = q + ((size_t)b * L_ + tok) * C_ + h * 64;
    const bf16x8 af0 = *(const bf16x8*)(qbase + (size_t)l16 * C_ + quad * 8);
    const bf16x8 af1 = *(const bf16x8*)(qbase + (size_t)l16 * C_ + 32 + quad * 8);

    // z-dot: B-tile col0 = k_mean
    const bf16x8 z8 = { bf16(0.f), bf16(0.f), bf16(0.f), bf16(0.f),
                        bf16(0.f), bf16(0.f), bf16(0.f), bf16(0.f) };
    const bf16x8 km0 = *(const bf16x8*)&kmS[quad * 8];
    const bf16x8 km1 = *(const bf16x8*)&kmS[32 + quad * 8];
    const bf16x8 b20 = (l16 == 0) ? km0 : z8;
    const bf16x8 b21 = (l16 == 0) ? km1 : z8;
    f32x4 zd = { 0.f, 0.f, 0.f, 0.f };
    zd = __builtin_amdgcn_mfma_f32_16x16x32_bf16(af0, b20, zd, 0, 0, 0);
    zd = __builtin_amdgcn_mfma_f32_16x16x32_bf16(af1, b21, zd, 0, 0, 0);
    float zr[4];
#pragma unroll
    for (int r = 0; r < 4; ++r)
        zr[r] = fastrcp(__shfl(zd[r], (lane & 48)) + 1e-6f);

    // q @ kvmatT^T
    f32x4 acc[4];
    const f32x4 zf4 = { 0.f, 0.f, 0.f, 0.f };
#pragma unroll
    for (int ni = 0; ni < 4; ++ni) acc[ni] = zf4;
#pragma unroll
    for (int ni = 0; ni < 4; ++ni) {
        const bf16x8 b0 = *(const bf16x8*)&kvT[(ni * 16 + l16) * 72 + quad * 8];
        const bf16x8 b1 = *(const bf16x8*)&kvT[(ni * 16 + l16) * 72 + 32 + quad * 8];
        acc[ni] = __builtin_amdgcn_mfma_f32_16x16x32_bf16(af0, b0, acc[ni], 0, 0, 0);
        acc[ni] = __builtin_amdgcn_mfma_f32_16x16x32_bf16(af1, b1, acc[ni], 0, 0, 0);
    }

    // epilogue: lane holds (token = tok+quad*4+r, e = ni*16+l16).
    // lepe taps from Vs: same values as global reads, identical FLOP order.
#pragma unroll
    for (int ni = 0; ni < 4; ++ni) {
        const int e = ni * 16 + l16;
        const int c = h * 64 + e;
        const float w0 = lw[3*c], w1 = lw[3*c+1], w2 = lw[3*c+2], lbc = lb[c];
        const bf16* vr = &Vs[e * 72];
#pragma unroll
        for (int r = 0; r < 4; ++r) {
            const int n = tok + quad * 4 + r;
            const int cb = wave * 16 + quad * 4 + r;   // n - n0, in [0,64)
            const float v0 = (float)vr[cb];
            const float vm = (float)((cb > 0)  ? vr[cb - 1] : vr[64]);
            const float vp = (float)((cb < 63) ? vr[cb + 1] : vr[65]);
            const float lepe = vm * w0 + v0 * w1 + vp * w2 + lbc;
            const float xa = acc[ni][r] * zr[r] + lepe;
            const size_t off = ((size_t)b * L_ + n) * C_ + c;
            xa_mul[off] = (bf16)(xa * (float)act_res[off]);
        }
    }
}

// ---------------------------------------------------------------------------
// bf16 MFMA GEMM, m97 structure + XOR-swizzled LDS tiles (128x128, 4 waves).
// Kept for N=512 shapes (q, out-proj, fc2).
// R11 epilogue: wide-store via wave-local LDS transpose (reuses As/Bs LDS
// after the final __syncthreads; per-wave disjoint scratch; no extra sync).
// EPI: 2 elu+1->bf16, 4 gelu->bf16, 5 +res->f32, 7 kvT (row<512 elu)->bf16,
//      8 fused act/in: col<512 silu->outp, else plain->outp2
// ---------------------------------------------------------------------------
template <int EPI>
__global__ __launch_bounds__(256) void gemm_bt(
    const bf16* __restrict__ A, const bf16* __restrict__ Bt,
    const float* __restrict__ bias, const float* __restrict__ res,
    void* __restrict__ outp, void* __restrict__ outp2, int K, int N)
{
    __shared__ bf16 smem[2 * 128 * 64];   // As | Bs (8192 each)
    bf16* As = smem;
    bf16* Bs = smem + 8192;
    const int tid = threadIdx.x;
    const int wave = tid >> 6, lane = tid & 63;
    const int wm = (wave & 1) * 64, wn = (wave >> 1) * 64;
    const int l16 = lane & 15, quad = lane >> 4;
    const size_t tileM = (size_t)blockIdx.x * 128;
    const size_t tileN = (size_t)blockIdx.y * 128;

    const int lrow = lane >> 3;
    const int lcol = (((lane & 7) ^ (lrow & 7))) * 8;   // swizzled source col
    const int swz  = l16 & 7;                           // read-side XOR

    const f32x4 z4 = { 0.f, 0.f, 0.f, 0.f };
    f32x4 acc[4][4];
#pragma unroll
    for (int mi = 0; mi < 4; ++mi)
#pragma unroll
        for (int ni = 0; ni < 4; ++ni) acc[mi][ni] = z4;

    for (int k0 = 0; k0 < K; k0 += 64) {
#pragma unroll
        for (int it = 0; it < 4; ++it) {
            const int rg = it * 32 + wave * 8;           // wave-uniform (mult of 8)
            load_lds16(A  + (tileM + rg + lrow) * (size_t)K + k0 + lcol, As + rg * 64);
            load_lds16(Bt + (tileN + rg + lrow) * (size_t)K + k0 + lcol, Bs + rg * 64);
        }
        __syncthreads();
#pragma unroll
        for (int kk = 0; kk < 64; kk += 32) {
            bf16x8 af[4], bfr[4];
#pragma unroll
            for (int mi = 0; mi < 4; ++mi)
                af[mi] = *(const bf16x8*)(&As[(wm + mi * 16 + l16) * 64
                                              + ((((kk >> 3) + quad) ^ swz) * 8)]);
#pragma unroll
            for (int ni = 0; ni < 4; ++ni)
                bfr[ni] = *(const bf16x8*)(&Bs[(wn + ni * 16 + l16) * 64
                                               + ((((kk >> 3) + quad) ^ swz) * 8)]);
#pragma unroll
            for (int mi = 0; mi < 4; ++mi)
#pragma unroll
                for (int ni = 0; ni < 4; ++ni)
                    acc[mi][ni] = __builtin_amdgcn_mfma_f32_16x16x32_bf16(
                        af[mi], bfr[ni], acc[mi][ni], 0, 0, 0);
        }
        __syncthreads();
    }

    // ---- epilogue: wave-local LDS transpose -> coalesced wide stores.
    const int rrow = lane >> 2;           // 0..15
    const int rseg = (lane & 3) * 16;     // 0/16/32/48

    if (EPI == 5 || EPI == 7) {
        float* sc = (float*)smem + wave * 1088;     // 16 rows x 68 f32
#pragma unroll
        for (int mi = 0; mi < 4; ++mi) {
#pragma unroll
            for (int ni = 0; ni < 4; ++ni)
#pragma unroll
                for (int r = 0; r < 4; ++r)
                    sc[(quad * 4 + r) * 68 + ni * 16 + l16] = acc[mi][ni][r];
            __builtin_amdgcn_sched_barrier(0);
            const size_t rowg = tileM + wm + mi * 16 + rrow;
            const int    colg = (int)tileN + wn + rseg;
            if (EPI == 5) {
                const float* rp = res + rowg * (size_t)N + colg;
                float*       op = (float*)outp + rowg * (size_t)N + colg;
#pragma unroll
                for (int u = 0; u < 4; ++u) {
                    f32x4 v = *(f32x4*)&sc[rrow * 68 + rseg + u * 4];
                    f32x4 rv = *(const f32x4*)(rp + u * 4);
                    f32x4 bv = *(const f32x4*)(bias + colg + u * 4);
                    f32x4 o;
#pragma unroll
                    for (int j = 0; j < 4; ++j) o[j] = v[j] + bv[j] + rv[j];
                    *(f32x4*)(op + u * 4) = o;
                }
            } else {  // EPI 7
                const float bv = bias[(int)rowg];
                const bool k_side = (rowg < 512);
                bf16* op = (bf16*)outp + rowg * (size_t)N + colg;
#pragma unroll
                for (int hh = 0; hh < 2; ++hh) {
                    bf16x8 o8;
#pragma unroll
                    for (int j = 0; j < 8; ++j) {
                        float x = sc[rrow * 68 + rseg + hh * 8 + j] + bv;
                        o8[j] = (bf16)(k_side ? elu1f(x) : x);
                    }
                    *(bf16x8*)(op + hh * 8) = o8;
                }
            }
            __builtin_amdgcn_sched_barrier(0);
        }
    } else {  // EPI 2, 4, 8: bf16 scratch, write-side bias+activation
        bf16* sc = (bf16*)smem + wave * 1152;       // 16 rows x 72 bf16
        float addc[4];
        bool  act_on[4];
#pragma unroll
        for (int ni = 0; ni < 4; ++ni) {
            const int cw = (int)tileN + wn + ni * 16 + l16;
            if (EPI == 8) {
                act_on[ni] = (cw < 512);
                addc[ni] = act_on[ni] ? bias[cw] : res[cw - 512];
            } else { addc[ni] = bias[cw]; act_on[ni] = true; }
        }
#pragma unroll
        for (int mi = 0; mi < 4; ++mi) {
#pragma unroll
            for (int ni = 0; ni < 4; ++ni)
#pragma unroll
                for (int r = 0; r < 4; ++r) {
                    float x = acc[mi][ni][r] + addc[ni];
                    float y;
                    if (EPI == 2)      y = elu1f(x);
                    else if (EPI == 4) y = geluf(x);
                    else               y = act_on[ni] ? siluf(x) : x;
                    sc[(quad * 4 + r) * 72 + ni * 16 + l16] = (bf16)y;
                }
            __builtin_amdgcn_sched_barrier(0);
            const size_t rowg = tileM + wm + mi * 16 + rrow;
            const int    colg = (int)tileN + wn + rseg;
            bf16x8 o0 = *(bf16x8*)&sc[rrow * 72 + rseg];
            bf16x8 o1 = *(bf16x8*)&sc[rrow * 72 + rseg + 8];
            if (EPI == 8) {
                const size_t orow = rowg * (size_t)512;
                bf16* dst = (colg < 512) ? ((bf16*)outp  + orow + colg)
                                         : ((bf16*)outp2 + orow + colg - 512);
                *(bf16x8*)dst = o0; *(bf16x8*)(dst + 8) = o1;
            } else {
                bf16* dst = (bf16*)outp + rowg * (size_t)N + colg;
                *(bf16x8*)dst = o0; *(bf16x8*)(dst + 8) = o1;
            }
            __builtin_amdgcn_sched_barrier(0);
        }
    }
}

// ---------------------------------------------------------------------------
// 256x256 8-wave (2M x 4N) deep-pipelined bf16 GEMM (R9 4-phase core). BK=64,
// double-buffered 128KB LDS, 4 phases per K-tile:
//   ph0: read A-half0(8) + B n0-1(4); stage next-tile loads 0-3;  MFMA m0-3 x n0-1
//   ph1: read B n2-3(4);              stage next-tile loads 4-7;  MFMA m0-3 x n2-3
//   ph2: read A-half1(8);                                         MFMA m4-7 x n0-1
//   ph3: vmcnt(0);                                                MFMA m4-7 x n2-3
// Each phase: raw s_barrier / lgkmcnt(0) / sched_barrier(0) / setprio(1) MFMA.
// R11 epilogue: wide-store via wave-local LDS transpose.
// Requires: M % 256 == 0, N % 256 == 0, K % 64 == 0.
// ---------------------------------------------------------------------------
template <int EPI>
__global__ __launch_bounds__(512, 2) void gemm8(
    const bf16* __restrict__ A, const bf16* __restrict__ Bt,
    const float* __restrict__ bias, const float* __restrict__ res,
    void* __restrict__ outp, void* __restrict__ outp2, int K, int N)
{
    __shared__ bf16 smem[4 * 256 * 64];   // As[2] (32768) | Bs[2] (32768)
    bf16* const AsBase = smem;
    bf16* const BsBase = smem + 32768;
    const int tid  = threadIdx.x;
    const int wave = tid >> 6, lane = tid & 63;
    const int wrow = wave >> 2, wcol = wave & 3;       // 2 x 4 wave grid
    const int l16 = lane & 15, quad = lane >> 4;
    const int lrow = lane >> 3;                        // 0..7
    const int lcol = ((lane & 7) ^ lrow) * 8;          // swizzled source chunk
    const int swz  = l16 & 7;                          // read-side XOR
    const size_t tileM = (size_t)blockIdx.x * 256;
    const size_t tileN = (size_t)blockIdx.y * 256;

    // staging bases: wave w, load j covers rows j*64 + w*8 .. +7
    const bf16* aBase = A  + (tileM + wave * 8 + lrow) * (size_t)K + lcol;
    const bf16* bBase = Bt + (tileN + wave * 8 + lrow) * (size_t)K + lcol;
    const int ldsRow0 = wave * 8;

    f32x4 acc[8][4];
    const f32x4 z4 = { 0.f, 0.f, 0.f, 0.f };
#pragma unroll
    for (int mi = 0; mi < 8; ++mi)
#pragma unroll
        for (int ni = 0; ni < 4; ++ni) acc[mi][ni] = z4;

    // prologue: stage K-tile 0 into buf 0 (8 loads/thread), drain, barrier
#pragma unroll
    for (int j = 0; j < 4; ++j) {
        load_lds16(aBase + (size_t)(j * 64) * K, AsBase + (j * 64 + ldsRow0) * 64);
        load_lds16(bBase + (size_t)(j * 64) * K, BsBase + (j * 64 + ldsRow0) * 64);
    }
    asm volatile("s_waitcnt vmcnt(0)" ::: "memory");
    __builtin_amdgcn_s_barrier();

    const int T = K >> 6;
    int cur = 0;
    for (int t = 0; t < T; ++t) {
        const int nxt = cur ^ 1;
        const bool pf = (t + 1 < T);
        const int kc = (t + 1) << 6;                   // next tile's K offset
        const bf16* as = AsBase + cur * 16384;
        const bf16* bs = BsBase + cur * 16384;
        bf16* asn = AsBase + nxt * 16384;
        bf16* bsn = BsBase + nxt * 16384;
        bf16x8 af[4][2], bfr[4][2];

        // ---------------- phase 0: A-half0 + B(n0,n1); stage loads 0-3 ----
#pragma unroll
        for (int j = 0; j < 4; ++j)
#pragma unroll
            for (int kh = 0; kh < 2; ++kh)
                af[j][kh] = *(const bf16x8*)&as[(wrow * 128 + j * 16 + l16) * 64
                                               + (((kh * 4 + quad) ^ swz) * 8)];
#pragma unroll
        for (int ni = 0; ni < 2; ++ni)
#pragma unroll
            for (int kh = 0; kh < 2; ++kh)
                bfr[ni][kh] = *(const bf16x8*)&bs[(wcol * 64 + ni * 16 + l16) * 64
                                                  + (((kh * 4 + quad) ^ swz) * 8)];
        if (pf) {
#pragma unroll
            for (int j = 0; j < 2; ++j) {
                load_lds16(aBase + (size_t)(j * 64) * K + kc, asn + (j * 64 + ldsRow0) * 64);
                load_lds16(bBase + (size_t)(j * 64) * K + kc, bsn + (j * 64 + ldsRow0) * 64);
            }
        }
        __builtin_amdgcn_s_barrier();
        asm volatile("s_waitcnt lgkmcnt(0)" ::: "memory");
        __builtin_amdgcn_sched_barrier(0);
        __builtin_amdgcn_s_setprio(1);
#pragma unroll
        for (int j = 0; j < 4; ++j)
#pragma unroll
            for (int ni = 0; ni < 2; ++ni)
#pragma unroll
                for (int kh = 0; kh < 2; ++kh)
                    acc[j][ni] = __builtin_amdgcn_mfma_f32_16x16x32_bf16(
                        af[j][kh], bfr[ni][kh], acc[j][ni], 0, 0, 0);
        __builtin_amdgcn_s_setprio(0);
        __builtin_amdgcn_s_barrier();

        // ---------------- phase 1: B(n2,n3); stage loads 4-7 --------------
#pragma unroll
        for (int ni = 2; ni < 4; ++ni)
#pragma unroll
            for (int kh = 0; kh < 2; ++kh)
                bfr[ni][kh] = *(const bf16x8*)&bs[(wcol * 64 + ni * 16 + l16) * 64
                                                  + (((kh * 4 + quad) ^ swz) * 8)];
        if (pf) {
#pragma unroll
            for (int j = 2; j < 4; ++j) {
                load_lds16(aBase + (size_t)(j * 64) * K + kc, asn + (j * 64 + ldsRow0) * 64);
                load_lds16(bBase + (size_t)(j * 64) * K + kc, bsn + (j * 64 + ldsRow0) * 64);
            }
        }
        __builtin_amdgcn_s_barrier();
        asm volatile("s_waitcnt lgkmcnt(0)" ::: "memory");
        __builtin_amdgcn_sched_barrier(0);
        __builtin_amdgcn_s_setprio(1);
#pragma unroll
        for (int j = 0; j < 4; ++j)
#pragma unroll
            for (int ni = 2; ni < 4; ++ni)
#pragma unroll
                for (int kh = 0; kh < 2; ++kh)
                    acc[j][ni] = __builtin_amdgcn_mfma_f32_16x16x32_bf16(
                        af[j][kh], bfr[ni][kh], acc[j][ni], 0, 0, 0);
        __builtin_amdgcn_s_setprio(0);
        __builtin_amdgcn_s_barrier();

        // ---------------- phase 2: A-half1 --------------------------------
#pragma unroll
        for (int j = 0; j < 4; ++j)
#pragma unroll
            for (int kh = 0; kh < 2; ++kh)
                af[j][kh] = *(const bf16x8*)&as[(wrow * 128 + 64 + j * 16 + l16) * 64
                                               + (((kh * 4 + quad) ^ swz) * 8)];
        __builtin_amdgcn_s_barrier();
        asm volatile("s_waitcnt lgkmcnt(0)" ::: "memory");
        __builtin_amdgcn_sched_barrier(0);
        __builtin_amdgcn_s_setprio(1);
#pragma unroll
        for (int j = 0; j < 4; ++j)
#pragma unroll
            for (int ni = 0; ni < 2; ++ni)
#pragma unroll
                for (int kh = 0; kh < 2; ++kh)
                    acc[4 + j][ni] = __builtin_amdgcn_mfma_f32_16x16x32_bf16(
                        af[j][kh], bfr[ni][kh], acc[4 + j][ni], 0, 0, 0);
        __builtin_amdgcn_s_setprio(0);
        __builtin_amdgcn_s_barrier();

        // ---------------- phase 3: wait next tile; last quadrant ----------
        if (pf) asm volatile("s_waitcnt vmcnt(0)" ::: "memory");
        __builtin_amdgcn_s_barrier();
        __builtin_amdgcn_sched_barrier(0);
        __builtin_amdgcn_s_setprio(1);
#pragma unroll
        for (int j = 0; j < 4; ++j)
#pragma unroll
            for (int ni = 2; ni < 4; ++ni)
#pragma unroll
                for (int kh = 0; kh < 2; ++kh)
                    acc[4 + j][ni] = __builtin_amdgcn_mfma_f32_16x16x32_bf16(
                        af[j][kh], bfr[ni][kh], acc[4 + j][ni], 0, 0, 0);
        __builtin_amdgcn_s_setprio(0);
        __builtin_amdgcn_s_barrier();

        cur = nxt;
    }

    // ---- epilogue: wave-local LDS transpose -> coalesced wide stores.
    // Loop ended with s_barrier: all waves done reading As/Bs; vmcnt drained.
    const int rrow = lane >> 2;           // 0..15
    const int rseg = (lane & 3) * 16;     // 0/16/32/48

    if (EPI == 5 || EPI == 7) {
        float* sc = (float*)smem + wave * 1088;     // 16 rows x 68 f32
#pragma unroll
        for (int mi = 0; mi < 8; ++mi) {
#pragma unroll
            for (int ni = 0; ni < 4; ++ni)
#pragma unroll
                for (int r = 0; r < 4; ++r)
                    sc[(quad * 4 + r) * 68 + ni * 16 + l16] = acc[mi][ni][r];
            __builtin_amdgcn_sched_barrier(0);
            const size_t rowg = tileM + wrow * 128 + mi * 16 + rrow;
            const int    colg = (int)tileN + wcol * 64 + rseg;
            if (EPI == 5) {
                const float* rp = res + rowg * (size_t)N + colg;
                float*       op = (float*)outp + rowg * (size_t)N + colg;
#pragma unroll
                for (int u = 0; u < 4; ++u) {
                    f32x4 v = *(f32x4*)&sc[rrow * 68 + rseg + u * 4];
                    f32x4 rv = *(const f32x4*)(rp + u * 4);
                    f32x4 bv = *(const f32x4*)(bias + colg + u * 4);
                    f32x4 o;
#pragma unroll
                    for (int j = 0; j < 4; ++j) o[j] = v[j] + bv[j] + rv[j];
                    *(f32x4*)(op + u * 4) = o;
                }
            } else {  // EPI 7
                const float bv = bias[(int)rowg];
                const bool k_side = (rowg < 512);
                bf16* op = (bf16*)outp + rowg * (size_t)N + colg;
#pragma unroll
                for (int hh = 0; hh < 2; ++hh) {
                    bf16x8 o8;
#pragma unroll
                    for (int j = 0; j < 8; ++j) {
                        float x = sc[rrow * 68 + rseg + hh * 8 + j] + bv;
                        o8[j] = (bf16)(k_side ? elu1f(x) : x);
                    }
                    *(bf16x8*)(op + hh * 8) = o8;
                }
            }
            __builtin_amdgcn_sched_barrier(0);
        }
    } else {  // EPI 2, 4, 8: bf16 scratch, write-side bias+activation
        bf16* sc = (bf16*)smem + wave * 1152;       // 16 rows x 72 bf16
        float addc[4];
        bool  act_on[4];
#pragma unroll
        for (int ni = 0; ni < 4; ++ni) {
            const int cw = (int)tileN + wcol * 64 + ni * 16 + l16;
            if (EPI == 8) {
                act_on[ni] = (cw < 512);
                addc[ni] = act_on[ni] ? bias[cw] : res[cw - 512];
            } else { addc[ni] = bias[cw]; act_on[ni] = true; }
        }
#pragma unroll
        for (int mi = 0; mi < 8; ++mi) {
#pragma unroll
            for (int ni = 0; ni < 4; ++ni)
#pragma unroll
                for (int r = 0; r < 4; ++r) {
                    float x = acc[mi][ni][r] + addc[ni];
                    float y;
                    if (EPI == 2)      y = elu1f(x);
                    else if (EPI == 4) y = geluf(x);
                    else               y = act_on[ni] ? siluf(x) : x;
                    sc[(quad * 4 + r) * 72 + ni * 16 + l16] = (bf16)y;
                }
            __builtin_amdgcn_sched_barrier(0);
            const size_t rowg = tileM + wrow * 128 + mi * 16 + rrow;
            const int    colg = (int)tileN + wcol * 64 + rseg;
            bf16x8 o0 = *(bf16x8*)&sc[rrow * 72 + rseg];
            bf16x8 o1 = *(bf16x8*)&sc[rrow * 72 + rseg + 8];
            if (EPI == 8) {
                const size_t orow = rowg * (size_t)512;
                bf16* dst = (colg < 512) ? ((bf16*)outp  + orow + colg)
                                         : ((bf16*)outp2 + orow + colg - 512);
                *(bf16x8*)dst = o0; *(bf16x8*)(dst + 8) = o1;
            } else {
                bf16* dst = (bf16*)outp + rowg * (size_t)N + colg;
                *(bf16x8*)dst = o0; *(bf16x8*)(dst + 8) = o1;
            }
            __builtin_amdgcn_sched_barrier(0);
        }
    }
}

// ---------------------------------------------------------------------------
// workspace layout (bytes) — total 125,845,504 (~120 MiB)
// ---------------------------------------------------------------------------
#define OFF_WT_ACTIN ((size_t)0)         // bf16 [1024][512] 1MB
#define OFF_WT_Q    ((size_t)1048576)
#define OFF_WT_KV   ((size_t)1572864)
#define OFF_WT_OUT  ((size_t)2621440)
#define OFF_WT_FC1  ((size_t)3145728)
#define OFF_WT_FC2  ((size_t)5242880)
#define OFF_XLN     ((size_t)7340032)    // bf16 16MB (kvbf, hln alias)
#define OFF_ACTRES  ((size_t)24117248)   // bf16 16MB (x3 aliases from here)
#define OFF_Y       ((size_t)40894464)   // bf16 16MB (qb aliases)
#define OFF_XP      ((size_t)57671680)   // bf16 16MB (kvpart, h1 alias from here)
#define OFF_KV      ((size_t)74448896)   // bf16 32MB  kvbT [1024][16384]
#define OFF_KSUM    ((size_t)108003328)  // f32 16KB
#define OFF_XAMUL   ((size_t)109068288)  // bf16 16MB  (xqb early, xamul late)
#define OFF_X3      ((size_t)24117248)   // f32 32MB over actres+Y (dead)
#define OFF_H1      ((size_t)57671680)   // bf16 64MB over xp+kv+xamul (dead)
#define WS_REQUIRED ((size_t)125845504)

extern "C" void kernel_launch(void* const* d_in, const int* in_sizes, int n_in,
                              void* d_out, int out_size, void* d_ws, size_t ws_size,
                              hipStream_t stream)
{
    const float* x_q    = (const float*)d_in[0];
    const float* x_kv   = (const float*)d_in[1];
    const float* cpe1_w = (const float*)d_in[2];
    const float* cpe1_b = (const float*)d_in[3];
    const float* n1_g   = (const float*)d_in[4];
    const float* n1_b   = (const float*)d_in[5];
    const float* in_w   = (const float*)d_in[6];
    const float* in_b   = (const float*)d_in[7];
    const float* act_w  = (const float*)d_in[8];
    const float* act_b  = (const float*)d_in[9];
    const float* dwc_w  = (const float*)d_in[10];
    const float* dwc_b  = (const float*)d_in[11];
    const float* q_w    = (const float*)d_in[12];
    const float* q_b    = (const float*)d_in[13];
    const float* kv_w   = (const float*)d_in[14];
    const float* kv_b   = (const float*)d_in[15];
    const float* lepe_w = (const float*)d_in[16];
    const float* lepe_b = (const float*)d_in[17];
    const float* out_w  = (const float*)d_in[18];
    const float* out_b  = (const float*)d_in[19];
    const float* cpe2_w = (const float*)d_in[20];
    const float* cpe2_b = (const float*)d_in[21];
    const float* n2_g   = (const float*)d_in[22];
    const float* n2_b   = (const float*)d_in[23];
    const float* fc1_w  = (const float*)d_in[24];
    const float* fc1_b  = (const float*)d_in[25];
    const float* fc2_w  = (const float*)d_in[26];
    const float* fc2_b  = (const float*)d_in[27];

    float* outf = (float*)d_out;

    if (ws_size < WS_REQUIRED) {
        zero_k<<<(out_size + 255) / 256, 256, 0, stream>>>(outf, out_size);
        ws_diag_k<<<1, 64, 0, stream>>>(outf, (float)ws_size);
        return;
    }

    char* ws = (char*)d_ws;
    bf16*  wt_actin = (bf16*)(ws + OFF_WT_ACTIN);
    bf16*  wt_q   = (bf16*)(ws + OFF_WT_Q);
    bf16*  wt_kv  = (bf16*)(ws + OFF_WT_KV);
    bf16*  wt_out = (bf16*)(ws + OFF_WT_OUT);
    bf16*  wt_fc1 = (bf16*)(ws + OFF_WT_FC1);
    bf16*  wt_fc2 = (bf16*)(ws + OFF_WT_FC2);
    bf16*  xln    = (bf16*)(ws + OFF_XLN);
    bf16*  kvbf   = (bf16*)(ws + OFF_XLN);      // alias: xln dead after act/in
    bf16*  hln    = (bf16*)(ws + OFF_XLN);      // alias: kvbf dead after attn
    bf16*  actres = (bf16*)(ws + OFF_ACTRES);
    bf16*  Y      = (bf16*)(ws + OFF_Y);
    bf16*  qb     = (bf16*)(ws + OFF_Y);        // alias: Y dead after dwc
    bf16*  xp     = (bf16*)(ws + OFF_XP);
    float* kvpart = (float*)(ws + OFF_XP);      // alias: xp dead after kv-gemm (4MB)
    bf16*  kvbT   = (bf16*)(ws + OFF_KV);       // [1024][16384]
    float* ksum   = (float*)(ws + OFF_KSUM);
    bf16*  xqb    = (bf16*)(ws + OFF_XAMUL);    // early use; dead before attn
    bf16*  xamul  = (bf16*)(ws + OFF_XAMUL);    // written by attn (after q-gemm)
    float* x3     = (float*)(ws + OFF_X3);      // alias
    bf16*  h1     = (bf16*)(ws + OFF_H1);       // alias

    // all weight transposes + x_q -> bf16 conversion, one launch
    TJobs jobs;
    jobs.j[0] = { act_w, wt_actin,             512,  512,    0 };
    jobs.j[1] = { in_w,  wt_actin + 512 * 512, 512,  512,  256 };
    jobs.j[2] = { q_w,   wt_q,                 512,  512,  512 };
    jobs.j[3] = { kv_w,  wt_kv,                512, 1024,  768 };
    jobs.j[4] = { out_w, wt_out,               512,  512, 1280 };
    jobs.j[5] = { fc1_w, wt_fc1,               512, 2048, 1536 };
    jobs.j[6] = { fc2_w, wt_fc2,              2048,  512, 2560 };
    transpose_all_k<<<11776, 256, 0, stream>>>(jobs, x_q, xqb);

    // cpe1 + LN1: shortcut (fp32) lives in d_out  [2 tokens/block]
    cpe_ln_k<<<M_ / 2, 256, 0, stream>>>(x_kv, cpe1_w, cpe1_b, n1_g, n1_b, outf, xln);

    // fused act gate + in-proj (one pass over xln), N=1024  [256x256 pipelined]
    gemm8<8><<<dim3(64, 4), 512, 0, stream>>>(xln, wt_actin, act_b, in_b, actres, Y, 512, 1024);

    // flat-reshape dwconv + silu -> xp (frees Y)
    dwc_silu_k<<<4096, 256, 0, stream>>>(Y, dwc_w, dwc_b, xp);

    // q = elu+1(xqb @ q_w) -> qb (@Y)
    gemm_bt<2><<<dim3(128, 4), 256, 0, stream>>>(xqb, wt_q, q_b, nullptr, qb, nullptr, 512, 512);

    // kvbT[c][token] = (xp @ kv_w)^T : roles swapped (A=wt_kv, Bt=xp)  [256x256]
    gemm8<7><<<dim3(4, 64), 512, 0, stream>>>(wt_kv, xp, kv_b, nullptr, kvbT, nullptr, 512, M_);

    // kvmatT partials (MFMA, no atomics), then fused reduce+convert & k-mean
    kvmat_mfma_k<<<dim3(64, 4), 256, 0, stream>>>(kvbT, kvpart);
    kvfin_k<<<1536, 256, 0, stream>>>(kvpart, kvbf, kvbT, ksum);

    // MFMA attention + lepe + gate multiply (xqb dead from here; xamul written)
    attn_mfma_k<<<dim3(64, 32), 256, 0, stream>>>(qb, kvbT, kvbf, ksum,
                                                  lepe_w, lepe_b, actres, xamul);

    // out-proj + shortcut residual, in-place on d_out
    gemm_bt<5><<<dim3(128, 4), 256, 0, stream>>>(xamul, wt_out, out_b, outf, outf, nullptr, 512, 512);

    // cpe2 + LN2: x2 (=d_out) -> x3 (fp32 ws) + hln (bf16)  [2 tokens/block]
    cpe_ln_k<<<M_ / 2, 256, 0, stream>>>(outf, cpe2_w, cpe2_b, n2_g, n2_b, x3, hln);

    // MLP: fc1 (gelu) [256x256 pipelined] -> fc2 (+x3) -> d_out
    gemm8<4><<<dim3(64, 8), 512, 0, stream>>>(hln, wt_fc1, fc1_b, nullptr, h1, nullptr, 512, 2048);
    gemm_bt<5><<<dim3(128, 4),  256, 0, stream>>>(h1,  wt_fc2, fc2_b, x3, outf, nullptr, 2048, 512);

    (void)in_sizes; (void)n_in; (void)out_size; (void)ws_size;
}

// Round 9
// 416.227 us; speedup vs baseline: 1.2930x; 1.0268x over previous
//
#include <hip/hip_runtime.h>
#include <cmath>

// ---------------------------------------------------------------------------
// MLLA block, B=8 L=2048 C=512 H=8 HD=64 MLP_H=2048, fp32 I/O, bf16 MFMA GEMMs
// R16: (1) attn Q-tile staged coalesced into LDS (Qs[64][72]) — A-frag loads
//      previously strided 1KB/lane (16 cache lines per bf16x8, 4x over-fetch),
//      same scatter pathology as R14's lepe fix. (2) cpe_ln 4 tokens/block
//      (6 row-reads per 4 tokens vs 8). Both bit-exact (identical values and
//      FLOP order). GEMMs byte-identical to R13-R15 (total 427.4us).
//      NOTE R15 forensics: profiled-replay dispatches can run in a slow mode
//      (all counters scale by ~0.64) — trust graph dur_us over replay counters.
// ---------------------------------------------------------------------------

typedef __bf16 bf16;
typedef __bf16 bf16x8 __attribute__((ext_vector_type(8)));
typedef __bf16 bf16x4 __attribute__((ext_vector_type(4)));
typedef float  f32x4  __attribute__((ext_vector_type(4)));

#define B_  8
#define L_  2048
#define C_  512
#define M_  (B_ * L_)          // 16384 tokens

__device__ __forceinline__ float fastrcp(float x) { return __builtin_amdgcn_rcpf(x); }

__device__ __forceinline__ float siluf(float x)
{
    return x * fastrcp(1.f + __expf(-x));
}
__device__ __forceinline__ float elu1f(float x) { return x > 0.f ? x + 1.f : __expf(x); }

// exact-GELU via Abramowitz-Stegun 7.1.25 erf (3-term, |eps| <= 2.5e-5)
__device__ __forceinline__ float geluf(float x)
{
    const float z = fabsf(x) * 0.70710678118654752f;
    const float t = fastrcp(__builtin_fmaf(z, 0.47047f, 1.f));
    const float poly = t * (0.3480242f + t * (-0.0958798f + t * 0.7478556f));
    const float erfz = __builtin_fmaf(-poly, __expf(-z * z), 1.f);
    const float hx = 0.5f * x;
    return __builtin_fmaf(hx, __builtin_copysignf(erfz, x), hx);
}

// global -> LDS direct DMA, 16B per lane. lds dest must be wave-uniform base;
// HW deposits lane i at base + i*16B.
__device__ __forceinline__ void load_lds16(const bf16* g, bf16* l)
{
    __builtin_amdgcn_global_load_lds(
        (const __attribute__((address_space(1))) void*)g,
        (__attribute__((address_space(3))) void*)l, 16, 0, 0);
}

// ---------------------------------------------------------------------------
__global__ __launch_bounds__(256) void zero_k(float* __restrict__ p, int n)
{
    int i = blockIdx.x * 256 + threadIdx.x;
    if (i < n) p[i] = 0.f;
}

__global__ __launch_bounds__(64) void ws_diag_k(float* __restrict__ out, float v)
{
    if (threadIdx.x == 0 && blockIdx.x == 0) out[0] = v;
}

// ---------------------------------------------------------------------------
// ALL weight transposes + x_q f32->bf16 conversion in ONE launch.
// Blocks [0, 3584): transpose jobs. Blocks [3584, 11776): x_q conversion.
// ---------------------------------------------------------------------------
struct TJob  { const float* W; bf16* Wt; int K; int N; int blk0; };
struct TJobs { TJob j[7]; };

__global__ __launch_bounds__(256) void transpose_all_k(
    TJobs jobs, const float* __restrict__ xq, bf16* __restrict__ xqb)
{
    const int bid = blockIdx.x;
    if (bid >= 3584) {
        const int i = (bid - 3584) * 256 + threadIdx.x;   // exactly M_*C_/4
        float4 v = ((const float4*)xq)[i];
        bf16x4 o = { (bf16)v.x, (bf16)v.y, (bf16)v.z, (bf16)v.w };
        ((bf16x4*)xqb)[i] = o;
        return;
    }
    __shared__ float tile[32][33];
    int ji = 0;
#pragma unroll
    for (int i = 1; i < 7; ++i) if (bid >= jobs.j[i].blk0) ji = i;
    const float* W  = jobs.j[ji].W;
    bf16*        Wt = jobs.j[ji].Wt;
    const int K = jobs.j[ji].K, N = jobs.j[ji].N;
    const int rel = bid - jobs.j[ji].blk0;
    const int nb = N >> 5;
    const int n0 = (rel % nb) * 32, k0 = (rel / nb) * 32;
    const int tx = threadIdx.x & 31, ty = threadIdx.x >> 5;   // 32 x 8
#pragma unroll
    for (int i = 0; i < 32; i += 8)
        tile[ty + i][tx] = W[(size_t)(k0 + ty + i) * N + n0 + tx];
    __syncthreads();
#pragma unroll
    for (int i = 0; i < 32; i += 8)
        Wt[(size_t)(n0 + ty + i) * K + k0 + tx] = (bf16)tile[tx][ty + i];
}

// ---------------------------------------------------------------------------
// depthwise conv (k=3, zero pad) along L + residual + LayerNorm.
// R16: 4 tokens per block (t0 = 4*blockIdx.x .. t0+3). Reads rows t0-1..t0+4
// (6) instead of 8 (2-tok version) / 12 (1-tok). Per-token conv, partials,
// shuffle tree, normalize identical -> bit-exact. l0 = t0 & 2047 is a multiple
// of 4: rows t0+1..t0+3 always in-batch; halo row t0+4 valid iff l0+4 < L_.
// ---------------------------------------------------------------------------
__global__ __launch_bounds__(256) void cpe_ln_k(
    const float* __restrict__ xin, const float* __restrict__ cw,
    const float* __restrict__ cb, const float* __restrict__ g,
    const float* __restrict__ bb, float* __restrict__ xres,
    bf16* __restrict__ xln)
{
    const int t0 = blockIdx.x * 4;
    const int l0 = t0 & (L_ - 1);
    const int tid = threadIdx.x;
    const float* r0 = xin + (size_t)t0 * C_;
    float v[4][2];
    float s[4] = {0.f, 0.f, 0.f, 0.f}, s2[4] = {0.f, 0.f, 0.f, 0.f};
#pragma unroll
    for (int i = 0; i < 2; ++i) {
        const int c = tid + i * 256;
        const float w0 = cw[3*c], w1 = cw[3*c+1], w2 = cw[3*c+2], cbc = cb[c];
        const float xm1 = (l0 > 0)      ? r0[c - C_]     : 0.f;  // row t0-1
        const float x0  = r0[c];                                 // row t0
        const float x1  = r0[c + C_];
        const float x2  = r0[c + 2 * C_];
        const float x3  = r0[c + 3 * C_];
        const float x4  = (l0 + 4 < L_) ? r0[c + 4 * C_] : 0.f;  // row t0+4
        const float t0v = x0 + xm1 * w0 + x0 * w1 + x1 * w2 + cbc;
        const float t1v = x1 + x0  * w0 + x1 * w1 + x2 * w2 + cbc;
        const float t2v = x2 + x1  * w0 + x2 * w1 + x3 * w2 + cbc;
        const float t3v = x3 + x2  * w0 + x3 * w1 + x4 * w2 + cbc;
        v[0][i] = t0v; v[1][i] = t1v; v[2][i] = t2v; v[3][i] = t3v;
        s[0] += t0v; s2[0] += t0v * t0v;
        s[1] += t1v; s2[1] += t1v * t1v;
        s[2] += t2v; s2[2] += t2v * t2v;
        s[3] += t3v; s2[3] += t3v * t3v;
    }
#pragma unroll
    for (int off = 32; off; off >>= 1)
#pragma unroll
        for (int t = 0; t < 4; ++t) {
            s[t]  += __shfl_down(s[t], off);
            s2[t] += __shfl_down(s2[t], off);
        }
    __shared__ float rs[4][4], rs2[4][4];
    if ((tid & 63) == 0)
#pragma unroll
        for (int t = 0; t < 4; ++t) {
            rs[t][tid >> 6] = s[t]; rs2[t][tid >> 6] = s2[t];
        }
    __syncthreads();
    float mu[4], rstd[4];
#pragma unroll
    for (int t = 0; t < 4; ++t) {
        const float S  = rs[t][0] + rs[t][1] + rs[t][2] + rs[t][3];
        const float S2 = rs2[t][0] + rs2[t][1] + rs2[t][2] + rs2[t][3];
        mu[t] = S * (1.f / C_);
        rstd[t] = rsqrtf(S2 * (1.f / C_) - mu[t] * mu[t] + 1e-5f);
    }
    float* orow = xres + (size_t)t0 * C_;
    bf16*  lrow = xln  + (size_t)t0 * C_;
#pragma unroll
    for (int i = 0; i < 2; ++i) {
        const int c = tid + i * 256;
        const float gc = g[c], bbc = bb[c];
#pragma unroll
        for (int t = 0; t < 4; ++t) {
            orow[t * C_ + c] = v[t][i];
            lrow[t * C_ + c] = (bf16)((v[t][i] - mu[t]) * rstd[t] * gc + bbc);
        }
    }
}

// ---------------------------------------------------------------------------
// dwc conv over the (b,c,l)-reinterpreted flat buffer + SiLU. x8 vectorized.
// ---------------------------------------------------------------------------
__global__ __launch_bounds__(256) void dwc_silu_k(
    const bf16* __restrict__ Y, const float* __restrict__ w,
    const float* __restrict__ b, bf16* __restrict__ xp)
{
    const size_t idx = ((size_t)blockIdx.x * 256 + threadIdx.x) * 8;
    const int m = (int)(idx & (size_t)(L_ * C_ - 1));
    const int ch = m >> 11;          // m / 2048
    const int pos = m & (L_ - 1);    // multiple of 8
    const bf16x8 c = *(const bf16x8*)(Y + idx);
    const float left  = (pos > 0)      ? (float)Y[idx - 1] : 0.f;
    const float right = (pos + 8 < L_) ? (float)Y[idx + 8] : 0.f;
    const float w0 = w[3*ch], w1 = w[3*ch+1], w2 = w[3*ch+2], bc = b[ch];
    bf16x8 o;
#pragma unroll
    for (int j = 0; j < 8; ++j) {
        const float x0 = (float)c[j];
        const float xm = j ? (float)c[j-1] : left;
        const float xq = (j < 7) ? (float)c[j+1] : right;
        o[j] = (bf16)siluf(xm * w0 + x0 * w1 + xq * w2 + bc);
    }
    *(bf16x8*)(xp + idx) = o;
}

// ---------------------------------------------------------------------------
// kvpart[split][b,h,e,d] = sum_{n in split} v[b,n,h,e] * k[b,n,h,d]
// via MFMA (transposed layout [e][d]); plain stores, no atomics.
// ---------------------------------------------------------------------------
__global__ __launch_bounds__(256) void kvmat_mfma_k(
    const bf16* __restrict__ kvbT, float* __restrict__ kvpart)
{
    const int bh = blockIdx.x, b = bh >> 3, h = bh & 7;
    const int tid = threadIdx.x;
    const int wave = tid >> 6, lane = tid & 63;
    const int l16 = lane & 15, quad = lane >> 4;
    __shared__ bf16 As[64 * 72];   // vT chunk: [e][n]
    __shared__ bf16 Bs[64 * 72];   // kT chunk: [d][n]
    const int r = tid >> 2;              // 0..63: LDS row
    const int cseg = (tid & 3) * 16;     // 16 bf16 per thread
    const size_t kRow = (size_t)(h * 64 + r) * M_;
    const size_t vRow = (size_t)(512 + h * 64 + r) * M_;

    f32x4 acc[4];
    const f32x4 z4 = { 0.f, 0.f, 0.f, 0.f };
#pragma unroll
    for (int ni = 0; ni < 4; ++ni) acc[ni] = z4;

    for (int it = 0; it < 8; ++it) {
        const size_t colBase = (size_t)b * L_ + blockIdx.y * 512 + it * 64;
        {
            const bf16* ga = kvbT + vRow + colBase + cseg;   // A = v
            const bf16* gb = kvbT + kRow + colBase + cseg;   // B = k
            *(uint4*)&As[r * 72 + cseg]     = *(const uint4*)ga;
            *(uint4*)&As[r * 72 + cseg + 8] = *(const uint4*)(ga + 8);
            *(uint4*)&Bs[r * 72 + cseg]     = *(const uint4*)gb;
            *(uint4*)&Bs[r * 72 + cseg + 8] = *(const uint4*)(gb + 8);
        }
        __syncthreads();
#pragma unroll
        for (int kk = 0; kk < 64; kk += 32) {
            bf16x8 af = *(const bf16x8*)(&As[(wave * 16 + l16) * 72 + kk + quad * 8]);
#pragma unroll
            for (int ni = 0; ni < 4; ++ni) {
                bf16x8 bfr = *(const bf16x8*)(&Bs[(ni * 16 + l16) * 72 + kk + quad * 8]);
                acc[ni] = __builtin_amdgcn_mfma_f32_16x16x32_bf16(af, bfr, acc[ni], 0, 0, 0);
            }
        }
        __syncthreads();
    }
    float* dst = kvpart + (size_t)blockIdx.y * 262144 + (size_t)bh * 4096;  // [e][d]
#pragma unroll
    for (int ni = 0; ni < 4; ++ni)
#pragma unroll
        for (int rr = 0; rr < 4; ++rr)
            dst[(wave * 16 + quad * 4 + rr) * 64 + ni * 16 + l16] = acc[ni][rr];
}

// ---------------------------------------------------------------------------
// kvfin: blocks [0,1024): sum 4 kvpart partials, scale 1/L, -> bf16 kvbf.
//        blocks [1024,1536): ksum[b,c] = sum_n k[b,n,c].
// ---------------------------------------------------------------------------
__global__ __launch_bounds__(256) void kvfin_k(
    const float* __restrict__ p, bf16* __restrict__ out,
    const bf16* __restrict__ kvbT, float* __restrict__ ksum)
{
    if (blockIdx.x < 1024) {
        int i = blockIdx.x * 256 + threadIdx.x;
        float s = p[i] + p[i + 262144] + p[i + 2 * 262144] + p[i + 3 * 262144];
        out[i] = (bf16)(s * (1.f / (float)L_));
        return;
    }
    const int c = blockIdx.x - 1024;
    const int wave = threadIdx.x >> 6, lane = threadIdx.x & 63;
#pragma unroll
    for (int i = 0; i < 2; ++i) {
        const int b = wave + i * 4;
        const bf16* src = kvbT + (size_t)c * M_ + b * L_ + lane * 32;
        float s = 0.f;
#pragma unroll
        for (int u = 0; u < 4; ++u) {
            bf16x8 v = *(const bf16x8*)(src + u * 8);
#pragma unroll
            for (int j = 0; j < 8; ++j) s += (float)v[j];
        }
#pragma unroll
        for (int o = 32; o; o >>= 1) s += __shfl_down(s, o);
        if (lane == 0) ksum[b * C_ + c] = s;
    }
}

// ---------------------------------------------------------------------------
// MFMA attention: per block (bh, 64-token tile); per wave 16 tokens.
// R14: V-halo tile in LDS (Vs). R16: Q tile also staged coalesced into LDS
// (Qs[64][72]) — A-frag loads previously strided 1KB/lane (16 lines/load).
// Identical values and FLOP order -> bit-exact.
// ---------------------------------------------------------------------------
__global__ __launch_bounds__(256) void attn_mfma_k(
    const bf16* __restrict__ q, const bf16* __restrict__ kvbT,
    const bf16* __restrict__ kvmatT, const float* __restrict__ ksum,
    const float* __restrict__ lw, const float* __restrict__ lb,
    const bf16* __restrict__ act_res, bf16* __restrict__ xa_mul)
{
    const int bh = blockIdx.x, b = bh >> 3, h = bh & 7;
    const int n0 = blockIdx.y * 64;
    const int tid = threadIdx.x;
    const int wave = tid >> 6, lane = tid & 63;
    const int l16 = lane & 15, quad = lane >> 4;

    __shared__ bf16 kvT[64 * 72];   // [e][d], stride 72 -> 2-way only
    __shared__ bf16 Vs[64 * 72];    // [e][token-in-tile] + halo cols 64/65
    __shared__ bf16 Qs[64 * 72];    // [token-in-tile][channel 0..63]
    __shared__ bf16 kmS[64];

    const bf16* vbase = kvbT + (size_t)(512 + h * 64) * M_ + (size_t)b * L_;
    const bf16* qtile = q + ((size_t)b * L_ + n0) * C_ + h * 64;

#pragma unroll
    for (int i = 0; i < 2; ++i) {
        const int idx = i * 256 + tid;               // 512 chunks of 8
        const int row = idx >> 3, col = (idx & 7) * 8;
        *(bf16x8*)&kvT[row * 72 + col] =
            *(const bf16x8*)&kvmatT[(size_t)bh * 4096 + idx * 8];
        *(bf16x8*)&Vs[row * 72 + col] =
            *(const bf16x8*)(vbase + (size_t)row * M_ + n0 + col);
        *(bf16x8*)&Qs[row * 72 + col] =
            *(const bf16x8*)(qtile + (size_t)row * C_ + col);
    }
    if (tid < 64) {
        Vs[tid * 72 + 64] = (n0 > 0) ? vbase[(size_t)tid * M_ + n0 - 1] : (bf16)0.f;
        kmS[tid] = (bf16)(ksum[b * C_ + h * 64 + tid] * (1.f / (float)L_));
    } else if (tid < 128) {
        const int r2 = tid - 64;
        Vs[r2 * 72 + 65] = (n0 + 64 < L_) ? vbase[(size_t)r2 * M_ + n0 + 64] : (bf16)0.f;
    }
    __syncthreads();

    // A-frags from LDS (token = wave*16 + l16, channels quad*8.. / +32)
    const int tok = n0 + wave * 16;
    const bf16x8 af0 = *(const bf16x8*)&Qs[(wave * 16 + l16) * 72 + quad * 8];
    const bf16x8 af1 = *(const bf16x8*)&Qs[(wave * 16 + l16) * 72 + 32 + quad * 8];

    // z-dot: B-tile col0 = k_mean
    const bf16x8 z8 = { bf16(0.f), bf16(0.f), bf16(0.f), bf16(0.f),
                        bf16(0.f), bf16(0.f), bf16(0.f), bf16(0.f) };
    const bf16x8 km0 = *(const bf16x8*)&kmS[quad * 8];
    const bf16x8 km1 = *(const bf16x8*)&kmS[32 + quad * 8];
    const bf16x8 b20 = (l16 == 0) ? km0 : z8;
    const bf16x8 b21 = (l16 == 0) ? km1 : z8;
    f32x4 zd = { 0.f, 0.f, 0.f, 0.f };
    zd = __builtin_amdgcn_mfma_f32_16x16x32_bf16(af0, b20, zd, 0, 0, 0);
    zd = __builtin_amdgcn_mfma_f32_16x16x32_bf16(af1, b21, zd, 0, 0, 0);
    float zr[4];
#pragma unroll
    for (int r = 0; r < 4; ++r)
        zr[r] = fastrcp(__shfl(zd[r], (lane & 48)) + 1e-6f);

    // q @ kvmatT^T
    f32x4 acc[4];
    const f32x4 zf4 = { 0.f, 0.f, 0.f, 0.f };
#pragma unroll
    for (int ni = 0; ni < 4; ++ni) acc[ni] = zf4;
#pragma unroll
    for (int ni = 0; ni < 4; ++ni) {
        const bf16x8 b0 = *(const bf16x8*)&kvT[(ni * 16 + l16) * 72 + quad * 8];
        const bf16x8 b1 = *(const bf16x8*)&kvT[(ni * 16 + l16) * 72 + 32 + quad * 8];
        acc[ni] = __builtin_amdgcn_mfma_f32_16x16x32_bf16(af0, b0, acc[ni], 0, 0, 0);
        acc[ni] = __builtin_amdgcn_mfma_f32_16x16x32_bf16(af1, b1, acc[ni], 0, 0, 0);
    }

    // epilogue: lane holds (token = tok+quad*4+r, e = ni*16+l16).
#pragma unroll
    for (int ni = 0; ni < 4; ++ni) {
        const int e = ni * 16 + l16;
        const int c = h * 64 + e;
        const float w0 = lw[3*c], w1 = lw[3*c+1], w2 = lw[3*c+2], lbc = lb[c];
        const bf16* vr = &Vs[e * 72];
#pragma unroll
        for (int r = 0; r < 4; ++r) {
            const int n = tok + quad * 4 + r;
            const int cb = wave * 16 + quad * 4 + r;   // n - n0, in [0,64)
            const float v0 = (float)vr[cb];
            const float vm = (float)((cb > 0)  ? vr[cb - 1] : vr[64]);
            const float vp = (float)((cb < 63) ? vr[cb + 1] : vr[65]);
            const float lepe = vm * w0 + v0 * w1 + vp * w2 + lbc;
            const float xa = acc[ni][r] * zr[r] + lepe;
            const size_t off = ((size_t)b * L_ + n) * C_ + c;
            xa_mul[off] = (bf16)(xa * (float)act_res[off]);
        }
    }
}

// ---------------------------------------------------------------------------
// bf16 MFMA GEMM, m97 structure + XOR-swizzled LDS tiles (128x128, 4 waves).
// Kept for N=512 shapes (q, out-proj, fc2).
// R11 epilogue: wide-store via wave-local LDS transpose.
// EPI: 2 elu+1->bf16, 4 gelu->bf16, 5 +res->f32, 7 kvT (row<512 elu)->bf16,
//      8 fused act/in: col<512 silu->outp, else plain->outp2
// ---------------------------------------------------------------------------
template <int EPI>
__global__ __launch_bounds__(256) void gemm_bt(
    const bf16* __restrict__ A, const bf16* __restrict__ Bt,
    const float* __restrict__ bias, const float* __restrict__ res,
    void* __restrict__ outp, void* __restrict__ outp2, int K, int N)
{
    __shared__ bf16 smem[2 * 128 * 64];   // As | Bs (8192 each)
    bf16* As = smem;
    bf16* Bs = smem + 8192;
    const int tid = threadIdx.x;
    const int wave = tid >> 6, lane = tid & 63;
    const int wm = (wave & 1) * 64, wn = (wave >> 1) * 64;
    const int l16 = lane & 15, quad = lane >> 4;
    const size_t tileM = (size_t)blockIdx.x * 128;
    const size_t tileN = (size_t)blockIdx.y * 128;

    const int lrow = lane >> 3;
    const int lcol = (((lane & 7) ^ (lrow & 7))) * 8;   // swizzled source col
    const int swz  = l16 & 7;                           // read-side XOR

    const f32x4 z4 = { 0.f, 0.f, 0.f, 0.f };
    f32x4 acc[4][4];
#pragma unroll
    for (int mi = 0; mi < 4; ++mi)
#pragma unroll
        for (int ni = 0; ni < 4; ++ni) acc[mi][ni] = z4;

    for (int k0 = 0; k0 < K; k0 += 64) {
#pragma unroll
        for (int it = 0; it < 4; ++it) {
            const int rg = it * 32 + wave * 8;           // wave-uniform (mult of 8)
            load_lds16(A  + (tileM + rg + lrow) * (size_t)K + k0 + lcol, As + rg * 64);
            load_lds16(Bt + (tileN + rg + lrow) * (size_t)K + k0 + lcol, Bs + rg * 64);
        }
        __syncthreads();
#pragma unroll
        for (int kk = 0; kk < 64; kk += 32) {
            bf16x8 af[4], bfr[4];
#pragma unroll
            for (int mi = 0; mi < 4; ++mi)
                af[mi] = *(const bf16x8*)(&As[(wm + mi * 16 + l16) * 64
                                              + ((((kk >> 3) + quad) ^ swz) * 8)]);
#pragma unroll
            for (int ni = 0; ni < 4; ++ni)
                bfr[ni] = *(const bf16x8*)(&Bs[(wn + ni * 16 + l16) * 64
                                               + ((((kk >> 3) + quad) ^ swz) * 8)]);
#pragma unroll
            for (int mi = 0; mi < 4; ++mi)
#pragma unroll
                for (int ni = 0; ni < 4; ++ni)
                    acc[mi][ni] = __builtin_amdgcn_mfma_f32_16x16x32_bf16(
                        af[mi], bfr[ni], acc[mi][ni], 0, 0, 0);
        }
        __syncthreads();
    }

    // ---- epilogue: wave-local LDS transpose -> coalesced wide stores.
    const int rrow = lane >> 2;           // 0..15
    const int rseg = (lane & 3) * 16;     // 0/16/32/48

    if (EPI == 5 || EPI == 7) {
        float* sc = (float*)smem + wave * 1088;     // 16 rows x 68 f32
#pragma unroll
        for (int mi = 0; mi < 4; ++mi) {
#pragma unroll
            for (int ni = 0; ni < 4; ++ni)
#pragma unroll
                for (int r = 0; r < 4; ++r)
                    sc[(quad * 4 + r) * 68 + ni * 16 + l16] = acc[mi][ni][r];
            __builtin_amdgcn_sched_barrier(0);
            const size_t rowg = tileM + wm + mi * 16 + rrow;
            const int    colg = (int)tileN + wn + rseg;
            if (EPI == 5) {
                const float* rp = res + rowg * (size_t)N + colg;
                float*       op = (float*)outp + rowg * (size_t)N + colg;
#pragma unroll
                for (int u = 0; u < 4; ++u) {
                    f32x4 v = *(f32x4*)&sc[rrow * 68 + rseg + u * 4];
                    f32x4 rv = *(const f32x4*)(rp + u * 4);
                    f32x4 bv = *(const f32x4*)(bias + colg + u * 4);
                    f32x4 o;
#pragma unroll
                    for (int j = 0; j < 4; ++j) o[j] = v[j] + bv[j] + rv[j];
                    *(f32x4*)(op + u * 4) = o;
                }
            } else {  // EPI 7
                const float bv = bias[(int)rowg];
                const bool k_side = (rowg < 512);
                bf16* op = (bf16*)outp + rowg * (size_t)N + colg;
#pragma unroll
                for (int hh = 0; hh < 2; ++hh) {
                    bf16x8 o8;
#pragma unroll
                    for (int j = 0; j < 8; ++j) {
                        float x = sc[rrow * 68 + rseg + hh * 8 + j] + bv;
                        o8[j] = (bf16)(k_side ? elu1f(x) : x);
                    }
                    *(bf16x8*)(op + hh * 8) = o8;
                }
            }
            __builtin_amdgcn_sched_barrier(0);
        }
    } else {  // EPI 2, 4, 8: bf16 scratch, write-side bias+activation
        bf16* sc = (bf16*)smem + wave * 1152;       // 16 rows x 72 bf16
        float addc[4];
        bool  act_on[4];
#pragma unroll
        for (int ni = 0; ni < 4; ++ni) {
            const int cw = (int)tileN + wn + ni * 16 + l16;
            if (EPI == 8) {
                act_on[ni] = (cw < 512);
                addc[ni] = act_on[ni] ? bias[cw] : res[cw - 512];
            } else { addc[ni] = bias[cw]; act_on[ni] = true; }
        }
#pragma unroll
        for (int mi = 0; mi < 4; ++mi) {
#pragma unroll
            for (int ni = 0; ni < 4; ++ni)
#pragma unroll
                for (int r = 0; r < 4; ++r) {
                    float x = acc[mi][ni][r] + addc[ni];
                    float y;
                    if (EPI == 2)      y = elu1f(x);
                    else if (EPI == 4) y = geluf(x);
                    else               y = act_on[ni] ? siluf(x) : x;
                    sc[(quad * 4 + r) * 72 + ni * 16 + l16] = (bf16)y;
                }
            __builtin_amdgcn_sched_barrier(0);
            const size_t rowg = tileM + wm + mi * 16 + rrow;
            const int    colg = (int)tileN + wn + rseg;
            bf16x8 o0 = *(bf16x8*)&sc[rrow * 72 + rseg];
            bf16x8 o1 = *(bf16x8*)&sc[rrow * 72 + rseg + 8];
            if (EPI == 8) {
                const size_t orow = rowg * (size_t)512;
                bf16* dst = (colg < 512) ? ((bf16*)outp  + orow + colg)
                                         : ((bf16*)outp2 + orow + colg - 512);
                *(bf16x8*)dst = o0; *(bf16x8*)(dst + 8) = o1;
            } else {
                bf16* dst = (bf16*)outp + rowg * (size_t)N + colg;
                *(bf16x8*)dst = o0; *(bf16x8*)(dst + 8) = o1;
            }
            __builtin_amdgcn_sched_barrier(0);
        }
    }
}

// ---------------------------------------------------------------------------
// 256x256 8-wave (2M x 4N) deep-pipelined bf16 GEMM (R9 4-phase core). BK=64,
// double-buffered 128KB LDS, 4 phases per K-tile. R11 wide-store epilogue.
// Requires: M % 256 == 0, N % 256 == 0, K % 64 == 0.
// ---------------------------------------------------------------------------
template <int EPI>
__global__ __launch_bounds__(512, 2) void gemm8(
    const bf16* __restrict__ A, const bf16* __restrict__ Bt,
    const float* __restrict__ bias, const float* __restrict__ res,
    void* __restrict__ outp, void* __restrict__ outp2, int K, int N)
{
    __shared__ bf16 smem[4 * 256 * 64];   // As[2] (32768) | Bs[2] (32768)
    bf16* const AsBase = smem;
    bf16* const BsBase = smem + 32768;
    const int tid  = threadIdx.x;
    const int wave = tid >> 6, lane = tid & 63;
    const int wrow = wave >> 2, wcol = wave & 3;       // 2 x 4 wave grid
    const int l16 = lane & 15, quad = lane >> 4;
    const int lrow = lane >> 3;                        // 0..7
    const int lcol = ((lane & 7) ^ lrow) * 8;          // swizzled source chunk
    const int swz  = l16 & 7;                          // read-side XOR
    const size_t tileM = (size_t)blockIdx.x * 256;
    const size_t tileN = (size_t)blockIdx.y * 256;

    // staging bases: wave w, load j covers rows j*64 + w*8 .. +7
    const bf16* aBase = A  + (tileM + wave * 8 + lrow) * (size_t)K + lcol;
    const bf16* bBase = Bt + (tileN + wave * 8 + lrow) * (size_t)K + lcol;
    const int ldsRow0 = wave * 8;

    f32x4 acc[8][4];
    const f32x4 z4 = { 0.f, 0.f, 0.f, 0.f };
#pragma unroll
    for (int mi = 0; mi < 8; ++mi)
#pragma unroll
        for (int ni = 0; ni < 4; ++ni) acc[mi][ni] = z4;

    // prologue: stage K-tile 0 into buf 0 (8 loads/thread), drain, barrier
#pragma unroll
    for (int j = 0; j < 4; ++j) {
        load_lds16(aBase + (size_t)(j * 64) * K, AsBase + (j * 64 + ldsRow0) * 64);
        load_lds16(bBase + (size_t)(j * 64) * K, BsBase + (j * 64 + ldsRow0) * 64);
    }
    asm volatile("s_waitcnt vmcnt(0)" ::: "memory");
    __builtin_amdgcn_s_barrier();

    const int T = K >> 6;
    int cur = 0;
    for (int t = 0; t < T; ++t) {
        const int nxt = cur ^ 1;
        const bool pf = (t + 1 < T);
        const int kc = (t + 1) << 6;                   // next tile's K offset
        const bf16* as = AsBase + cur * 16384;
        const bf16* bs = BsBase + cur * 16384;
        bf16* asn = AsBase + nxt * 16384;
        bf16* bsn = BsBase + nxt * 16384;
        bf16x8 af[4][2], bfr[4][2];

        // ---------------- phase 0: A-half0 + B(n0,n1); stage loads 0-3 ----
#pragma unroll
        for (int j = 0; j < 4; ++j)
#pragma unroll
            for (int kh = 0; kh < 2; ++kh)
                af[j][kh] = *(const bf16x8*)&as[(wrow * 128 + j * 16 + l16) * 64
                                               + (((kh * 4 + quad) ^ swz) * 8)];
#pragma unroll
        for (int ni = 0; ni < 2; ++ni)
#pragma unroll
            for (int kh = 0; kh < 2; ++kh)
                bfr[ni][kh] = *(const bf16x8*)&bs[(wcol * 64 + ni * 16 + l16) * 64
                                                  + (((kh * 4 + quad) ^ swz) * 8)];
        if (pf) {
#pragma unroll
            for (int j = 0; j < 2; ++j) {
                load_lds16(aBase + (size_t)(j * 64) * K + kc, asn + (j * 64 + ldsRow0) * 64);
                load_lds16(bBase + (size_t)(j * 64) * K + kc, bsn + (j * 64 + ldsRow0) * 64);
            }
        }
        __builtin_amdgcn_s_barrier();
        asm volatile("s_waitcnt lgkmcnt(0)" ::: "memory");
        __builtin_amdgcn_sched_barrier(0);
        __builtin_amdgcn_s_setprio(1);
#pragma unroll
        for (int j = 0; j < 4; ++j)
#pragma unroll
            for (int ni = 0; ni < 2; ++ni)
#pragma unroll
                for (int kh = 0; kh < 2; ++kh)
                    acc[j][ni] = __builtin_amdgcn_mfma_f32_16x16x32_bf16(
                        af[j][kh], bfr[ni][kh], acc[j][ni], 0, 0, 0);
        __builtin_amdgcn_s_setprio(0);
        __builtin_amdgcn_s_barrier();

        // ---------------- phase 1: B(n2,n3); stage loads 4-7 --------------
#pragma unroll
        for (int ni = 2; ni < 4; ++ni)
#pragma unroll
            for (int kh = 0; kh < 2; ++kh)
                bfr[ni][kh] = *(const bf16x8*)&bs[(wcol * 64 + ni * 16 + l16) * 64
                                                  + (((kh * 4 + quad) ^ swz) * 8)];
        if (pf) {
#pragma unroll
            for (int j = 2; j < 4; ++j) {
                load_lds16(aBase + (size_t)(j * 64) * K + kc, asn + (j * 64 + ldsRow0) * 64);
                load_lds16(bBase + (size_t)(j * 64) * K + kc, bsn + (j * 64 + ldsRow0) * 64);
            }
        }
        __builtin_amdgcn_s_barrier();
        asm volatile("s_waitcnt lgkmcnt(0)" ::: "memory");
        __builtin_amdgcn_sched_barrier(0);
        __builtin_amdgcn_s_setprio(1);
#pragma unroll
        for (int j = 0; j < 4; ++j)
#pragma unroll
            for (int ni = 2; ni < 4; ++ni)
#pragma unroll
                for (int kh = 0; kh < 2; ++kh)
                    acc[j][ni] = __builtin_amdgcn_mfma_f32_16x16x32_bf16(
                        af[j][kh], bfr[ni][kh], acc[j][ni], 0, 0, 0);
        __builtin_amdgcn_s_setprio(0);
        __builtin_amdgcn_s_barrier();

        // ---------------- phase 2: A-half1 --------------------------------
#pragma unroll
        for (int j = 0; j < 4; ++j)
#pragma unroll
            for (int kh = 0; kh < 2; ++kh)
                af[j][kh] = *(const bf16x8*)&as[(wrow * 128 + 64 + j * 16 + l16) * 64
                                               + (((kh * 4 + quad) ^ swz) * 8)];
        __builtin_amdgcn_s_barrier();
        asm volatile("s_waitcnt lgkmcnt(0)" ::: "memory");
        __builtin_amdgcn_sched_barrier(0);
        __builtin_amdgcn_s_setprio(1);
#pragma unroll
        for (int j = 0; j < 4; ++j)
#pragma unroll
            for (int ni = 0; ni < 2; ++ni)
#pragma unroll
                for (int kh = 0; kh < 2; ++kh)
                    acc[4 + j][ni] = __builtin_amdgcn_mfma_f32_16x16x32_bf16(
                        af[j][kh], bfr[ni][kh], acc[4 + j][ni], 0, 0, 0);
        __builtin_amdgcn_s_setprio(0);
        __builtin_amdgcn_s_barrier();

        // ---------------- phase 3: wait next tile; last quadrant ----------
        if (pf) asm volatile("s_waitcnt vmcnt(0)" ::: "memory");
        __builtin_amdgcn_s_barrier();
        __builtin_amdgcn_sched_barrier(0);
        __builtin_amdgcn_s_setprio(1);
#pragma unroll
        for (int j = 0; j < 4; ++j)
#pragma unroll
            for (int ni = 2; ni < 4; ++ni)
#pragma unroll
                for (int kh = 0; kh < 2; ++kh)
                    acc[4 + j][ni] = __builtin_amdgcn_mfma_f32_16x16x32_bf16(
                        af[j][kh], bfr[ni][kh], acc[4 + j][ni], 0, 0, 0);
        __builtin_amdgcn_s_setprio(0);
        __builtin_amdgcn_s_barrier();

        cur = nxt;
    }

    // ---- epilogue: wave-local LDS transpose -> coalesced wide stores.
    const int rrow = lane >> 2;           // 0..15
    const int rseg = (lane & 3) * 16;     // 0/16/32/48

    if (EPI == 5 || EPI == 7) {
        float* sc = (float*)smem + wave * 1088;     // 16 rows x 68 f32
#pragma unroll
        for (int mi = 0; mi < 8; ++mi) {
#pragma unroll
            for (int ni = 0; ni < 4; ++ni)
#pragma unroll
                for (int r = 0; r < 4; ++r)
                    sc[(quad * 4 + r) * 68 + ni * 16 + l16] = acc[mi][ni][r];
            __builtin_amdgcn_sched_barrier(0);
            const size_t rowg = tileM + wrow * 128 + mi * 16 + rrow;
            const int    colg = (int)tileN + wcol * 64 + rseg;
            if (EPI == 5) {
                const float* rp = res + rowg * (size_t)N + colg;
                float*       op = (float*)outp + rowg * (size_t)N + colg;
#pragma unroll
                for (int u = 0; u < 4; ++u) {
                    f32x4 v = *(f32x4*)&sc[rrow * 68 + rseg + u * 4];
                    f32x4 rv = *(const f32x4*)(rp + u * 4);
                    f32x4 bv = *(const f32x4*)(bias + colg + u * 4);
                    f32x4 o;
#pragma unroll
                    for (int j = 0; j < 4; ++j) o[j] = v[j] + bv[j] + rv[j];
                    *(f32x4*)(op + u * 4) = o;
                }
            } else {  // EPI 7
                const float bv = bias[(int)rowg];
                const bool k_side = (rowg < 512);
                bf16* op = (bf16*)outp + rowg * (size_t)N + colg;
#pragma unroll
                for (int hh = 0; hh < 2; ++hh) {
                    bf16x8 o8;
#pragma unroll
                    for (int j = 0; j < 8; ++j) {
                        float x = sc[rrow * 68 + rseg + hh * 8 + j] + bv;
                        o8[j] = (bf16)(k_side ? elu1f(x) : x);
                    }
                    *(bf16x8*)(op + hh * 8) = o8;
                }
            }
            __builtin_amdgcn_sched_barrier(0);
        }
    } else {  // EPI 2, 4, 8: bf16 scratch, write-side bias+activation
        bf16* sc = (bf16*)smem + wave * 1152;       // 16 rows x 72 bf16
        float addc[4];
        bool  act_on[4];
#pragma unroll
        for (int ni = 0; ni < 4; ++ni) {
            const int cw = (int)tileN + wcol * 64 + ni * 16 + l16;
            if (EPI == 8) {
                act_on[ni] = (cw < 512);
                addc[ni] = act_on[ni] ? bias[cw] : res[cw - 512];
            } else { addc[ni] = bias[cw]; act_on[ni] = true; }
        }
#pragma unroll
        for (int mi = 0; mi < 8; ++mi) {
#pragma unroll
            for (int ni = 0; ni < 4; ++ni)
#pragma unroll
                for (int r = 0; r < 4; ++r) {
                    float x = acc[mi][ni][r] + addc[ni];
                    float y;
                    if (EPI == 2)      y = elu1f(x);
                    else if (EPI == 4) y = geluf(x);
                    else               y = act_on[ni] ? siluf(x) : x;
                    sc[(quad * 4 + r) * 72 + ni * 16 + l16] = (bf16)y;
                }
            __builtin_amdgcn_sched_barrier(0);
            const size_t rowg = tileM + wrow * 128 + mi * 16 + rrow;
            const int    colg = (int)tileN + wcol * 64 + rseg;
            bf16x8 o0 = *(bf16x8*)&sc[rrow * 72 + rseg];
            bf16x8 o1 = *(bf16x8*)&sc[rrow * 72 + rseg + 8];
            if (EPI == 8) {
                const size_t orow = rowg * (size_t)512;
                bf16* dst = (colg < 512) ? ((bf16*)outp  + orow + colg)
                                         : ((bf16*)outp2 + orow + colg - 512);
                *(bf16x8*)dst = o0; *(bf16x8*)(dst + 8) = o1;
            } else {
                bf16* dst = (bf16*)outp + rowg * (size_t)N + colg;
                *(bf16x8*)dst = o0; *(bf16x8*)(dst + 8) = o1;
            }
            __builtin_amdgcn_sched_barrier(0);
        }
    }
}

// ---------------------------------------------------------------------------
// workspace layout (bytes) — total 125,845,504 (~120 MiB)
// ---------------------------------------------------------------------------
#define OFF_WT_ACTIN ((size_t)0)         // bf16 [1024][512] 1MB
#define OFF_WT_Q    ((size_t)1048576)
#define OFF_WT_KV   ((size_t)1572864)
#define OFF_WT_OUT  ((size_t)2621440)
#define OFF_WT_FC1  ((size_t)3145728)
#define OFF_WT_FC2  ((size_t)5242880)
#define OFF_XLN     ((size_t)7340032)    // bf16 16MB (kvbf, hln alias)
#define OFF_ACTRES  ((size_t)24117248)   // bf16 16MB (x3 aliases from here)
#define OFF_Y       ((size_t)40894464)   // bf16 16MB (qb aliases)
#define OFF_XP      ((size_t)57671680)   // bf16 16MB (kvpart, h1 alias from here)
#define OFF_KV      ((size_t)74448896)   // bf16 32MB  kvbT [1024][16384]
#define OFF_KSUM    ((size_t)108003328)  // f32 16KB
#define OFF_XAMUL   ((size_t)109068288)  // bf16 16MB  (xqb early, xamul late)
#define OFF_X3      ((size_t)24117248)   // f32 32MB over actres+Y (dead)
#define OFF_H1      ((size_t)57671680)   // bf16 64MB over xp+kv+xamul (dead)
#define WS_REQUIRED ((size_t)125845504)

extern "C" void kernel_launch(void* const* d_in, const int* in_sizes, int n_in,
                              void* d_out, int out_size, void* d_ws, size_t ws_size,
                              hipStream_t stream)
{
    const float* x_q    = (const float*)d_in[0];
    const float* x_kv   = (const float*)d_in[1];
    const float* cpe1_w = (const float*)d_in[2];
    const float* cpe1_b = (const float*)d_in[3];
    const float* n1_g   = (const float*)d_in[4];
    const float* n1_b   = (const float*)d_in[5];
    const float* in_w   = (const float*)d_in[6];
    const float* in_b   = (const float*)d_in[7];
    const float* act_w  = (const float*)d_in[8];
    const float* act_b  = (const float*)d_in[9];
    const float* dwc_w  = (const float*)d_in[10];
    const float* dwc_b  = (const float*)d_in[11];
    const float* q_w    = (const float*)d_in[12];
    const float* q_b    = (const float*)d_in[13];
    const float* kv_w   = (const float*)d_in[14];
    const float* kv_b   = (const float*)d_in[15];
    const float* lepe_w = (const float*)d_in[16];
    const float* lepe_b = (const float*)d_in[17];
    const float* out_w  = (const float*)d_in[18];
    const float* out_b  = (const float*)d_in[19];
    const float* cpe2_w = (const float*)d_in[20];
    const float* cpe2_b = (const float*)d_in[21];
    const float* n2_g   = (const float*)d_in[22];
    const float* n2_b   = (const float*)d_in[23];
    const float* fc1_w  = (const float*)d_in[24];
    const float* fc1_b  = (const float*)d_in[25];
    const float* fc2_w  = (const float*)d_in[26];
    const float* fc2_b  = (const float*)d_in[27];

    float* outf = (float*)d_out;

    if (ws_size < WS_REQUIRED) {
        zero_k<<<(out_size + 255) / 256, 256, 0, stream>>>(outf, out_size);
        ws_diag_k<<<1, 64, 0, stream>>>(outf, (float)ws_size);
        return;
    }

    char* ws = (char*)d_ws;
    bf16*  wt_actin = (bf16*)(ws + OFF_WT_ACTIN);
    bf16*  wt_q   = (bf16*)(ws + OFF_WT_Q);
    bf16*  wt_kv  = (bf16*)(ws + OFF_WT_KV);
    bf16*  wt_out = (bf16*)(ws + OFF_WT_OUT);
    bf16*  wt_fc1 = (bf16*)(ws + OFF_WT_FC1);
    bf16*  wt_fc2 = (bf16*)(ws + OFF_WT_FC2);
    bf16*  xln    = (bf16*)(ws + OFF_XLN);
    bf16*  kvbf   = (bf16*)(ws + OFF_XLN);      // alias: xln dead after act/in
    bf16*  hln    = (bf16*)(ws + OFF_XLN);      // alias: kvbf dead after attn
    bf16*  actres = (bf16*)(ws + OFF_ACTRES);
    bf16*  Y      = (bf16*)(ws + OFF_Y);
    bf16*  qb     = (bf16*)(ws + OFF_Y);        // alias: Y dead after dwc
    bf16*  xp     = (bf16*)(ws + OFF_XP);
    float* kvpart = (float*)(ws + OFF_XP);      // alias: xp dead after kv-gemm (4MB)
    bf16*  kvbT   = (bf16*)(ws + OFF_KV);       // [1024][16384]
    float* ksum   = (float*)(ws + OFF_KSUM);
    bf16*  xqb    = (bf16*)(ws + OFF_XAMUL);    // early use; dead before attn
    bf16*  xamul  = (bf16*)(ws + OFF_XAMUL);    // written by attn (after q-gemm)
    float* x3     = (float*)(ws + OFF_X3);      // alias
    bf16*  h1     = (bf16*)(ws + OFF_H1);       // alias

    // all weight transposes + x_q -> bf16 conversion, one launch
    TJobs jobs;
    jobs.j[0] = { act_w, wt_actin,             512,  512,    0 };
    jobs.j[1] = { in_w,  wt_actin + 512 * 512, 512,  512,  256 };
    jobs.j[2] = { q_w,   wt_q,                 512,  512,  512 };
    jobs.j[3] = { kv_w,  wt_kv,                512, 1024,  768 };
    jobs.j[4] = { out_w, wt_out,               512,  512, 1280 };
    jobs.j[5] = { fc1_w, wt_fc1,               512, 2048, 1536 };
    jobs.j[6] = { fc2_w, wt_fc2,              2048,  512, 2560 };
    transpose_all_k<<<11776, 256, 0, stream>>>(jobs, x_q, xqb);

    // cpe1 + LN1: shortcut (fp32) lives in d_out  [4 tokens/block]
    cpe_ln_k<<<M_ / 4, 256, 0, stream>>>(x_kv, cpe1_w, cpe1_b, n1_g, n1_b, outf, xln);

    // fused act gate + in-proj (one pass over xln), N=1024  [256x256 pipelined]
    gemm8<8><<<dim3(64, 4), 512, 0, stream>>>(xln, wt_actin, act_b, in_b, actres, Y, 512, 1024);

    // flat-reshape dwconv + silu -> xp (frees Y)
    dwc_silu_k<<<4096, 256, 0, stream>>>(Y, dwc_w, dwc_b, xp);

    // q = elu+1(xqb @ q_w) -> qb (@Y)
    gemm_bt<2><<<dim3(128, 4), 256, 0, stream>>>(xqb, wt_q, q_b, nullptr, qb, nullptr, 512, 512);

    // kvbT[c][token] = (xp @ kv_w)^T : roles swapped (A=wt_kv, Bt=xp)  [256x256]
    gemm8<7><<<dim3(4, 64), 512, 0, stream>>>(wt_kv, xp, kv_b, nullptr, kvbT, nullptr, 512, M_);

    // kvmatT partials (MFMA, no atomics), then fused reduce+convert & k-mean
    kvmat_mfma_k<<<dim3(64, 4), 256, 0, stream>>>(kvbT, kvpart);
    kvfin_k<<<1536, 256, 0, stream>>>(kvpart, kvbf, kvbT, ksum);

    // MFMA attention + lepe + gate multiply (xqb dead from here; xamul written)
    attn_mfma_k<<<dim3(64, 32), 256, 0, stream>>>(qb, kvbT, kvbf, ksum,
                                                  lepe_w, lepe_b, actres, xamul);

    // out-proj + shortcut residual, in-place on d_out
    gemm_bt<5><<<dim3(128, 4), 256, 0, stream>>>(xamul, wt_out, out_b, outf, outf, nullptr, 512, 512);

    // cpe2 + LN2: x2 (=d_out) -> x3 (fp32 ws) + hln (bf16)  [4 tokens/block]
    cpe_ln_k<<<M_ / 4, 256, 0, stream>>>(outf, cpe2_w, cpe2_b, n2_g, n2_b, x3, hln);

    // MLP: fc1 (gelu) [256x256 pipelined] -> fc2 (+x3) -> d_out
    gemm8<4><<<dim3(64, 8), 512, 0, stream>>>(hln, wt_fc1, fc1_b, nullptr, h1, nullptr, 512, 2048);
    gemm_bt<5><<<dim3(128, 4),  256, 0, stream>>>(h1,  wt_fc2, fc2_b, x3, outf, nullptr, 2048, 512);

    (void)in_sizes; (void)n_in; (void)out_size; (void)ws_size;
}